// Round 1
// baseline (2040.458 us; speedup 1.0000x reference)
//
#include <hip/hip_runtime.h>
#include <stdint.h>

#define N_NODES 50000
#define N_EDGES 800000

typedef unsigned short u16;
typedef unsigned int u32;

// ---------------- helpers ----------------
__device__ __forceinline__ float b2f(u16 v) {
    u32 u = ((u32)v) << 16; float f; __builtin_memcpy(&f, &u, 4); return f;
}
__device__ __forceinline__ u16 f2b(float f) {
    u32 u; __builtin_memcpy(&u, &f, 4);
    u32 r = (u + 0x7fffu + ((u >> 16) & 1u)) >> 16; return (u16)r;
}
__device__ __forceinline__ float loadf(const void* p, long idx, bool bf) {
    return bf ? b2f(((const u16*)p)[idx]) : ((const float*)p)[idx];
}
__device__ __forceinline__ float fast_tanh(float x) {
    float e = __expf(2.f * x);
    return 1.f - 2.f / (e + 1.f);
}

// ---------------- f32 weight-block offsets (element counts) ----------------
enum : int {
    NE_W0 = 0,     NE_B0 = 704,   NE_W1 = 768,   NE_B1 = 4864,  NE_W2 = 4928,  NE_B2 = 9024,
    EE_W0 = 9088,  EE_B0 = 9280,  EE_W1 = 9344,  EE_B1 = 13440, EE_W2 = 13504, EE_B2 = 17600,
    MP_W0 = 17664, MP_B0 = 42240, LNW_O = 42624, LNB_O = 43008, MP_W1 = 43392, MP_B1 = 67968,
    PI_W0 = 68160, PI_B0 = 72256, PI_W1 = 72320, PI_B1 = 76416, PI_W2 = 76480, PI_B2 = 76608,
    W_TOTAL = 76610
};

// ---------------- workspace layout (bytes) ----------------
#define OFF_W       ((size_t)0)
#define OFF_FLAG    ((size_t)0x60000)
#define OFF_X0      ((size_t)0x80000)
#define OFF_X1      ((size_t)0x00D00000)
#define OFF_H64     ((size_t)0x01A00000)
#define OFF_E       ((size_t)0x02700000)
#define OFF_ROWPTR  ((size_t)0x08900000)
#define OFF_CURSOR  ((size_t)0x08940000)
#define OFF_ORDER   ((size_t)0x08980000)

struct Ptrs24 { const void* p[24]; };

// ---------------- kernels ----------------

// Detect whether float tensors are stored as bf16 (flag=1) or f32 (flag=0).
// bf16 N(0,1) samples: low u16's exponent field concentrated in [118,132].
// f32: low 16 bits are mantissa noise -> ~6% hit rate.
__global__ void detect_kernel(const void* nf, int* flag) {
    u32 w = ((const u32*)nf)[threadIdx.x & 63];
    u32 lo = w & 0xffffu;
    int e = (int)((lo >> 7) & 0xff);
    int good = ((e >= 118 && e <= 132) || lo == 0) ? 1 : 0;
    unsigned long long b = __ballot(good != 0);
    if (threadIdx.x == 0) *flag = (__popcll(b) >= 48) ? 1 : 0;
}

__global__ void convert_weights(Ptrs24 ps, float* __restrict__ W, const int* flag) {
    const int ksz[24] = {704,64,4096,64,4096,64, 192,64,4096,64,4096,64,
                         24576,384,384,384,24576,192, 4096,64,4096,64,128,2};
    int t = blockIdx.x * blockDim.x + threadIdx.x;
    if (t >= W_TOTAL) return;
    bool bf = (*flag != 0);
    int seg = 0, off = t;
    while (off >= ksz[seg]) { off -= ksz[seg]; seg++; }
    W[t] = bf ? b2f(((const u16*)ps.p[seg])[off]) : ((const float*)ps.p[seg])[off];
}

__global__ void node_encoder(const void* nf, float* __restrict__ x,
                             const float* __restrict__ W, const int* flag) {
    int n = blockIdx.x * blockDim.x + threadIdx.x;
    if (n >= N_NODES) return;
    bool bf = (*flag != 0);
    float in[11];
#pragma unroll
    for (int j = 0; j < 11; j++) in[j] = loadf(nf, (long)n * 11 + j, bf);
    float h1[64], h2[64];
#pragma unroll
    for (int i = 0; i < 64; i++) {
        float a = W[NE_B0 + i];
#pragma unroll
        for (int j = 0; j < 11; j++) a = fmaf(W[NE_W0 + i * 11 + j], in[j], a);
        h1[i] = fast_tanh(a);
    }
#pragma unroll
    for (int i = 0; i < 64; i++) {
        float a = W[NE_B1 + i];
#pragma unroll
        for (int j = 0; j < 64; j++) a = fmaf(W[NE_W1 + i * 64 + j], h1[j], a);
        h2[i] = fast_tanh(a);
    }
#pragma unroll
    for (int i = 0; i < 64; i++) {
        float a = W[NE_B2 + i];
#pragma unroll
        for (int j = 0; j < 64; j++) a = fmaf(W[NE_W2 + i * 64 + j], h2[j], a);
        x[(long)n * 64 + i] = fast_tanh(a);
    }
}

__global__ void edge_encoder(const void* ef, u16* __restrict__ ebuf,
                             const float* __restrict__ W, const int* flag) {
    int e = blockIdx.x * blockDim.x + threadIdx.x;
    if (e >= N_EDGES) return;
    bool bf = (*flag != 0);
    float in0 = loadf(ef, (long)e * 3 + 0, bf);
    float in1 = loadf(ef, (long)e * 3 + 1, bf);
    float in2 = loadf(ef, (long)e * 3 + 2, bf);
    float h1[64], h2[64];
#pragma unroll
    for (int i = 0; i < 64; i++) {
        float a = W[EE_B0 + i];
        a = fmaf(W[EE_W0 + i * 3 + 0], in0, a);
        a = fmaf(W[EE_W0 + i * 3 + 1], in1, a);
        a = fmaf(W[EE_W0 + i * 3 + 2], in2, a);
        h1[i] = fast_tanh(a);
    }
#pragma unroll
    for (int i = 0; i < 64; i++) {
        float a = W[EE_B1 + i];
#pragma unroll
        for (int j = 0; j < 64; j++) a = fmaf(W[EE_W1 + i * 64 + j], h1[j], a);
        h2[i] = fast_tanh(a);
    }
#pragma unroll
    for (int i = 0; i < 64; i++) {
        float a = W[EE_B2 + i];
#pragma unroll
        for (int j = 0; j < 64; j++) a = fmaf(W[EE_W2 + i * 64 + j], h2[j], a);
        ebuf[(long)e * 64 + i] = f2b(fast_tanh(a));
    }
}

__global__ void hist_kernel(const int* __restrict__ dst, int* __restrict__ rowptr) {
    int e = blockIdx.x * blockDim.x + threadIdx.x;
    if (e < N_EDGES) atomicAdd(&rowptr[dst[e] + 1], 1);
}

// single-block inclusive scan over rowptr[0..N_NODES]
__global__ void scan_kernel(int* __restrict__ rowptr) {
    __shared__ int sm[1024];
    int carry = 0;
    for (int base = 0; base <= N_NODES; base += 1024) {
        int i = base + (int)threadIdx.x;
        int v = (i <= N_NODES) ? rowptr[i] : 0;
        sm[threadIdx.x] = v;
        __syncthreads();
        for (int off = 1; off < 1024; off <<= 1) {
            int t = (threadIdx.x >= (unsigned)off) ? sm[threadIdx.x - off] : 0;
            __syncthreads();
            sm[threadIdx.x] += t;
            __syncthreads();
        }
        int incl = sm[threadIdx.x];
        int total = sm[1023];
        if (i <= N_NODES) rowptr[i] = incl + carry;
        carry += total;
        __syncthreads();
    }
}

__global__ void cursor_init(const int* __restrict__ rowptr, int* __restrict__ cursor) {
    int n = blockIdx.x * blockDim.x + threadIdx.x;
    if (n < N_NODES) cursor[n] = rowptr[n];
}

__global__ void scatter_kernel(const int* __restrict__ dst, int* __restrict__ cursor,
                               int* __restrict__ order) {
    int e = blockIdx.x * blockDim.x + threadIdx.x;
    if (e >= N_EDGES) return;
    int p = atomicAdd(&cursor[dst[e]], 1);
    order[p] = e;
}

// one wave per node, lane = feature; register-only softmax aggregation
__global__ __launch_bounds__(256) void aggregate_kernel(
        const float* __restrict__ x, const u16* __restrict__ ebuf,
        const int* __restrict__ order, const int* __restrict__ rowptr,
        const int* __restrict__ src, float* __restrict__ h64) {
    int gw = (int)((blockIdx.x * 256 + threadIdx.x) >> 6);
    int lane = (int)(threadIdx.x & 63);
    if (gw >= N_NODES) return;
    int beg = rowptr[gw], end = rowptr[gw + 1];
    float num = 0.f, den = 0.f;
    for (int k = beg; k < end; k++) {
        int j = order[k];
        int s = src[j];
        float m = x[(long)s * 64 + lane] + b2f(ebuf[(long)j * 64 + lane]);
        m = fmaxf(m, 0.f) + 1e-7f;
        float w = __expf(m);          // max-shift dropped: msg bounded, alpha identical
        num = fmaf(w, m, num);
        den += w;
    }
    float agg = (den > 0.f) ? num / den : 0.f;
    h64[(long)gw * 64 + lane] = x[(long)gw * 64 + lane] + agg;
}

// thread per node: Lin(64->128) -> LN -> relu -> Lin(128->64), two-pass (no t[128] array)
__global__ void node_mlp(const float* __restrict__ h64, float* __restrict__ xout,
                         const float* __restrict__ W, int r) {
    int n = blockIdx.x * blockDim.x + threadIdx.x;
    if (n >= N_NODES) return;
    const float* w0 = W + MP_W0 + r * 128 * 64;
    const float* b0 = W + MP_B0 + r * 128;
    const float* lw = W + LNW_O + r * 128;
    const float* lb = W + LNB_O + r * 128;
    const float* w1 = W + MP_W1 + r * 64 * 128;
    const float* b1 = W + MP_B1 + r * 64;
    float h[64];
#pragma unroll
    for (int j = 0; j < 64; j++) h[j] = h64[(long)n * 64 + j];
    float sum = 0.f, sumsq = 0.f;
    for (int i = 0; i < 128; i++) {
        float a = b0[i];
#pragma unroll
        for (int j = 0; j < 64; j++) a = fmaf(w0[i * 64 + j], h[j], a);
        sum += a; sumsq += a * a;
    }
    float mu = sum * (1.f / 128.f);
    float var = sumsq * (1.f / 128.f) - mu * mu;
    float inv = rsqrtf(var + 1e-5f);
    float out[64];
#pragma unroll
    for (int j = 0; j < 64; j++) out[j] = b1[j];
    for (int i = 0; i < 128; i++) {
        float a = b0[i];
#pragma unroll
        for (int j = 0; j < 64; j++) a = fmaf(w0[i * 64 + j], h[j], a);
        float u = fmaf((a - mu) * inv, lw[i], lb[i]);
        u = fmaxf(u, 0.f);
#pragma unroll
        for (int j = 0; j < 64; j++) out[j] = fmaf(w1[j * 128 + i], u, out[j]);
    }
#pragma unroll
    for (int j = 0; j < 64; j++) xout[(long)n * 64 + j] = out[j];
}

__global__ void policy_head(const float* __restrict__ x, void* out,
                            const float* __restrict__ W, const int* flag) {
    int n = blockIdx.x * blockDim.x + threadIdx.x;
    if (n >= N_NODES) return;
    bool bf = (*flag != 0);
    float h[64], h2[64];
#pragma unroll
    for (int j = 0; j < 64; j++) h[j] = x[(long)n * 64 + j];
#pragma unroll
    for (int i = 0; i < 64; i++) {
        float a = W[PI_B0 + i];
#pragma unroll
        for (int j = 0; j < 64; j++) a = fmaf(W[PI_W0 + i * 64 + j], h[j], a);
        h2[i] = fast_tanh(a);
    }
#pragma unroll
    for (int i = 0; i < 64; i++) {
        float a = W[PI_B1 + i];
#pragma unroll
        for (int j = 0; j < 64; j++) a = fmaf(W[PI_W1 + i * 64 + j], h2[j], a);
        h[i] = fast_tanh(a);
    }
    float o0 = W[PI_B2 + 0];
#pragma unroll
    for (int j = 0; j < 64; j++) o0 = fmaf(W[PI_W2 + j], h[j], o0);
    float means = 30.f * o0;   // -30 + (o0+1)*30
    if (bf) ((u16*)out)[n] = f2b(means);
    else    ((float*)out)[n] = means;
}

// ---------------- launch ----------------
extern "C" void kernel_launch(void* const* d_in, const int* in_sizes, int n_in,
                              void* d_out, int out_size, void* d_ws, size_t ws_size,
                              hipStream_t stream) {
    char* ws = (char*)d_ws;
    float* W      = (float*)(ws + OFF_W);
    int*   flag   = (int*)(ws + OFF_FLAG);
    float* x0     = (float*)(ws + OFF_X0);
    float* x1     = (float*)(ws + OFF_X1);
    float* h64    = (float*)(ws + OFF_H64);
    u16*   ebuf   = (u16*)(ws + OFF_E);
    int*   rowptr = (int*)(ws + OFF_ROWPTR);
    int*   cursor = (int*)(ws + OFF_CURSOR);
    int*   order  = (int*)(ws + OFF_ORDER);

    const int* ei   = (const int*)d_in[2];
    const int* srcv = ei;
    const int* dstv = ei + N_EDGES;

    detect_kernel<<<1, 64, 0, stream>>>(d_in[0], flag);
    hipMemsetAsync(rowptr, 0, (N_NODES + 1) * sizeof(int), stream);

    Ptrs24 ps;
    for (int k = 0; k < 24; k++) ps.p[k] = d_in[3 + k];
    convert_weights<<<(W_TOTAL + 255) / 256, 256, 0, stream>>>(ps, W, flag);

    node_encoder<<<(N_NODES + 255) / 256, 256, 0, stream>>>(d_in[0], x0, W, flag);
    edge_encoder<<<(N_EDGES + 255) / 256, 256, 0, stream>>>(d_in[1], ebuf, W, flag);

    hist_kernel<<<(N_EDGES + 255) / 256, 256, 0, stream>>>(dstv, rowptr);
    scan_kernel<<<1, 1024, 0, stream>>>(rowptr);
    cursor_init<<<(N_NODES + 255) / 256, 256, 0, stream>>>(rowptr, cursor);
    scatter_kernel<<<(N_EDGES + 255) / 256, 256, 0, stream>>>(dstv, cursor, order);

    float* xc = x0; float* xn = x1;
    for (int r = 0; r < 3; r++) {
        aggregate_kernel<<<(N_NODES * 64) / 256, 256, 0, stream>>>(xc, ebuf, order, rowptr, srcv, h64);
        node_mlp<<<(N_NODES + 255) / 256, 256, 0, stream>>>(h64, xn, W, r);
        float* t = xc; xc = xn; xn = t;
    }
    policy_head<<<(N_NODES + 255) / 256, 256, 0, stream>>>(xc, d_out, W, flag);
}

// Round 2
// 1146.836 us; speedup vs baseline: 1.7792x; 1.7792x over previous
//
#include <hip/hip_runtime.h>
#include <stdint.h>

#define N_NODES 50000
#define N_EDGES 800000

typedef unsigned short u16;
typedef unsigned int u32;

// ---------------- helpers ----------------
__device__ __forceinline__ float b2f(u16 v) {
    u32 u = ((u32)v) << 16; float f; __builtin_memcpy(&f, &u, 4); return f;
}
__device__ __forceinline__ u16 f2b(float f) {
    u32 u; __builtin_memcpy(&u, &f, 4);
    u32 r = (u + 0x7fffu + ((u >> 16) & 1u)) >> 16; return (u16)r;
}
__device__ __forceinline__ float lo2f(u32 p) {
    u32 u = p << 16; float f; __builtin_memcpy(&f, &u, 4); return f;
}
__device__ __forceinline__ float hi2f(u32 p) {
    u32 u = p & 0xffff0000u; float f; __builtin_memcpy(&f, &u, 4); return f;
}
__device__ __forceinline__ u32 pack2(float a, float b) {
    return (u32)f2b(a) | (((u32)f2b(b)) << 16);
}
__device__ __forceinline__ float fast_tanh(float x) {
    float e = __expf(2.f * x);
    return 1.f - __fdividef(2.f, e + 1.f);
}

// ---------------- f32 weight layout (transposed to [in][out]) ----------------
enum : int {
    NE_T0 = 0,     NE_B0 = 704,   NE_T1 = 768,   NE_B1 = 4864,  NE_T2 = 4928,  NE_B2 = 9024,
    EE_T0 = 9088,  EE_B0 = 9280,  EE_T1 = 9344,  EE_B1 = 13440, EE_T2 = 13504, EE_B2 = 17600,
    MP_T0 = 17664, MP_B0 = 42240, LNW_O = 42624, LNB_O = 43008, MP_T1 = 43392, MP_B1 = 67968,
    PI_T0 = 68160, PI_B0 = 72256, PI_T1 = 72320, PI_B1 = 76416, PI_W2 = 76480, PI_B2 = 76608,
    W_TOTAL = 76610
};

// ---------------- workspace layout (bytes) ----------------
#define OFF_W       ((size_t)0)
#define OFF_FLAG    ((size_t)0x60000)
#define OFF_X0      ((size_t)0x80000)
#define OFF_X1      ((size_t)0x00D00000)
#define OFF_H64     ((size_t)0x01A00000)
#define OFF_E       ((size_t)0x02700000)   // ebuf: 800k x 64 bf16 = 102.4 MB
#define OFF_ROWPTR  ((size_t)0x08900000)
#define OFF_CURSOR  ((size_t)0x08940000)
#define OFF_PERM    ((size_t)0x08980000)
#define OFF_SRCS    ((size_t)0x08D00000)
#define OFF_T       ((size_t)0x09100000)   // t: 50k x 128 bf16 = 12.8 MB

struct Ptrs24 { const void* p[24]; };

// ---------------- kernels ----------------

// bf16-vs-f32 detector (see round 1): exponent of low u16 concentrated for bf16 data
__global__ void detect_kernel(const void* nf, int* flag) {
    u32 w = ((const u32*)nf)[threadIdx.x & 63];
    u32 lo = w & 0xffffu;
    int e = (int)((lo >> 7) & 0xff);
    int good = ((e >= 118 && e <= 132) || lo == 0) ? 1 : 0;
    unsigned long long b = __ballot(good != 0);
    if (threadIdx.x == 0) *flag = (__popcll(b) >= 48) ? 1 : 0;
}

// build f32 weight buffer; weight matrices transposed to [in][out]
__global__ void convert_weights(Ptrs24 ps, float* __restrict__ W, const int* flag) {
    // {IN, OUT, slices, transpose}; count = IN*OUT*slices
    const int segIN[24] = {11,64,64,64,64,64, 3,64,64,64,64,64, 64,384,384,384,128,192, 64,64,64,64,128,2};
    const int segOUT[24]= {64, 1,64, 1,64, 1, 64, 1,64, 1,64, 1, 128, 1,  1,  1, 64,  1, 64, 1,64, 1,  1,1};
    const int segS[24]  = { 1, 1, 1, 1, 1, 1,  1, 1, 1, 1, 1, 1,   3, 1,  1,  1,  3,  1,  1, 1, 1, 1,  1,1};
    const int segTR[24] = { 1, 0, 1, 0, 1, 0,  1, 0, 1, 0, 1, 0,   1, 0,  0,  0,  1,  0,  1, 0, 1, 0,  0,0};
    int t = blockIdx.x * blockDim.x + threadIdx.x;
    if (t >= W_TOTAL) return;
    bool bf = (*flag != 0);
    int seg = 0, off = t;
    for (;;) {
        int cnt = segIN[seg] * segOUT[seg] * segS[seg];
        if (off < cnt) break;
        off -= cnt; seg++;
    }
    int srcIdx;
    if (segTR[seg]) {
        int per = segIN[seg] * segOUT[seg];
        int s = off / per, d = off % per;
        int j = d / segOUT[seg], i = d % segOUT[seg];   // dst T[j][i] = src w[i][j]
        srcIdx = s * per + i * segIN[seg] + j;
    } else {
        srcIdx = off;
    }
    const void* p = ps.p[seg];
    W[t] = bf ? b2f(((const u16*)p)[srcIdx]) : ((const float*)p)[srcIdx];
}

// ---- generic 64->64 layer: input = packed-bf16 LDS row, weights transposed ----
template<bool TANH>
__device__ __forceinline__ void layer64_lds(const u32* lin, u32* lout,
        const float* __restrict__ Wt, const float* __restrict__ bias) {
    for (int c = 0; c < 4; c++) {
        float acc[16];
#pragma unroll
        for (int k = 0; k < 16; k++) acc[k] = bias[c * 16 + k];
#pragma unroll 4
        for (int jp = 0; jp < 32; jp++) {
            u32 p = lin[jp];
            float f0 = lo2f(p), f1 = hi2f(p);
            const float* w = Wt + (2 * jp) * 64 + c * 16;
#pragma unroll
            for (int k = 0; k < 16; k++) acc[k] = fmaf(w[k], f0, acc[k]);
#pragma unroll
            for (int k = 0; k < 16; k++) acc[k] = fmaf(w[64 + k], f1, acc[k]);
        }
#pragma unroll
        for (int k = 0; k < 8; k++) {
            float a0 = TANH ? fast_tanh(acc[2 * k]) : acc[2 * k];
            float a1 = TANH ? fast_tanh(acc[2 * k + 1]) : acc[2 * k + 1];
            lout[c * 8 + k] = pack2(a0, a1);
        }
    }
}

// final 64->64 tanh layer writing packed bf16 to global
__device__ __forceinline__ void layer64_gbf16(const u32* lin, u32* gout,
        const float* __restrict__ Wt, const float* __restrict__ bias) {
    for (int c = 0; c < 4; c++) {
        float acc[16];
#pragma unroll
        for (int k = 0; k < 16; k++) acc[k] = bias[c * 16 + k];
#pragma unroll 4
        for (int jp = 0; jp < 32; jp++) {
            u32 p = lin[jp];
            float f0 = lo2f(p), f1 = hi2f(p);
            const float* w = Wt + (2 * jp) * 64 + c * 16;
#pragma unroll
            for (int k = 0; k < 16; k++) acc[k] = fmaf(w[k], f0, acc[k]);
#pragma unroll
            for (int k = 0; k < 16; k++) acc[k] = fmaf(w[64 + k], f1, acc[k]);
        }
#pragma unroll
        for (int k = 0; k < 8; k++)
            gout[c * 8 + k] = pack2(fast_tanh(acc[2 * k]), fast_tanh(acc[2 * k + 1]));
    }
}

// final 64->64 layer writing f32 to global
template<bool TANH>
__device__ __forceinline__ void layer64_gf32(const u32* lin, float* gout,
        const float* __restrict__ Wt, const float* __restrict__ bias) {
    for (int c = 0; c < 4; c++) {
        float acc[16];
#pragma unroll
        for (int k = 0; k < 16; k++) acc[k] = bias[c * 16 + k];
#pragma unroll 4
        for (int jp = 0; jp < 32; jp++) {
            u32 p = lin[jp];
            float f0 = lo2f(p), f1 = hi2f(p);
            const float* w = Wt + (2 * jp) * 64 + c * 16;
#pragma unroll
            for (int k = 0; k < 16; k++) acc[k] = fmaf(w[k], f0, acc[k]);
#pragma unroll
            for (int k = 0; k < 16; k++) acc[k] = fmaf(w[64 + k], f1, acc[k]);
        }
#pragma unroll
        for (int k = 0; k < 16; k++)
            gout[c * 16 + k] = TANH ? fast_tanh(acc[k]) : acc[k];
    }
}

#define BLK 192   // 3 waves; 2 LDS row-buffers of 192x33 dwords = 50688 B < 64 KB

__global__ __launch_bounds__(BLK) void node_encoder(const void* nf, float* __restrict__ x,
        const float* __restrict__ W, const int* flag) {
    __shared__ u32 lds[2 * BLK * 33];
    int n = blockIdx.x * BLK + threadIdx.x;
    if (n >= N_NODES) return;
    bool bf = (*flag != 0);
    float in[11];
#pragma unroll
    for (int j = 0; j < 11; j++)
        in[j] = bf ? b2f(((const u16*)nf)[(long)n * 11 + j]) : ((const float*)nf)[(long)n * 11 + j];
    u32* rowA = lds + threadIdx.x * 33;
    u32* rowB = lds + BLK * 33 + threadIdx.x * 33;
    for (int c = 0; c < 4; c++) {          // 11 -> 64
        float acc[16];
#pragma unroll
        for (int k = 0; k < 16; k++) acc[k] = W[NE_B0 + c * 16 + k];
#pragma unroll
        for (int j = 0; j < 11; j++) {
            const float* w = W + NE_T0 + j * 64 + c * 16;
#pragma unroll
            for (int k = 0; k < 16; k++) acc[k] = fmaf(w[k], in[j], acc[k]);
        }
#pragma unroll
        for (int k = 0; k < 8; k++)
            rowA[c * 8 + k] = pack2(fast_tanh(acc[2 * k]), fast_tanh(acc[2 * k + 1]));
    }
    layer64_lds<true>(rowA, rowB, W + NE_T1, W + NE_B1);
    layer64_gf32<true>(rowB, x + (long)n * 64, W + NE_T2, W + NE_B2);
}

__global__ __launch_bounds__(BLK) void edge_encoder(const void* ef, u32* __restrict__ ebuf_u32,
        const int* __restrict__ perm, const float* __restrict__ W, const int* flag) {
    __shared__ u32 lds[2 * BLK * 33];
    int e = blockIdx.x * BLK + threadIdx.x;
    if (e >= N_EDGES) return;
    bool bf = (*flag != 0);
    float i0, i1, i2;
    if (bf) { const u16* p = (const u16*)ef + (long)e * 3; i0 = b2f(p[0]); i1 = b2f(p[1]); i2 = b2f(p[2]); }
    else    { const float* p = (const float*)ef + (long)e * 3; i0 = p[0]; i1 = p[1]; i2 = p[2]; }
    u32* rowA = lds + threadIdx.x * 33;
    u32* rowB = lds + BLK * 33 + threadIdx.x * 33;
    for (int c = 0; c < 4; c++) {          // 3 -> 64
        float acc[16];
#pragma unroll
        for (int k = 0; k < 16; k++) acc[k] = W[EE_B0 + c * 16 + k];
        const float* w0 = W + EE_T0 + c * 16;
#pragma unroll
        for (int k = 0; k < 16; k++) acc[k] = fmaf(w0[k], i0, acc[k]);
#pragma unroll
        for (int k = 0; k < 16; k++) acc[k] = fmaf(w0[64 + k], i1, acc[k]);
#pragma unroll
        for (int k = 0; k < 16; k++) acc[k] = fmaf(w0[128 + k], i2, acc[k]);
#pragma unroll
        for (int k = 0; k < 8; k++)
            rowA[c * 8 + k] = pack2(fast_tanh(acc[2 * k]), fast_tanh(acc[2 * k + 1]));
    }
    layer64_lds<true>(rowA, rowB, W + EE_T1, W + EE_B1);
    // write in dst-sorted order so aggregation streams ebuf
    u32* gout = ebuf_u32 + (long)perm[e] * 32;
    layer64_gbf16(rowB, gout, W + EE_T2, W + EE_B2);
}

__global__ void hist_kernel(const int* __restrict__ dst, int* __restrict__ rowptr) {
    int e = blockIdx.x * blockDim.x + threadIdx.x;
    if (e < N_EDGES) atomicAdd(&rowptr[dst[e] + 1], 1);
}

// wave-shuffle scan, 1024 threads, inclusive over rowptr[0..N_NODES]
__global__ void scan_kernel(int* __restrict__ rowptr) {
    __shared__ int wsum[16];
    int tid = threadIdx.x, lane = tid & 63, wid = tid >> 6;
    int carry = 0;
    for (int base = 0; base <= N_NODES; base += 1024) {
        int i = base + tid;
        int v = (i <= N_NODES) ? rowptr[i] : 0;
#pragma unroll
        for (int off = 1; off < 64; off <<= 1) {
            int t = __shfl_up(v, off, 64);
            if (lane >= off) v += t;
        }
        if (lane == 63) wsum[wid] = v;
        __syncthreads();
        if (tid == 0) {
            int s = 0;
            for (int w2 = 0; w2 < 16; w2++) { s += wsum[w2]; wsum[w2] = s; }
        }
        __syncthreads();
        int add = carry + (wid ? wsum[wid - 1] : 0);
        if (i <= N_NODES) rowptr[i] = v + add;
        carry += wsum[15];
        __syncthreads();
    }
}

__global__ void cursor_init(const int* __restrict__ rowptr, int* __restrict__ cursor) {
    int n = blockIdx.x * blockDim.x + threadIdx.x;
    if (n < N_NODES) cursor[n] = rowptr[n];
}

__global__ void scatter_kernel(const int* __restrict__ dst, const int* __restrict__ src,
                               int* __restrict__ cursor, int* __restrict__ perm,
                               int* __restrict__ srcs) {
    int e = blockIdx.x * blockDim.x + threadIdx.x;
    if (e >= N_EDGES) return;
    int p = atomicAdd(&cursor[dst[e]], 1);
    perm[e] = p;
    srcs[p] = src[e];
}

// wave per node, lane = feature; ebuf/srcs stream contiguously, only x[s] gathers
__global__ __launch_bounds__(256) void aggregate_kernel(
        const float* __restrict__ x, const u16* __restrict__ ebuf,
        const int* __restrict__ srcs, const int* __restrict__ rowptr,
        float* __restrict__ h64) {
    int gw = (int)((blockIdx.x * 256 + threadIdx.x) >> 6);
    int lane = (int)(threadIdx.x & 63);
    if (gw >= N_NODES) return;
    int beg = rowptr[gw], end = rowptr[gw + 1];
    float num = 0.f, den = 0.f;
    int k = beg;
    for (; k + 1 < end; k += 2) {
        int s0 = srcs[k], s1 = srcs[k + 1];
        float e0 = b2f(ebuf[(long)k * 64 + lane]);
        float e1 = b2f(ebuf[(long)(k + 1) * 64 + lane]);
        float m0 = fmaxf(x[(long)s0 * 64 + lane] + e0, 0.f) + 1e-7f;
        float m1 = fmaxf(x[(long)s1 * 64 + lane] + e1, 0.f) + 1e-7f;
        float w0 = __expf(m0), w1 = __expf(m1);     // max-shift dropped: msg bounded
        num = fmaf(w0, m0, num); den += w0;
        num = fmaf(w1, m1, num); den += w1;
    }
    if (k < end) {
        int s0 = srcs[k];
        float m0 = fmaxf(x[(long)s0 * 64 + lane] + b2f(ebuf[(long)k * 64 + lane]), 0.f) + 1e-7f;
        float w0 = __expf(m0);
        num = fmaf(w0, m0, num); den += w0;
    }
    float agg = (den > 0.f) ? __fdividef(num, den) : 0.f;
    h64[(long)gw * 64 + lane] = x[(long)gw * 64 + lane] + agg;
}

// node MLP part A: 64 -> 128 (no activation), t written packed bf16
__global__ __launch_bounds__(BLK) void mlpA(const float* __restrict__ h64,
        u32* __restrict__ tbuf, const float* __restrict__ W, int r) {
    __shared__ u32 lds[BLK * 33];
    int n = blockIdx.x * BLK + threadIdx.x;
    if (n >= N_NODES) return;
    u32* row = lds + threadIdx.x * 33;
    const float* hrow = h64 + (long)n * 64;
#pragma unroll 8
    for (int q = 0; q < 32; q++) row[q] = pack2(hrow[2 * q], hrow[2 * q + 1]);
    const float* T0 = W + MP_T0 + r * 8192;
    const float* B0 = W + MP_B0 + r * 128;
    u32* trow = tbuf + (long)n * 64;
    for (int c = 0; c < 8; c++) {
        float acc[16];
#pragma unroll
        for (int k = 0; k < 16; k++) acc[k] = B0[c * 16 + k];
#pragma unroll 4
        for (int jp = 0; jp < 32; jp++) {
            u32 p = row[jp];
            float f0 = lo2f(p), f1 = hi2f(p);
            const float* w = T0 + (2 * jp) * 128 + c * 16;
#pragma unroll
            for (int k = 0; k < 16; k++) acc[k] = fmaf(w[k], f0, acc[k]);
#pragma unroll
            for (int k = 0; k < 16; k++) acc[k] = fmaf(w[128 + k], f1, acc[k]);
        }
#pragma unroll
        for (int k = 0; k < 8; k++) trow[c * 8 + k] = pack2(acc[2 * k], acc[2 * k + 1]);
    }
}

// node MLP part B: LayerNorm(128) -> ReLU -> 128 -> 64, f32 out
__global__ __launch_bounds__(BLK) void mlpB(const u32* __restrict__ tbuf,
        float* __restrict__ xout, const float* __restrict__ W, int r) {
    __shared__ u32 lds[BLK * 65];
    int n = blockIdx.x * BLK + threadIdx.x;
    if (n >= N_NODES) return;
    u32* row = lds + threadIdx.x * 65;
    const u32* trow = tbuf + (long)n * 64;
    float sum = 0.f, sq = 0.f;
#pragma unroll 8
    for (int q = 0; q < 64; q++) {
        u32 p = trow[q]; row[q] = p;
        float f0 = lo2f(p), f1 = hi2f(p);
        sum += f0 + f1;
        sq = fmaf(f0, f0, sq); sq = fmaf(f1, f1, sq);
    }
    float mu = sum * (1.f / 128.f);
    float var = sq * (1.f / 128.f) - mu * mu;
    float inv = rsqrtf(var + 1e-5f);
    const float* LW = W + LNW_O + r * 128;
    const float* LB = W + LNB_O + r * 128;
#pragma unroll 8
    for (int q = 0; q < 64; q++) {
        u32 p = row[q];
        float f0 = (lo2f(p) - mu) * inv, f1 = (hi2f(p) - mu) * inv;
        float u0 = fmaxf(fmaf(f0, LW[2 * q], LB[2 * q]), 0.f);
        float u1 = fmaxf(fmaf(f1, LW[2 * q + 1], LB[2 * q + 1]), 0.f);
        row[q] = pack2(u0, u1);
    }
    const float* T1 = W + MP_T1 + r * 8192;
    const float* B1 = W + MP_B1 + r * 64;
    float* xrow = xout + (long)n * 64;
    for (int c = 0; c < 4; c++) {
        float acc[16];
#pragma unroll
        for (int k = 0; k < 16; k++) acc[k] = B1[c * 16 + k];
#pragma unroll 4
        for (int jp = 0; jp < 64; jp++) {
            u32 p = row[jp];
            float f0 = lo2f(p), f1 = hi2f(p);
            const float* w = T1 + (2 * jp) * 64 + c * 16;
#pragma unroll
            for (int k = 0; k < 16; k++) acc[k] = fmaf(w[k], f0, acc[k]);
#pragma unroll
            for (int k = 0; k < 16; k++) acc[k] = fmaf(w[64 + k], f1, acc[k]);
        }
#pragma unroll
        for (int k = 0; k < 16; k++) xrow[c * 16 + k] = acc[k];
    }
}

__global__ __launch_bounds__(BLK) void policy_head(const float* __restrict__ x, void* out,
        const float* __restrict__ W, const int* flag) {
    __shared__ u32 lds[2 * BLK * 33];
    int n = blockIdx.x * BLK + threadIdx.x;
    if (n >= N_NODES) return;
    bool bf = (*flag != 0);
    u32* rowA = lds + threadIdx.x * 33;
    u32* rowB = lds + BLK * 33 + threadIdx.x * 33;
    const float* xr = x + (long)n * 64;
#pragma unroll 8
    for (int q = 0; q < 32; q++) rowA[q] = pack2(xr[2 * q], xr[2 * q + 1]);
    layer64_lds<true>(rowA, rowB, W + PI_T0, W + PI_B0);
    layer64_lds<true>(rowB, rowA, W + PI_T1, W + PI_B1);
    float o = W[PI_B2];
#pragma unroll 8
    for (int q = 0; q < 32; q++) {
        u32 p = rowA[q];
        o = fmaf(W[PI_W2 + 2 * q], lo2f(p), o);
        o = fmaf(W[PI_W2 + 2 * q + 1], hi2f(p), o);
    }
    float means = 30.f * o;   // -30 + (o+1)*30
    if (bf) ((u16*)out)[n] = f2b(means);
    else    ((float*)out)[n] = means;
}

// ---------------- launch ----------------
extern "C" void kernel_launch(void* const* d_in, const int* in_sizes, int n_in,
                              void* d_out, int out_size, void* d_ws, size_t ws_size,
                              hipStream_t stream) {
    char* ws = (char*)d_ws;
    float* W      = (float*)(ws + OFF_W);
    int*   flag   = (int*)(ws + OFF_FLAG);
    float* x0     = (float*)(ws + OFF_X0);
    float* x1     = (float*)(ws + OFF_X1);
    float* h64    = (float*)(ws + OFF_H64);
    u32*   ebuf32 = (u32*)(ws + OFF_E);
    u16*   ebuf16 = (u16*)(ws + OFF_E);
    int*   rowptr = (int*)(ws + OFF_ROWPTR);
    int*   cursor = (int*)(ws + OFF_CURSOR);
    int*   perm   = (int*)(ws + OFF_PERM);
    int*   srcs   = (int*)(ws + OFF_SRCS);
    u32*   tbuf   = (u32*)(ws + OFF_T);

    const int* ei   = (const int*)d_in[2];
    const int* srcv = ei;
    const int* dstv = ei + N_EDGES;

    detect_kernel<<<1, 64, 0, stream>>>(d_in[0], flag);
    hipMemsetAsync(rowptr, 0, (N_NODES + 1) * sizeof(int), stream);

    Ptrs24 ps;
    for (int k = 0; k < 24; k++) ps.p[k] = d_in[3 + k];
    convert_weights<<<(W_TOTAL + 255) / 256, 256, 0, stream>>>(ps, W, flag);

    hist_kernel<<<(N_EDGES + 255) / 256, 256, 0, stream>>>(dstv, rowptr);
    scan_kernel<<<1, 1024, 0, stream>>>(rowptr);
    cursor_init<<<(N_NODES + 255) / 256, 256, 0, stream>>>(rowptr, cursor);
    scatter_kernel<<<(N_EDGES + 255) / 256, 256, 0, stream>>>(dstv, srcv, cursor, perm, srcs);

    node_encoder<<<(N_NODES + BLK - 1) / BLK, BLK, 0, stream>>>(d_in[0], x0, W, flag);
    edge_encoder<<<(N_EDGES + BLK - 1) / BLK, BLK, 0, stream>>>(d_in[1], ebuf32, perm, W, flag);

    float* xc = x0; float* xn = x1;
    for (int r = 0; r < 3; r++) {
        aggregate_kernel<<<(N_NODES * 64 + 255) / 256, 256, 0, stream>>>(xc, ebuf16, srcs, rowptr, h64);
        mlpA<<<(N_NODES + BLK - 1) / BLK, BLK, 0, stream>>>(h64, tbuf, W, r);
        mlpB<<<(N_NODES + BLK - 1) / BLK, BLK, 0, stream>>>(tbuf, xn, W, r);
        float* t = xc; xc = xn; xn = t;
    }
    policy_head<<<(N_NODES + BLK - 1) / BLK, BLK, 0, stream>>>(xc, d_out, W, flag);
}

// Round 3
// 558.154 us; speedup vs baseline: 3.6557x; 2.0547x over previous
//
#include <hip/hip_runtime.h>
#include <stdint.h>

#define N_NODES 50000
#define N_EDGES 800000

typedef unsigned short u16;
typedef unsigned int u32;
typedef __attribute__((ext_vector_type(8))) short short8;   // 8 bf16 = A/B frag
typedef __attribute__((ext_vector_type(4))) float f32x4;    // C/D frag
typedef __attribute__((ext_vector_type(4))) u32 u32x4;

// ---------------- helpers ----------------
__device__ __forceinline__ float b2f(u16 v) {
    u32 u = ((u32)v) << 16; float f; __builtin_memcpy(&f, &u, 4); return f;
}
__device__ __forceinline__ u16 f2b(float f) {
    u32 u; __builtin_memcpy(&u, &f, 4);
    u32 r = (u + 0x7fffu + ((u >> 16) & 1u)) >> 16; return (u16)r;
}
__device__ __forceinline__ u32 pack2(float a, float b) {
    return (u32)f2b(a) | (((u32)f2b(b)) << 16);
}
__device__ __forceinline__ float fast_tanh(float x) {
    float e = __expf(2.f * x);
    return 1.f - __fdividef(2.f, e + 1.f);
}
__device__ __forceinline__ f32x4 mfma16(short8 a, short8 b, f32x4 c) {
    return __builtin_amdgcn_mfma_f32_16x16x32_bf16(a, b, c, 0, 0, 0);
}

// ---------------- f32 weight layout (transposed to [in][out]) ----------------
enum : int {
    NE_T0 = 0,     NE_B0 = 704,   NE_T1 = 768,   NE_B1 = 4864,  NE_T2 = 4928,  NE_B2 = 9024,
    EE_T0 = 9088,  EE_B0 = 9280,  EE_T1 = 9344,  EE_B1 = 13440, EE_T2 = 13504, EE_B2 = 17600,
    MP_T0 = 17664, MP_B0 = 42240, LNW_O = 42624, LNB_O = 43008, MP_T1 = 43392, MP_B1 = 67968,
    PI_T0 = 68160, PI_B0 = 72256, PI_T1 = 72320, PI_B1 = 76416, PI_W2 = 76480, PI_B2 = 76608,
    W_TOTAL = 76610
};

// fragment-buffer layer bases (frag id; 512 bf16 per frag)
enum : int {
    FR_EE1 = 0, FR_EE2 = 4, FR_EE3 = 12, FR_NE1 = 20, FR_NE2 = 24, FR_NE3 = 32,
    FR_MP0 = 40, FR_MP1 = 88, FR_PI0 = 136, FR_PI1 = 144, FR_TOTAL = 152
};

// ---------------- workspace layout (bytes) ----------------
#define OFF_W       ((size_t)0)
#define OFF_FLAG    ((size_t)0x60000)
#define OFF_WB      ((size_t)0x61000)      // 152*512*2 = 155648 B
#define OFF_X0      ((size_t)0x90000)
#define OFF_X1      ((size_t)0x00D00000)
#define OFF_H64     ((size_t)0x01A00000)
#define OFF_E       ((size_t)0x02700000)   // ebuf: 800k x 64 bf16 = 102.4 MB
#define OFF_ROWPTR  ((size_t)0x08900000)
#define OFF_CURSOR  ((size_t)0x08940000)
#define OFF_PERM    ((size_t)0x08980000)
#define OFF_SRCS    ((size_t)0x08D00000)
#define OFF_BSUM    ((size_t)0x09100000)

struct Ptrs24 { const void* p[24]; };

// ---------------- setup kernels ----------------

__global__ void detect_kernel(const void* nf, int* flag) {
    u32 w = ((const u32*)nf)[threadIdx.x & 63];
    u32 lo = w & 0xffffu;
    int e = (int)((lo >> 7) & 0xff);
    int good = ((e >= 118 && e <= 132) || lo == 0) ? 1 : 0;
    unsigned long long b = __ballot(good != 0);
    if (threadIdx.x == 0) *flag = (__popcll(b) >= 48) ? 1 : 0;
}

__global__ void convert_weights(Ptrs24 ps, float* __restrict__ W, const int* flag) {
    const int segIN[24] = {11,64,64,64,64,64, 3,64,64,64,64,64, 64,384,384,384,128,192, 64,64,64,64,128,2};
    const int segOUT[24]= {64, 1,64, 1,64, 1, 64, 1,64, 1,64, 1, 128, 1,  1,  1, 64,  1, 64, 1,64, 1,  1,1};
    const int segS[24]  = { 1, 1, 1, 1, 1, 1,  1, 1, 1, 1, 1, 1,   3, 1,  1,  1,  3,  1,  1, 1, 1, 1,  1,1};
    const int segTR[24] = { 1, 0, 1, 0, 1, 0,  1, 0, 1, 0, 1, 0,   1, 0,  0,  0,  1,  0,  1, 0, 1, 0,  0,0};
    int t = blockIdx.x * blockDim.x + threadIdx.x;
    if (t >= W_TOTAL) return;
    bool bf = (*flag != 0);
    int seg = 0, off = t;
    for (;;) {
        int cnt = segIN[seg] * segOUT[seg] * segS[seg];
        if (off < cnt) break;
        off -= cnt; seg++;
    }
    int srcIdx;
    if (segTR[seg]) {
        int per = segIN[seg] * segOUT[seg];
        int s = off / per, d = off % per;
        int j = d / segOUT[seg], i = d % segOUT[seg];
        srcIdx = s * per + i * segIN[seg] + j;
    } else {
        srcIdx = off;
    }
    const void* p = ps.p[seg];
    W[t] = bf ? b2f(((const u16*)p)[srcIdx]) : ((const float*)p)[srcIdx];
}

// bake bf16 MFMA A-operand fragments: frag(lane,j) = W_T[kt*32+(lane>>4)*8+j][nt*16+(lane&15)]
__global__ void make_frags(const float* __restrict__ W, u16* __restrict__ Wb) {
    const int base[15] = {FR_EE1,FR_EE2,FR_EE3,FR_NE1,FR_NE2,FR_NE3,
                          FR_MP0,FR_MP0+16,FR_MP0+32, FR_MP1,FR_MP1+16,FR_MP1+32,
                          FR_PI0,FR_PI1,FR_TOTAL};
    const int woff[14] = {EE_T0,EE_T1,EE_T2, NE_T0,NE_T1,NE_T2,
                          MP_T0,MP_T0+8192,MP_T0+16384, MP_T1,MP_T1+8192,MP_T1+16384,
                          PI_T0,PI_T1};
    const int kreal[14] = {3,64,64, 11,64,64, 64,64,64, 128,128,128, 64,64};
    const int nn[14]    = {64,64,64, 64,64,64, 128,128,128, 64,64,64, 64,64};
    int t = blockIdx.x * blockDim.x + threadIdx.x;
    if (t >= FR_TOTAL * 512) return;
    int f = t >> 9, r = t & 511, lane = r >> 3, j = r & 7;
    int l = 0;
    while (f >= base[l + 1]) l++;
    int lf = f - base[l];
    int NT = nn[l] >> 4;
    int kt = lf / NT, nt = lf % NT;
    int k = kt * 32 + (lane >> 4) * 8 + j;
    int n = nt * 16 + (lane & 15);
    float v = (k < kreal[l]) ? W[woff[l] + k * nn[l] + n] : 0.f;
    Wb[t] = f2b(v);
}

// ---------------- graph build ----------------

__global__ void hist_kernel(const int* __restrict__ dst, int* __restrict__ rowptr) {
    int e = blockIdx.x * blockDim.x + threadIdx.x;
    if (e < N_EDGES) atomicAdd(&rowptr[dst[e] + 1], 1);
}

// 3-phase scan over rowptr[0..N_NODES]
__global__ void scanA(int* __restrict__ rowptr, int* __restrict__ bsum) {
    __shared__ int wsum[16];
    int tid = threadIdx.x, lane = tid & 63, wid = tid >> 6;
    int i0 = blockIdx.x * 2048 + tid * 2;
    int v0 = (i0 <= N_NODES) ? rowptr[i0] : 0;
    int v1 = (i0 + 1 <= N_NODES) ? rowptr[i0 + 1] : 0;
    int v = v0 + v1;
#pragma unroll
    for (int off = 1; off < 64; off <<= 1) {
        int t = __shfl_up(v, off, 64);
        if (lane >= off) v += t;
    }
    if (lane == 63) wsum[wid] = v;
    __syncthreads();
    if (tid == 0) { int a = 0; for (int w = 0; w < 16; w++) { a += wsum[w]; wsum[w] = a; } }
    __syncthreads();
    int incl = v + (wid ? wsum[wid - 1] : 0);
    if (i0 <= N_NODES) rowptr[i0] = incl - v1;
    if (i0 + 1 <= N_NODES) rowptr[i0 + 1] = incl;
    if (tid == 1023) bsum[blockIdx.x] = incl;
}
__global__ void scanB(int* __restrict__ bsum, int nb) {
    int lane = threadIdx.x;
    int v = (lane < nb) ? bsum[lane] : 0;
#pragma unroll
    for (int off = 1; off < 64; off <<= 1) {
        int t = __shfl_up(v, off, 64);
        if (lane >= off) v += t;
    }
    if (lane < nb) bsum[lane] = v;
}
__global__ void scanC(const int* __restrict__ bsum, int* __restrict__ rowptr,
                      int* __restrict__ cursor) {
    int i = blockIdx.x * 1024 + threadIdx.x;
    if (i > N_NODES) return;
    int b = i >> 11;
    int v = rowptr[i] + (b ? bsum[b - 1] : 0);
    rowptr[i] = v;
    if (i < N_NODES) cursor[i] = v;
}

__global__ void scatter_kernel(const int* __restrict__ dst, const int* __restrict__ src,
                               int* __restrict__ cursor, int* __restrict__ perm,
                               int* __restrict__ srcs) {
    int e = blockIdx.x * blockDim.x + threadIdx.x;
    if (e >= N_EDGES) return;
    int p = atomicAdd(&cursor[dst[e]], 1);
    perm[e] = p;
    srcs[p] = src[e];
}

// ---------------- MFMA layer building blocks ----------------
// Orientation: D = Wfrag(A) x ActFrag(B) -> D[n'][m]: m = lane&15, n = nt*16 + (lane>>4)*4 + reg.
// Activation frag (B-op) element (lane,j) = X[m=lane&15][k = kt*32 + (lane>>4)*8 + j]
// -> ds_read_b128 of a contiguous bf16 row slice.

template<int KT, int NT, int INSTR>
__device__ __forceinline__ void mfma_layer(const u32* ldsin, int lane,
        const short8* __restrict__ Wf, int basef, const float* __restrict__ bias, f32x4* acc) {
    int q = lane >> 4, mr = lane & 15;
#pragma unroll
    for (int nt = 0; nt < NT; nt++) acc[nt] = *(const f32x4*)(bias + nt * 16 + q * 4);
#pragma unroll
    for (int kt = 0; kt < KT; kt++) {
        short8 act = *(const short8*)(ldsin + mr * INSTR + kt * 16 + q * 4);
#pragma unroll
        for (int nt = 0; nt < NT; nt++)
            acc[nt] = mfma16(Wf[(basef + kt * NT + nt) * 64 + lane], act, acc[nt]);
    }
}

template<int KT, int NT>
__device__ __forceinline__ void mfma_layer_reg(const short8* act, int lane,
        const short8* __restrict__ Wf, int basef, const float* __restrict__ bias, f32x4* acc) {
    int q = lane >> 4;
#pragma unroll
    for (int nt = 0; nt < NT; nt++) acc[nt] = *(const f32x4*)(bias + nt * 16 + q * 4);
#pragma unroll
    for (int kt = 0; kt < KT; kt++)
#pragma unroll
        for (int nt = 0; nt < NT; nt++)
            acc[nt] = mfma16(Wf[(basef + kt * NT + nt) * 64 + lane], act[kt], acc[nt]);
}

template<int NT, int OUTSTR>
__device__ __forceinline__ void tanh_pack_lds(const f32x4* acc, u32* ldsout, int lane) {
    int q = lane >> 4, mr = lane & 15;
#pragma unroll
    for (int nt = 0; nt < NT; nt++) {
        f32x4 a = acc[nt];
        ldsout[mr * OUTSTR + nt * 8 + q * 2 + 0] = pack2(fast_tanh(a[0]), fast_tanh(a[1]));
        ldsout[mr * OUTSTR + nt * 8 + q * 2 + 1] = pack2(fast_tanh(a[2]), fast_tanh(a[3]));
    }
}

__device__ __forceinline__ short8 frag_from_gf32(const float* rowp, bool valid) {
    f32x4 a = {0.f,0.f,0.f,0.f}, b = {0.f,0.f,0.f,0.f};
    if (valid) { a = *(const f32x4*)rowp; b = *(const f32x4*)(rowp + 4); }
    u32x4 t;
    t.x = pack2(a[0], a[1]); t.y = pack2(a[2], a[3]);
    t.z = pack2(b[0], b[1]); t.w = pack2(b[2], b[3]);
    return __builtin_bit_cast(short8, t);
}

// ---------------- encoders / MLP / head (MFMA) ----------------

// per-wave LDS (dwords): bufI 16x20=320, bufA 16x36=576, bufB 576  -> 1472
__global__ __launch_bounds__(256) void edge_encoder(const void* ef, u32* __restrict__ ebuf,
        const int* __restrict__ perm, const float* __restrict__ W,
        const short8* __restrict__ Wf, const int* flag) {
    __shared__ u32 lds[4 * 1472];
    int wv = threadIdx.x >> 6, lane = threadIdx.x & 63;
    u32* bufI = lds + wv * 1472;
    u32* bufA = bufI + 320;
    u32* bufB = bufI + 896;
    long ebase = (long)blockIdx.x * 64 + wv * 16;
    bool bf = (*flag != 0);
    if (lane < 16) {
        long e = ebase + lane;
        float i0 = 0.f, i1 = 0.f, i2 = 0.f;
        if (e < N_EDGES) {
            if (bf) { const u16* p = (const u16*)ef + e * 3; i0 = b2f(p[0]); i1 = b2f(p[1]); i2 = b2f(p[2]); }
            else    { const float* p = (const float*)ef + e * 3; i0 = p[0]; i1 = p[1]; i2 = p[2]; }
        }
        u32* row = bufI + lane * 20;
        row[0] = pack2(i0, i1); row[1] = pack2(i2, 0.f);
#pragma unroll
        for (int d = 2; d < 16; d++) row[d] = 0;
    }
    __syncthreads();
    f32x4 acc[4];
    mfma_layer<1, 4, 20>(bufI, lane, Wf, FR_EE1, W + EE_B0, acc);
    tanh_pack_lds<4, 36>(acc, bufA, lane);
    __syncthreads();
    mfma_layer<2, 4, 36>(bufA, lane, Wf, FR_EE2, W + EE_B1, acc);
    tanh_pack_lds<4, 36>(acc, bufB, lane);
    __syncthreads();
    mfma_layer<2, 4, 36>(bufB, lane, Wf, FR_EE3, W + EE_B2, acc);
    tanh_pack_lds<4, 36>(acc, bufA, lane);
    __syncthreads();
    int ro = lane >> 2, cc = (lane & 3) * 8;
    long e = ebase + ro;
    if (e < N_EDGES) {
        long prow = perm[e];
        u32x4 v0 = *(const u32x4*)&bufA[ro * 36 + cc];
        u32x4 v1 = *(const u32x4*)&bufA[ro * 36 + cc + 4];
        *(u32x4*)&ebuf[prow * 32 + cc] = v0;
        *(u32x4*)&ebuf[prow * 32 + cc + 4] = v1;
    }
}

// per-wave LDS: bufI 320, bufA 576, bufB 576, bufF 16x68=1088 -> 2560 dwords
__global__ __launch_bounds__(256) void node_encoder(const void* nf, float* __restrict__ x,
        const float* __restrict__ W, const short8* __restrict__ Wf, const int* flag) {
    __shared__ u32 lds[4 * 2560];
    int wv = threadIdx.x >> 6, lane = threadIdx.x & 63;
    int q = lane >> 4, mr = lane & 15;
    u32* bufI = lds + wv * 2560;
    u32* bufA = bufI + 320;
    u32* bufB = bufI + 896;
    u32* bufF = bufI + 1472;
    long nbase = (long)blockIdx.x * 64 + wv * 16;
    bool bf = (*flag != 0);
    if (lane < 16) {
        long n = nbase + lane;
        float in[12];
#pragma unroll
        for (int j = 0; j < 12; j++) in[j] = 0.f;
        if (n < N_NODES) {
#pragma unroll
            for (int j = 0; j < 11; j++)
                in[j] = bf ? b2f(((const u16*)nf)[n * 11 + j]) : ((const float*)nf)[n * 11 + j];
        }
        u32* row = bufI + lane * 20;
#pragma unroll
        for (int d = 0; d < 6; d++) row[d] = pack2(in[2 * d], in[2 * d + 1]);
#pragma unroll
        for (int d = 6; d < 16; d++) row[d] = 0;
    }
    __syncthreads();
    f32x4 acc[4];
    mfma_layer<1, 4, 20>(bufI, lane, Wf, FR_NE1, W + NE_B0, acc);
    tanh_pack_lds<4, 36>(acc, bufA, lane);
    __syncthreads();
    mfma_layer<2, 4, 36>(bufA, lane, Wf, FR_NE2, W + NE_B1, acc);
    tanh_pack_lds<4, 36>(acc, bufB, lane);
    __syncthreads();
    mfma_layer<2, 4, 36>(bufB, lane, Wf, FR_NE3, W + NE_B2, acc);
#pragma unroll
    for (int nt = 0; nt < 4; nt++)
#pragma unroll
        for (int rr = 0; rr < 4; rr++) {
            float v = fast_tanh(acc[nt][rr]);
            bufF[mr * 68 + nt * 16 + q * 4 + rr] = *(u32*)&v;
        }
    __syncthreads();
    int ro = lane >> 2, c0 = (lane & 3) * 16;
    long n = nbase + ro;
    if (n < N_NODES) {
#pragma unroll
        for (int i = 0; i < 4; i++) {
            u32x4 v = *(const u32x4*)&bufF[ro * 68 + c0 + 4 * i];
            *(u32x4*)((u32*)x + n * 64 + c0 + 4 * i) = v;
        }
    }
}

// wave per node, lane = feature; ebuf/srcs stream contiguously, only x[s] gathers
__global__ __launch_bounds__(256) void aggregate_kernel(
        const float* __restrict__ x, const u16* __restrict__ ebuf,
        const int* __restrict__ srcs, const int* __restrict__ rowptr,
        float* __restrict__ h64) {
    int gw = (int)((blockIdx.x * 256 + threadIdx.x) >> 6);
    int lane = (int)(threadIdx.x & 63);
    if (gw >= N_NODES) return;
    int beg = rowptr[gw], end = rowptr[gw + 1];
    float num = 0.f, den = 0.f;
    int k = beg;
    for (; k + 1 < end; k += 2) {
        int s0 = srcs[k], s1 = srcs[k + 1];
        float e0 = b2f(ebuf[(long)k * 64 + lane]);
        float e1 = b2f(ebuf[(long)(k + 1) * 64 + lane]);
        float m0 = fmaxf(x[(long)s0 * 64 + lane] + e0, 0.f) + 1e-7f;
        float m1 = fmaxf(x[(long)s1 * 64 + lane] + e1, 0.f) + 1e-7f;
        float w0 = __expf(m0), w1 = __expf(m1);
        num = fmaf(w0, m0, num); den += w0;
        num = fmaf(w1, m1, num); den += w1;
    }
    if (k < end) {
        int s0 = srcs[k];
        float m0 = fmaxf(x[(long)s0 * 64 + lane] + b2f(ebuf[(long)k * 64 + lane]), 0.f) + 1e-7f;
        float w0 = __expf(m0);
        num = fmaf(w0, m0, num); den += w0;
    }
    float agg = (den > 0.f) ? __fdividef(num, den) : 0.f;
    h64[(long)gw * 64 + lane] = x[(long)gw * 64 + lane] + agg;
}

// fused node MLP: 64->128, LayerNorm (shuffle-reduced), ReLU, 128->64
// per-wave LDS: bufY 16x68=1088, bufO 1088 -> 2176 dwords
__global__ __launch_bounds__(256) void mlp_fused(const float* __restrict__ h64,
        float* __restrict__ xout, const float* __restrict__ W,
        const short8* __restrict__ Wf, int r) {
    __shared__ u32 lds[4 * 2176];
    int wv = threadIdx.x >> 6, lane = threadIdx.x & 63;
    int q = lane >> 4, mr = lane & 15;
    u32* bufY = lds + wv * 2176;
    u32* bufO = bufY + 1088;
    long nbase = (long)blockIdx.x * 64 + wv * 16;
    long row = nbase + mr;
    short8 act[2];
#pragma unroll
    for (int kt = 0; kt < 2; kt++)
        act[kt] = frag_from_gf32(h64 + row * 64 + kt * 32 + q * 8, row < N_NODES);
    f32x4 acc[8];
    mfma_layer_reg<2, 8>(act, lane, Wf, FR_MP0 + r * 16, W + MP_B0 + r * 128, acc);
    // LayerNorm over n=128 for row m: lane holds 32 values; combine 4 quads via shfl_xor
    float s = 0.f, sq = 0.f;
#pragma unroll
    for (int nt = 0; nt < 8; nt++)
#pragma unroll
        for (int rr = 0; rr < 4; rr++) { float v = acc[nt][rr]; s += v; sq = fmaf(v, v, sq); }
    s += __shfl_xor(s, 16, 64);  s += __shfl_xor(s, 32, 64);
    sq += __shfl_xor(sq, 16, 64); sq += __shfl_xor(sq, 32, 64);
    float mu = s * (1.f / 128.f);
    float var = sq * (1.f / 128.f) - mu * mu;
    float inv = rsqrtf(var + 1e-5f);
    const float* LW = W + LNW_O + r * 128;
    const float* LB = W + LNB_O + r * 128;
#pragma unroll
    for (int nt = 0; nt < 8; nt++) {
        f32x4 lw = *(const f32x4*)(LW + nt * 16 + q * 4);
        f32x4 lb = *(const f32x4*)(LB + nt * 16 + q * 4);
        float u0 = fmaxf(fmaf((acc[nt][0] - mu) * inv, lw[0], lb[0]), 0.f);
        float u1 = fmaxf(fmaf((acc[nt][1] - mu) * inv, lw[1], lb[1]), 0.f);
        float u2 = fmaxf(fmaf((acc[nt][2] - mu) * inv, lw[2], lb[2]), 0.f);
        float u3 = fmaxf(fmaf((acc[nt][3] - mu) * inv, lw[3], lb[3]), 0.f);
        bufY[mr * 68 + nt * 8 + q * 2 + 0] = pack2(u0, u1);
        bufY[mr * 68 + nt * 8 + q * 2 + 1] = pack2(u2, u3);
    }
    __syncthreads();
    f32x4 acc2[4];
    mfma_layer<4, 4, 68>(bufY, lane, Wf, FR_MP1 + r * 16, W + MP_B1 + r * 64, acc2);
#pragma unroll
    for (int nt = 0; nt < 4; nt++)
#pragma unroll
        for (int rr = 0; rr < 4; rr++) {
            float v = acc2[nt][rr];
            bufO[mr * 68 + nt * 16 + q * 4 + rr] = *(u32*)&v;
        }
    __syncthreads();
    int ro = lane >> 2, c0 = (lane & 3) * 16;
    long orow = nbase + ro;
    if (orow < N_NODES) {
#pragma unroll
        for (int i = 0; i < 4; i++) {
            u32x4 v = *(const u32x4*)&bufO[ro * 68 + c0 + 4 * i];
            *(u32x4*)((u32*)xout + orow * 64 + c0 + 4 * i) = v;
        }
    }
}

// per-wave LDS: bufY 576 dwords
__global__ __launch_bounds__(256) void policy_head(const float* __restrict__ x, void* out,
        const float* __restrict__ W, const short8* __restrict__ Wf, const int* flag) {
    __shared__ u32 lds[4 * 576];
    int wv = threadIdx.x >> 6, lane = threadIdx.x & 63;
    int q = lane >> 4, mr = lane & 15;
    u32* bufY = lds + wv * 576;
    long nbase = (long)blockIdx.x * 64 + wv * 16;
    long row = nbase + mr;
    bool bf = (*flag != 0);
    short8 act[2];
#pragma unroll
    for (int kt = 0; kt < 2; kt++)
        act[kt] = frag_from_gf32(x + row * 64 + kt * 32 + q * 8, row < N_NODES);
    f32x4 acc[4];
    mfma_layer_reg<2, 4>(act, lane, Wf, FR_PI0, W + PI_B0, acc);
    tanh_pack_lds<4, 36>(acc, bufY, lane);
    __syncthreads();
    mfma_layer<2, 4, 36>(bufY, lane, Wf, FR_PI1, W + PI_B1, acc);
    float o = 0.f;
#pragma unroll
    for (int nt = 0; nt < 4; nt++) {
        f32x4 w2 = *(const f32x4*)(W + PI_W2 + nt * 16 + q * 4);
#pragma unroll
        for (int rr = 0; rr < 4; rr++) o = fmaf(fast_tanh(acc[nt][rr]), w2[rr], o);
    }
    o += __shfl_xor(o, 16, 64);
    o += __shfl_xor(o, 32, 64);
    if (lane < 16 && row < N_NODES) {
        float means = 30.f * (o + W[PI_B2]);
        if (bf) ((u16*)out)[row] = f2b(means);
        else    ((float*)out)[row] = means;
    }
}

// ---------------- launch ----------------
extern "C" void kernel_launch(void* const* d_in, const int* in_sizes, int n_in,
                              void* d_out, int out_size, void* d_ws, size_t ws_size,
                              hipStream_t stream) {
    char* ws = (char*)d_ws;
    float* W      = (float*)(ws + OFF_W);
    int*   flag   = (int*)(ws + OFF_FLAG);
    u16*   Wb     = (u16*)(ws + OFF_WB);
    const short8* Wf = (const short8*)(ws + OFF_WB);
    float* x0     = (float*)(ws + OFF_X0);
    float* x1     = (float*)(ws + OFF_X1);
    float* h64    = (float*)(ws + OFF_H64);
    u32*   ebuf32 = (u32*)(ws + OFF_E);
    u16*   ebuf16 = (u16*)(ws + OFF_E);
    int*   rowptr = (int*)(ws + OFF_ROWPTR);
    int*   cursor = (int*)(ws + OFF_CURSOR);
    int*   perm   = (int*)(ws + OFF_PERM);
    int*   srcs   = (int*)(ws + OFF_SRCS);
    int*   bsum   = (int*)(ws + OFF_BSUM);

    const int* ei   = (const int*)d_in[2];
    const int* srcv = ei;
    const int* dstv = ei + N_EDGES;

    detect_kernel<<<1, 64, 0, stream>>>(d_in[0], flag);
    hipMemsetAsync(rowptr, 0, (N_NODES + 1) * sizeof(int), stream);

    Ptrs24 ps;
    for (int k = 0; k < 24; k++) ps.p[k] = d_in[3 + k];
    convert_weights<<<(W_TOTAL + 255) / 256, 256, 0, stream>>>(ps, W, flag);
    make_frags<<<(FR_TOTAL * 512 + 255) / 256, 256, 0, stream>>>(W, Wb);

    hist_kernel<<<(N_EDGES + 255) / 256, 256, 0, stream>>>(dstv, rowptr);
    scanA<<<25, 1024, 0, stream>>>(rowptr, bsum);
    scanB<<<1, 64, 0, stream>>>(bsum, 25);
    scanC<<<(N_NODES + 1024) / 1024, 1024, 0, stream>>>(bsum, rowptr, cursor);
    scatter_kernel<<<(N_EDGES + 255) / 256, 256, 0, stream>>>(dstv, srcv, cursor, perm, srcs);

    node_encoder<<<(N_NODES + 63) / 64, 256, 0, stream>>>(d_in[0], x0, W, Wf, flag);
    edge_encoder<<<(N_EDGES + 63) / 64, 256, 0, stream>>>(d_in[1], ebuf32, perm, W, Wf, flag);

    float* xc = x0; float* xn = x1;
    for (int r = 0; r < 3; r++) {
        aggregate_kernel<<<(N_NODES * 64 + 255) / 256, 256, 0, stream>>>(xc, ebuf16, srcs, rowptr, h64);
        mlp_fused<<<(N_NODES + 63) / 64, 256, 0, stream>>>(h64, xn, W, Wf, r);
        float* t = xc; xc = xn; xn = t;
    }
    policy_head<<<(N_NODES + 63) / 64, 256, 0, stream>>>(xc, d_out, W, Wf, flag);
}

// Round 4
// 481.091 us; speedup vs baseline: 4.2413x; 1.1602x over previous
//
#include <hip/hip_runtime.h>
#include <stdint.h>

#define N_NODES 50000
#define N_EDGES 800000

typedef unsigned short u16;
typedef unsigned int u32;
typedef __attribute__((ext_vector_type(8))) short short8;   // 8 bf16 = A/B frag
typedef __attribute__((ext_vector_type(4))) float f32x4;    // C/D frag
typedef __attribute__((ext_vector_type(4))) u32 u32x4;
typedef __attribute__((ext_vector_type(2))) u32 u32x2;

// wave-private LDS exchange: writes committed (lgkmcnt==0) before reads issue.
// All LDS buffers below are per-wave slices, so no s_barrier is needed.
#define WAVE_SYNC() asm volatile("s_waitcnt lgkmcnt(0)" ::: "memory")

// ---------------- helpers ----------------
__device__ __forceinline__ float b2f(u16 v) {
    u32 u = ((u32)v) << 16; float f; __builtin_memcpy(&f, &u, 4); return f;
}
// round-half-up bf16 (2 ops); tie bias negligible, no overflow for |x| < 3e38
__device__ __forceinline__ u16 f2b(float f) {
    u32 u; __builtin_memcpy(&u, &f, 4);
    return (u16)((u + 0x8000u) >> 16);
}
__device__ __forceinline__ u32 pack2(float a, float b) {
    u32 ua, ub; __builtin_memcpy(&ua, &a, 4); __builtin_memcpy(&ub, &b, 4);
    return ((ua + 0x8000u) >> 16) | ((ub + 0x8000u) & 0xffff0000u);
}
__device__ __forceinline__ float fast_tanh(float x) {
    float e = __expf(2.f * x);
    return 1.f - __fdividef(2.f, e + 1.f);
}
__device__ __forceinline__ f32x4 mfma16(short8 a, short8 b, f32x4 c) {
    return __builtin_amdgcn_mfma_f32_16x16x32_bf16(a, b, c, 0, 0, 0);
}

// ---------------- f32 weight layout (transposed to [in][out]) ----------------
enum : int {
    NE_T0 = 0,     NE_B0 = 704,   NE_T1 = 768,   NE_B1 = 4864,  NE_T2 = 4928,  NE_B2 = 9024,
    EE_T0 = 9088,  EE_B0 = 9280,  EE_T1 = 9344,  EE_B1 = 13440, EE_T2 = 13504, EE_B2 = 17600,
    MP_T0 = 17664, MP_B0 = 42240, LNW_O = 42624, LNB_O = 43008, MP_T1 = 43392, MP_B1 = 67968,
    PI_T0 = 68160, PI_B0 = 72256, PI_T1 = 72320, PI_B1 = 76416, PI_W2 = 76480, PI_B2 = 76608,
    W_TOTAL = 76610
};

// fragment-buffer layer bases (frag id; 512 bf16 per frag)
enum : int {
    FR_EE1 = 0, FR_EE2 = 4, FR_EE3 = 12, FR_NE1 = 20, FR_NE2 = 24, FR_NE3 = 32,
    FR_MP0 = 40, FR_MP1 = 88, FR_PI0 = 136, FR_PI1 = 144, FR_TOTAL = 152
};

// ---------------- workspace layout (bytes) ----------------
#define OFF_W       ((size_t)0)
#define OFF_FLAG    ((size_t)0x60000)
#define OFF_WB      ((size_t)0x61000)      // 152*512*2 = 155648 B
#define OFF_X0      ((size_t)0x90000)      // 12.8 MB f32
#define OFF_X1      ((size_t)0x00D00000)   // 12.8 MB f32
#define OFF_H64B    ((size_t)0x01A00000)   // 6.4 MB bf16
#define OFF_XB0     ((size_t)0x02080000)   // 6.4 MB bf16
#define OFF_E       ((size_t)0x02700000)   // ebuf: 800k x 64 bf16 = 102.4 MB
#define OFF_ROWPTR  ((size_t)0x08900000)
#define OFF_CURSOR  ((size_t)0x08940000)
#define OFF_PERM    ((size_t)0x08980000)
#define OFF_SRCS    ((size_t)0x08D00000)
#define OFF_BSUM    ((size_t)0x09080000)
#define OFF_XB1     ((size_t)0x09100000)   // 6.4 MB bf16

struct Ptrs24 { const void* p[24]; };

// ---------------- setup kernels ----------------

__global__ void detect_kernel(const void* nf, int* flag) {
    u32 w = ((const u32*)nf)[threadIdx.x & 63];
    u32 lo = w & 0xffffu;
    int e = (int)((lo >> 7) & 0xff);
    int good = ((e >= 118 && e <= 132) || lo == 0) ? 1 : 0;
    unsigned long long b = __ballot(good != 0);
    if (threadIdx.x == 0) *flag = (__popcll(b) >= 48) ? 1 : 0;
}

__global__ void convert_weights(Ptrs24 ps, float* __restrict__ W, const int* flag) {
    const int segIN[24] = {11,64,64,64,64,64, 3,64,64,64,64,64, 64,384,384,384,128,192, 64,64,64,64,128,2};
    const int segOUT[24]= {64, 1,64, 1,64, 1, 64, 1,64, 1,64, 1, 128, 1,  1,  1, 64,  1, 64, 1,64, 1,  1,1};
    const int segS[24]  = { 1, 1, 1, 1, 1, 1,  1, 1, 1, 1, 1, 1,   3, 1,  1,  1,  3,  1,  1, 1, 1, 1,  1,1};
    const int segTR[24] = { 1, 0, 1, 0, 1, 0,  1, 0, 1, 0, 1, 0,   1, 0,  0,  0,  1,  0,  1, 0, 1, 0,  0,0};
    int t = blockIdx.x * blockDim.x + threadIdx.x;
    if (t >= W_TOTAL) return;
    bool bf = (*flag != 0);
    int seg = 0, off = t;
    for (;;) {
        int cnt = segIN[seg] * segOUT[seg] * segS[seg];
        if (off < cnt) break;
        off -= cnt; seg++;
    }
    int srcIdx;
    if (segTR[seg]) {
        int per = segIN[seg] * segOUT[seg];
        int s = off / per, d = off % per;
        int j = d / segOUT[seg], i = d % segOUT[seg];
        srcIdx = s * per + i * segIN[seg] + j;
    } else {
        srcIdx = off;
    }
    const void* p = ps.p[seg];
    W[t] = bf ? b2f(((const u16*)p)[srcIdx]) : ((const float*)p)[srcIdx];
}

// bake bf16 MFMA A-operand fragments: frag(lane,j) = W_T[kt*32+(lane>>4)*8+j][nt*16+(lane&15)]
__global__ void make_frags(const float* __restrict__ W, u16* __restrict__ Wb) {
    const int base[15] = {FR_EE1,FR_EE2,FR_EE3,FR_NE1,FR_NE2,FR_NE3,
                          FR_MP0,FR_MP0+16,FR_MP0+32, FR_MP1,FR_MP1+16,FR_MP1+32,
                          FR_PI0,FR_PI1,FR_TOTAL};
    const int woff[14] = {EE_T0,EE_T1,EE_T2, NE_T0,NE_T1,NE_T2,
                          MP_T0,MP_T0+8192,MP_T0+16384, MP_T1,MP_T1+8192,MP_T1+16384,
                          PI_T0,PI_T1};
    const int kreal[14] = {3,64,64, 11,64,64, 64,64,64, 128,128,128, 64,64};
    const int nn[14]    = {64,64,64, 64,64,64, 128,128,128, 64,64,64, 64,64};
    int t = blockIdx.x * blockDim.x + threadIdx.x;
    if (t >= FR_TOTAL * 512) return;
    int f = t >> 9, r = t & 511, lane = r >> 3, j = r & 7;
    int l = 0;
    while (f >= base[l + 1]) l++;
    int lf = f - base[l];
    int NT = nn[l] >> 4;
    int kt = lf / NT, nt = lf % NT;
    int k = kt * 32 + (lane >> 4) * 8 + j;
    int n = nt * 16 + (lane & 15);
    float v = (k < kreal[l]) ? W[woff[l] + k * nn[l] + n] : 0.f;
    Wb[t] = f2b(v);
}

// ---------------- graph build ----------------

__global__ void hist_kernel(const int* __restrict__ dst, int* __restrict__ rowptr) {
    int e = blockIdx.x * blockDim.x + threadIdx.x;
    if (e < N_EDGES) atomicAdd(&rowptr[dst[e] + 1], 1);
}

__global__ void scanA(int* __restrict__ rowptr, int* __restrict__ bsum) {
    __shared__ int wsum[16];
    int tid = threadIdx.x, lane = tid & 63, wid = tid >> 6;
    int i0 = blockIdx.x * 2048 + tid * 2;
    int v0 = (i0 <= N_NODES) ? rowptr[i0] : 0;
    int v1 = (i0 + 1 <= N_NODES) ? rowptr[i0 + 1] : 0;
    int v = v0 + v1;
#pragma unroll
    for (int off = 1; off < 64; off <<= 1) {
        int t = __shfl_up(v, off, 64);
        if (lane >= off) v += t;
    }
    if (lane == 63) wsum[wid] = v;
    __syncthreads();
    if (tid == 0) { int a = 0; for (int w = 0; w < 16; w++) { a += wsum[w]; wsum[w] = a; } }
    __syncthreads();
    int incl = v + (wid ? wsum[wid - 1] : 0);
    if (i0 <= N_NODES) rowptr[i0] = incl - v1;
    if (i0 + 1 <= N_NODES) rowptr[i0 + 1] = incl;
    if (tid == 1023) bsum[blockIdx.x] = incl;
}
__global__ void scanB(int* __restrict__ bsum, int nb) {
    int lane = threadIdx.x;
    int v = (lane < nb) ? bsum[lane] : 0;
#pragma unroll
    for (int off = 1; off < 64; off <<= 1) {
        int t = __shfl_up(v, off, 64);
        if (lane >= off) v += t;
    }
    if (lane < nb) bsum[lane] = v;
}
__global__ void scanC(const int* __restrict__ bsum, int* __restrict__ rowptr,
                      int* __restrict__ cursor) {
    int i = blockIdx.x * 1024 + threadIdx.x;
    if (i > N_NODES) return;
    int b = i >> 11;
    int v = rowptr[i] + (b ? bsum[b - 1] : 0);
    rowptr[i] = v;
    if (i < N_NODES) cursor[i] = v;
}

__global__ void scatter_kernel(const int* __restrict__ dst, const int* __restrict__ src,
                               int* __restrict__ cursor, int* __restrict__ perm,
                               int* __restrict__ srcs) {
    int e = blockIdx.x * blockDim.x + threadIdx.x;
    if (e >= N_EDGES) return;
    int p = atomicAdd(&cursor[dst[e]], 1);
    perm[e] = p;
    srcs[p] = src[e];
}

// ---------------- MFMA layer building blocks ----------------
// D = Wfrag(A) x ActFrag(B) -> D[n][m]: m = lane&15, n = nt*16 + (lane>>4)*4 + reg.
// Act B-frag (lane,j) = X[m=lane&15][k = kt*32 + (lane>>4)*8 + j] -> contiguous b128.

template<int KT, int NT, int INSTR>
__device__ __forceinline__ void mfma_layer(const u32* ldsin, int lane,
        const short8* __restrict__ Wf, int basef, const float* __restrict__ bias, f32x4* acc) {
    int q = lane >> 4, mr = lane & 15;
#pragma unroll
    for (int nt = 0; nt < NT; nt++) acc[nt] = *(const f32x4*)(bias + nt * 16 + q * 4);
#pragma unroll
    for (int kt = 0; kt < KT; kt++) {
        short8 act = *(const short8*)(ldsin + mr * INSTR + kt * 16 + q * 4);
#pragma unroll
        for (int nt = 0; nt < NT; nt++)
            acc[nt] = mfma16(Wf[(basef + kt * NT + nt) * 64 + lane], act, acc[nt]);
    }
}

template<int KT, int NT>
__device__ __forceinline__ void mfma_layer_reg(const short8* act, int lane,
        const short8* __restrict__ Wf, int basef, const float* __restrict__ bias, f32x4* acc) {
    int q = lane >> 4;
#pragma unroll
    for (int nt = 0; nt < NT; nt++) acc[nt] = *(const f32x4*)(bias + nt * 16 + q * 4);
#pragma unroll
    for (int kt = 0; kt < KT; kt++)
#pragma unroll
        for (int nt = 0; nt < NT; nt++)
            acc[nt] = mfma16(Wf[(basef + kt * NT + nt) * 64 + lane], act[kt], acc[nt]);
}

template<int NT, int OUTSTR>
__device__ __forceinline__ void tanh_pack_lds(const f32x4* acc, u32* ldsout, int lane) {
    int q = lane >> 4, mr = lane & 15;
#pragma unroll
    for (int nt = 0; nt < NT; nt++) {
        f32x4 a = acc[nt];
        ldsout[mr * OUTSTR + nt * 8 + q * 2 + 0] = pack2(fast_tanh(a[0]), fast_tanh(a[1]));
        ldsout[mr * OUTSTR + nt * 8 + q * 2 + 1] = pack2(fast_tanh(a[2]), fast_tanh(a[3]));
    }
}

// ---------------- encoders / MLP / head (MFMA, barrier-free) ----------------

// per-wave LDS: 2 ping-pong bufs of 16x36 dwords = 1152 dwords (4608 B)
__global__ __launch_bounds__(256) void edge_encoder(const void* ef, u32* __restrict__ ebuf,
        const int* __restrict__ perm, const float* __restrict__ W,
        const short8* __restrict__ Wf, const int* flag) {
    __shared__ u32 lds[4 * 1152];
    int wv = threadIdx.x >> 6, lane = threadIdx.x & 63;
    u32* B0 = lds + wv * 1152;
    u32* B1 = B0 + 576;
    long ebase = (long)blockIdx.x * 64 + wv * 16;
    bool bf = (*flag != 0);
    if (lane < 16) {
        long e = ebase + lane;   // N_EDGES % 64 == 0: always valid
        float i0, i1, i2;
        if (bf) { const u16* p = (const u16*)ef + e * 3; i0 = b2f(p[0]); i1 = b2f(p[1]); i2 = b2f(p[2]); }
        else    { const float* p = (const float*)ef + e * 3; i0 = p[0]; i1 = p[1]; i2 = p[2]; }
        u32* row = B0 + lane * 36;
        row[0] = pack2(i0, i1); row[1] = pack2(i2, 0.f);
#pragma unroll
        for (int d = 2; d < 16; d++) row[d] = 0;
    }
    WAVE_SYNC();
    f32x4 acc[4];
    mfma_layer<1, 4, 36>(B0, lane, Wf, FR_EE1, W + EE_B0, acc);
    tanh_pack_lds<4, 36>(acc, B1, lane);
    WAVE_SYNC();
    mfma_layer<2, 4, 36>(B1, lane, Wf, FR_EE2, W + EE_B1, acc);
    tanh_pack_lds<4, 36>(acc, B0, lane);
    WAVE_SYNC();
    mfma_layer<2, 4, 36>(B0, lane, Wf, FR_EE3, W + EE_B2, acc);
    tanh_pack_lds<4, 36>(acc, B1, lane);
    WAVE_SYNC();
    int ro = lane >> 2, cc = (lane & 3) * 8;
    long e = ebase + ro;
    long prow = perm[e];
    u32x4 v0 = *(const u32x4*)&B1[ro * 36 + cc];
    u32x4 v1 = *(const u32x4*)&B1[ro * 36 + cc + 4];
    *(u32x4*)&ebuf[prow * 32 + cc] = v0;
    *(u32x4*)&ebuf[prow * 32 + cc + 4] = v1;
}

// per-wave LDS: 2 bufs of 576 dwords; outputs stored direct from regs
__global__ __launch_bounds__(256) void node_encoder(const void* nf, float* __restrict__ x,
        u16* __restrict__ xbf, const float* __restrict__ W,
        const short8* __restrict__ Wf, const int* flag) {
    __shared__ u32 lds[4 * 1152];
    int wv = threadIdx.x >> 6, lane = threadIdx.x & 63;
    int q = lane >> 4, mr = lane & 15;
    u32* B0 = lds + wv * 1152;
    u32* B1 = B0 + 576;
    long nbase = (long)blockIdx.x * 64 + wv * 16;
    bool bf = (*flag != 0);
    if (lane < 16) {
        long n = nbase + lane;
        float in[12];
#pragma unroll
        for (int j = 0; j < 12; j++) in[j] = 0.f;
        if (n < N_NODES) {
#pragma unroll
            for (int j = 0; j < 11; j++)
                in[j] = bf ? b2f(((const u16*)nf)[n * 11 + j]) : ((const float*)nf)[n * 11 + j];
        }
        u32* row = B0 + lane * 36;
#pragma unroll
        for (int d = 0; d < 6; d++) row[d] = pack2(in[2 * d], in[2 * d + 1]);
#pragma unroll
        for (int d = 6; d < 16; d++) row[d] = 0;
    }
    WAVE_SYNC();
    f32x4 acc[4];
    mfma_layer<1, 4, 36>(B0, lane, Wf, FR_NE1, W + NE_B0, acc);
    tanh_pack_lds<4, 36>(acc, B1, lane);
    WAVE_SYNC();
    mfma_layer<2, 4, 36>(B1, lane, Wf, FR_NE2, W + NE_B1, acc);
    tanh_pack_lds<4, 36>(acc, B0, lane);
    WAVE_SYNC();
    mfma_layer<2, 4, 36>(B0, lane, Wf, FR_NE3, W + NE_B2, acc);
    long n = nbase + mr;
    if (n < N_NODES) {
#pragma unroll
        for (int nt = 0; nt < 4; nt++) {
            f32x4 v;
#pragma unroll
            for (int rr = 0; rr < 4; rr++) v[rr] = fast_tanh(acc[nt][rr]);
            *(f32x4*)(x + n * 64 + nt * 16 + q * 4) = v;
            u32x2 pb; pb.x = pack2(v[0], v[1]); pb.y = pack2(v[2], v[3]);
            *(u32x2*)&xbf[n * 64 + nt * 16 + q * 4] = pb;
        }
    }
}

// wave per node, lane = feature. srcs broadcast via one coalesced load + readlane;
// x gathered as bf16 (128 B rows); output bf16 (exactly what the MLP packs anyway).
__global__ __launch_bounds__(256) void aggregate_kernel(
        const float* __restrict__ x, const u16* __restrict__ xbf,
        const u16* __restrict__ ebuf, const int* __restrict__ srcs,
        const int* __restrict__ rowptr, u16* __restrict__ h64bf) {
    int gw = (int)((blockIdx.x * 256 + threadIdx.x) >> 6);
    int lane = (int)(threadIdx.x & 63);
    if (gw >= N_NODES) return;
    gw = __builtin_amdgcn_readfirstlane(gw);   // wave-uniform -> scalar control flow
    int beg = rowptr[gw], end = rowptr[gw + 1];
    int cnt = end - beg;
    float num = 0.f, den = 0.f;
    for (int base = 0; base < cnt; base += 64) {
        int m = cnt - base; if (m > 64) m = 64;
        int sk = (base + lane < cnt) ? srcs[beg + base + lane] : 0;
        const u16* ep = ebuf + (long)(beg + base) * 64 + lane;
        int kk = 0;
        for (; kk + 4 <= m; kk += 4) {
            int s0 = __shfl(sk, kk, 64), s1 = __shfl(sk, kk + 1, 64);
            int s2 = __shfl(sk, kk + 2, 64), s3 = __shfl(sk, kk + 3, 64);
            float xa0 = b2f(xbf[(long)s0 * 64 + lane]);
            float xa1 = b2f(xbf[(long)s1 * 64 + lane]);
            float xa2 = b2f(xbf[(long)s2 * 64 + lane]);
            float xa3 = b2f(xbf[(long)s3 * 64 + lane]);
            float e0 = b2f(ep[(long)kk * 64]);
            float e1 = b2f(ep[(long)(kk + 1) * 64]);
            float e2 = b2f(ep[(long)(kk + 2) * 64]);
            float e3 = b2f(ep[(long)(kk + 3) * 64]);
            float m0 = fmaxf(xa0 + e0, 0.f) + 1e-7f;
            float m1 = fmaxf(xa1 + e1, 0.f) + 1e-7f;
            float m2 = fmaxf(xa2 + e2, 0.f) + 1e-7f;
            float m3 = fmaxf(xa3 + e3, 0.f) + 1e-7f;
            float w0 = __expf(m0), w1 = __expf(m1), w2 = __expf(m2), w3 = __expf(m3);
            num = fmaf(w0, m0, num); den += w0;
            num = fmaf(w1, m1, num); den += w1;
            num = fmaf(w2, m2, num); den += w2;
            num = fmaf(w3, m3, num); den += w3;
        }
        for (; kk < m; kk++) {
            int s0 = __shfl(sk, kk, 64);
            float m0 = fmaxf(b2f(xbf[(long)s0 * 64 + lane]) + b2f(ep[(long)kk * 64]), 0.f) + 1e-7f;
            float w0 = __expf(m0);
            num = fmaf(w0, m0, num); den += w0;
        }
    }
    float agg = (den > 0.f) ? __fdividef(num, den) : 0.f;
    float h = x[(long)gw * 64 + lane] + agg;
    h64bf[(long)gw * 64 + lane] = f2b(h);
}

// fused node MLP: 64->128 (acts direct from h64bf), LN (shfl), ReLU, 128->64
// per-wave LDS: bufY 16x68 = 1088 dwords
__global__ __launch_bounds__(256) void mlp_fused(const u16* __restrict__ h64bf,
        float* __restrict__ xout, u16* __restrict__ xbf,
        const float* __restrict__ W, const short8* __restrict__ Wf, int r) {
    __shared__ u32 lds[4 * 1088];
    int wv = threadIdx.x >> 6, lane = threadIdx.x & 63;
    int q = lane >> 4, mr = lane & 15;
    u32* bufY = lds + wv * 1088;
    long nbase = (long)blockIdx.x * 64 + wv * 16;
    long row = nbase + mr;
    long rc = (row < N_NODES) ? row : (N_NODES - 1);
    short8 act[2];
#pragma unroll
    for (int kt = 0; kt < 2; kt++)
        act[kt] = *(const short8*)&h64bf[rc * 64 + kt * 32 + q * 8];
    f32x4 acc[8];
    mfma_layer_reg<2, 8>(act, lane, Wf, FR_MP0 + r * 16, W + MP_B0 + r * 128, acc);
    float s = 0.f, sq = 0.f;
#pragma unroll
    for (int nt = 0; nt < 8; nt++)
#pragma unroll
        for (int rr = 0; rr < 4; rr++) { float v = acc[nt][rr]; s += v; sq = fmaf(v, v, sq); }
    s += __shfl_xor(s, 16, 64);  s += __shfl_xor(s, 32, 64);
    sq += __shfl_xor(sq, 16, 64); sq += __shfl_xor(sq, 32, 64);
    float mu = s * (1.f / 128.f);
    float var = sq * (1.f / 128.f) - mu * mu;
    float inv = rsqrtf(var + 1e-5f);
    const float* LW = W + LNW_O + r * 128;
    const float* LB = W + LNB_O + r * 128;
#pragma unroll
    for (int nt = 0; nt < 8; nt++) {
        f32x4 lw = *(const f32x4*)(LW + nt * 16 + q * 4);
        f32x4 lb = *(const f32x4*)(LB + nt * 16 + q * 4);
        float u0 = fmaxf(fmaf((acc[nt][0] - mu) * inv, lw[0], lb[0]), 0.f);
        float u1 = fmaxf(fmaf((acc[nt][1] - mu) * inv, lw[1], lb[1]), 0.f);
        float u2 = fmaxf(fmaf((acc[nt][2] - mu) * inv, lw[2], lb[2]), 0.f);
        float u3 = fmaxf(fmaf((acc[nt][3] - mu) * inv, lw[3], lb[3]), 0.f);
        bufY[mr * 68 + nt * 8 + q * 2 + 0] = pack2(u0, u1);
        bufY[mr * 68 + nt * 8 + q * 2 + 1] = pack2(u2, u3);
    }
    WAVE_SYNC();
    f32x4 acc2[4];
    mfma_layer<4, 4, 68>(bufY, lane, Wf, FR_MP1 + r * 16, W + MP_B1 + r * 64, acc2);
    if (row < N_NODES) {
#pragma unroll
        for (int nt = 0; nt < 4; nt++) {
            f32x4 v = acc2[nt];
            *(f32x4*)(xout + row * 64 + nt * 16 + q * 4) = v;
            u32x2 pb; pb.x = pack2(v[0], v[1]); pb.y = pack2(v[2], v[3]);
            *(u32x2*)&xbf[row * 64 + nt * 16 + q * 4] = pb;
        }
    }
}

// per-wave LDS: bufY 576 dwords; acts direct from xbf
__global__ __launch_bounds__(256) void policy_head(const u16* __restrict__ xbf, void* out,
        const float* __restrict__ W, const short8* __restrict__ Wf, const int* flag) {
    __shared__ u32 lds[4 * 576];
    int wv = threadIdx.x >> 6, lane = threadIdx.x & 63;
    int q = lane >> 4, mr = lane & 15;
    u32* bufY = lds + wv * 576;
    long nbase = (long)blockIdx.x * 64 + wv * 16;
    long row = nbase + mr;
    long rc = (row < N_NODES) ? row : (N_NODES - 1);
    bool bf = (*flag != 0);
    short8 act[2];
#pragma unroll
    for (int kt = 0; kt < 2; kt++)
        act[kt] = *(const short8*)&xbf[rc * 64 + kt * 32 + q * 8];
    f32x4 acc[4];
    mfma_layer_reg<2, 4>(act, lane, Wf, FR_PI0, W + PI_B0, acc);
    tanh_pack_lds<4, 36>(acc, bufY, lane);
    WAVE_SYNC();
    mfma_layer<2, 4, 36>(bufY, lane, Wf, FR_PI1, W + PI_B1, acc);
    float o = 0.f;
#pragma unroll
    for (int nt = 0; nt < 4; nt++) {
        f32x4 w2 = *(const f32x4*)(W + PI_W2 + nt * 16 + q * 4);
#pragma unroll
        for (int rr = 0; rr < 4; rr++) o = fmaf(fast_tanh(acc[nt][rr]), w2[rr], o);
    }
    o += __shfl_xor(o, 16, 64);
    o += __shfl_xor(o, 32, 64);
    if (lane < 16 && row < N_NODES) {
        float means = 30.f * (o + W[PI_B2]);
        if (bf) ((u16*)out)[row] = f2b(means);
        else    ((float*)out)[row] = means;
    }
}

// ---------------- launch ----------------
extern "C" void kernel_launch(void* const* d_in, const int* in_sizes, int n_in,
                              void* d_out, int out_size, void* d_ws, size_t ws_size,
                              hipStream_t stream) {
    char* ws = (char*)d_ws;
    float* W      = (float*)(ws + OFF_W);
    int*   flag   = (int*)(ws + OFF_FLAG);
    u16*   Wb     = (u16*)(ws + OFF_WB);
    const short8* Wf = (const short8*)(ws + OFF_WB);
    float* x0     = (float*)(ws + OFF_X0);
    float* x1     = (float*)(ws + OFF_X1);
    u16*   xb0    = (u16*)(ws + OFF_XB0);
    u16*   xb1    = (u16*)(ws + OFF_XB1);
    u16*   h64bf  = (u16*)(ws + OFF_H64B);
    u32*   ebuf32 = (u32*)(ws + OFF_E);
    u16*   ebuf16 = (u16*)(ws + OFF_E);
    int*   rowptr = (int*)(ws + OFF_ROWPTR);
    int*   cursor = (int*)(ws + OFF_CURSOR);
    int*   perm   = (int*)(ws + OFF_PERM);
    int*   srcs   = (int*)(ws + OFF_SRCS);
    int*   bsum   = (int*)(ws + OFF_BSUM);

    const int* ei   = (const int*)d_in[2];
    const int* srcv = ei;
    const int* dstv = ei + N_EDGES;

    detect_kernel<<<1, 64, 0, stream>>>(d_in[0], flag);
    hipMemsetAsync(rowptr, 0, (N_NODES + 1) * sizeof(int), stream);

    Ptrs24 ps;
    for (int k = 0; k < 24; k++) ps.p[k] = d_in[3 + k];
    convert_weights<<<(W_TOTAL + 255) / 256, 256, 0, stream>>>(ps, W, flag);
    make_frags<<<(FR_TOTAL * 512 + 255) / 256, 256, 0, stream>>>(W, Wb);

    hist_kernel<<<(N_EDGES + 255) / 256, 256, 0, stream>>>(dstv, rowptr);
    scanA<<<25, 1024, 0, stream>>>(rowptr, bsum);
    scanB<<<1, 64, 0, stream>>>(bsum, 25);
    scanC<<<(N_NODES + 1024) / 1024, 1024, 0, stream>>>(bsum, rowptr, cursor);
    scatter_kernel<<<(N_EDGES + 255) / 256, 256, 0, stream>>>(dstv, srcv, cursor, perm, srcs);

    node_encoder<<<(N_NODES + 63) / 64, 256, 0, stream>>>(d_in[0], x0, xb0, W, Wf, flag);
    edge_encoder<<<N_EDGES / 64, 256, 0, stream>>>(d_in[1], ebuf32, perm, W, Wf, flag);

    float* xc = x0; float* xn = x1;
    u16* xbc = xb0; u16* xbn = xb1;
    for (int r = 0; r < 3; r++) {
        aggregate_kernel<<<(N_NODES * 64 + 255) / 256, 256, 0, stream>>>(xc, xbc, ebuf16, srcs, rowptr, h64bf);
        mlp_fused<<<(N_NODES + 63) / 64, 256, 0, stream>>>(h64bf, xn, xbn, W, Wf, r);
        float* t = xc; xc = xn; xn = t;
        u16* tb = xbc; xbc = xbn; xbn = tb;
    }
    policy_head<<<(N_NODES + 63) / 64, 256, 0, stream>>>(xbc, d_out, W, Wf, flag);
}

// Round 5
// 463.610 us; speedup vs baseline: 4.4012x; 1.0377x over previous
//
#include <hip/hip_runtime.h>
#include <stdint.h>

#define N_NODES 50000
#define N_EDGES 800000

typedef unsigned short u16;
typedef unsigned int u32;
typedef __attribute__((ext_vector_type(8))) short short8;   // 8 bf16 = A/B frag
typedef __attribute__((ext_vector_type(4))) float f32x4;    // C/D frag
typedef __attribute__((ext_vector_type(4))) u32 u32x4;
typedef __attribute__((ext_vector_type(2))) u32 u32x2;

// wave-private LDS exchange: writes committed (lgkmcnt==0) before reads issue.
#define WAVE_SYNC() asm volatile("s_waitcnt lgkmcnt(0)" ::: "memory")

// ---------------- helpers ----------------
__device__ __forceinline__ float b2f(u16 v) {
    u32 u = ((u32)v) << 16; float f; __builtin_memcpy(&f, &u, 4); return f;
}
__device__ __forceinline__ u16 f2b(float f) {
    u32 u; __builtin_memcpy(&u, &f, 4);
    return (u16)((u + 0x8000u) >> 16);
}
__device__ __forceinline__ float lo2f(u32 p) {
    u32 u = p << 16; float f; __builtin_memcpy(&f, &u, 4); return f;
}
__device__ __forceinline__ float hi2f(u32 p) {
    u32 u = p & 0xffff0000u; float f; __builtin_memcpy(&f, &u, 4); return f;
}
// pack two f32 -> two bf16 (round-half-up) in 3 ops via v_perm_b32
__device__ __forceinline__ u32 pack2(float a, float b) {
    u32 ua, ub; __builtin_memcpy(&ua, &a, 4); __builtin_memcpy(&ub, &b, 4);
    return __builtin_amdgcn_perm(ub + 0x8000u, ua + 0x8000u, 0x07060302u);
}
__device__ __forceinline__ f32x4 mfma16(short8 a, short8 b, f32x4 c) {
    return __builtin_amdgcn_mfma_f32_16x16x32_bf16(a, b, c, 0, 0, 0);
}

// ---- LUT tanh: 192 segments, step 1/32 over [0,6); y = fma(s, a, b~), sign restored.
// interp err <= 9.4e-5; tail (clamp at 5.97) err <= 1.3e-5.
#define TANH_TBL_N 192
__device__ __forceinline__ void build_tanh_tbl(float2* tbl) {
    int i = (int)threadIdx.x;
    if (i < TANH_TBL_N) {
        float x0 = i * 0.03125f, x1 = x0 + 0.03125f;
        float t0 = tanhf(x0), t1 = tanhf(x1);
        float s = (t1 - t0) * 32.f;
        tbl[i] = make_float2(fmaf(-s, x0, t0), s);   // b~ = t0 - s*x0
    }
    __syncthreads();
}
__device__ __forceinline__ float lut_tanh(const float2* __restrict__ tbl, float x) {
    float a = __builtin_fabsf(x);
    a = fminf(a, 5.96875f);
    int i = (int)(a * 32.f);
    float2 bs = tbl[i];
    float y = fmaf(bs.y, a, bs.x);
    u32 uy, ux; __builtin_memcpy(&uy, &y, 4); __builtin_memcpy(&ux, &x, 4);
    u32 r = (uy & 0x7fffffffu) | (ux & 0x80000000u);
    float o; __builtin_memcpy(&o, &r, 4); return o;
}

// ---------------- f32 weight layout (transposed to [in][out]) ----------------
enum : int {
    NE_T0 = 0,     NE_B0 = 704,   NE_T1 = 768,   NE_B1 = 4864,  NE_T2 = 4928,  NE_B2 = 9024,
    EE_T0 = 9088,  EE_B0 = 9280,  EE_T1 = 9344,  EE_B1 = 13440, EE_T2 = 13504, EE_B2 = 17600,
    MP_T0 = 17664, MP_B0 = 42240, LNW_O = 42624, LNB_O = 43008, MP_T1 = 43392, MP_B1 = 67968,
    PI_T0 = 68160, PI_B0 = 72256, PI_T1 = 72320, PI_B1 = 76416, PI_W2 = 76480, PI_B2 = 76608,
    W_TOTAL = 76610
};

// fragment-buffer layer bases (frag id; 512 bf16 per frag)
enum : int {
    FR_EE1 = 0, FR_EE2 = 4, FR_EE3 = 12, FR_NE1 = 20, FR_NE2 = 24, FR_NE3 = 32,
    FR_MP0 = 40, FR_MP1 = 88, FR_PI0 = 136, FR_PI1 = 144, FR_TOTAL = 152
};

// ---------------- workspace layout (bytes) ----------------
#define OFF_W       ((size_t)0)
#define OFF_FLAG    ((size_t)0x60000)
#define OFF_WB      ((size_t)0x61000)
#define OFF_X0      ((size_t)0x90000)      // 12.8 MB f32
#define OFF_X1      ((size_t)0x00D00000)   // 12.8 MB f32
#define OFF_H64B    ((size_t)0x01A00000)   // 6.4 MB bf16
#define OFF_XB0     ((size_t)0x02080000)   // 6.4 MB bf16
#define OFF_E       ((size_t)0x02700000)   // ebuf: 800k x 64 bf16 = 102.4 MB
#define OFF_ROWPTR  ((size_t)0x08900000)
#define OFF_CURSOR  ((size_t)0x08940000)
#define OFF_PERM    ((size_t)0x08980000)
#define OFF_SRCS    ((size_t)0x08D00000)
#define OFF_BSUM    ((size_t)0x09080000)
#define OFF_XB1     ((size_t)0x09100000)   // 6.4 MB bf16

struct Ptrs24 { const void* p[24]; };

// ---------------- setup kernels ----------------

__global__ void detect_kernel(const void* nf, int* flag) {
    u32 w = ((const u32*)nf)[threadIdx.x & 63];
    u32 lo = w & 0xffffu;
    int e = (int)((lo >> 7) & 0xff);
    int good = ((e >= 118 && e <= 132) || lo == 0) ? 1 : 0;
    unsigned long long b = __ballot(good != 0);
    if (threadIdx.x == 0) *flag = (__popcll(b) >= 48) ? 1 : 0;
}

__global__ void convert_weights(Ptrs24 ps, float* __restrict__ W, const int* flag) {
    const int segIN[24] = {11,64,64,64,64,64, 3,64,64,64,64,64, 64,384,384,384,128,192, 64,64,64,64,128,2};
    const int segOUT[24]= {64, 1,64, 1,64, 1, 64, 1,64, 1,64, 1, 128, 1,  1,  1, 64,  1, 64, 1,64, 1,  1,1};
    const int segS[24]  = { 1, 1, 1, 1, 1, 1,  1, 1, 1, 1, 1, 1,   3, 1,  1,  1,  3,  1,  1, 1, 1, 1,  1,1};
    const int segTR[24] = { 1, 0, 1, 0, 1, 0,  1, 0, 1, 0, 1, 0,   1, 0,  0,  0,  1,  0,  1, 0, 1, 0,  0,0};
    int t = blockIdx.x * blockDim.x + threadIdx.x;
    if (t >= W_TOTAL) return;
    bool bf = (*flag != 0);
    int seg = 0, off = t;
    for (;;) {
        int cnt = segIN[seg] * segOUT[seg] * segS[seg];
        if (off < cnt) break;
        off -= cnt; seg++;
    }
    int srcIdx;
    if (segTR[seg]) {
        int per = segIN[seg] * segOUT[seg];
        int s = off / per, d = off % per;
        int j = d / segOUT[seg], i = d % segOUT[seg];
        srcIdx = s * per + i * segIN[seg] + j;
    } else {
        srcIdx = off;
    }
    const void* p = ps.p[seg];
    W[t] = bf ? b2f(((const u16*)p)[srcIdx]) : ((const float*)p)[srcIdx];
}

__global__ void make_frags(const float* __restrict__ W, u16* __restrict__ Wb) {
    const int base[15] = {FR_EE1,FR_EE2,FR_EE3,FR_NE1,FR_NE2,FR_NE3,
                          FR_MP0,FR_MP0+16,FR_MP0+32, FR_MP1,FR_MP1+16,FR_MP1+32,
                          FR_PI0,FR_PI1,FR_TOTAL};
    const int woff[14] = {EE_T0,EE_T1,EE_T2, NE_T0,NE_T1,NE_T2,
                          MP_T0,MP_T0+8192,MP_T0+16384, MP_T1,MP_T1+8192,MP_T1+16384,
                          PI_T0,PI_T1};
    const int kreal[14] = {3,64,64, 11,64,64, 64,64,64, 128,128,128, 64,64};
    const int nn[14]    = {64,64,64, 64,64,64, 128,128,128, 64,64,64, 64,64};
    int t = blockIdx.x * blockDim.x + threadIdx.x;
    if (t >= FR_TOTAL * 512) return;
    int f = t >> 9, r = t & 511, lane = r >> 3, j = r & 7;
    int l = 0;
    while (f >= base[l + 1]) l++;
    int lf = f - base[l];
    int NT = nn[l] >> 4;
    int kt = lf / NT, nt = lf % NT;
    int k = kt * 32 + (lane >> 4) * 8 + j;
    int n = nt * 16 + (lane & 15);
    float v = (k < kreal[l]) ? W[woff[l] + k * nn[l] + n] : 0.f;
    u32 u; __builtin_memcpy(&u, &v, 4);
    Wb[t] = (u16)((u + 0x7fffu + ((u >> 16) & 1u)) >> 16);   // RNE for weights
}

// ---------------- graph build ----------------

__global__ void hist_kernel(const int* __restrict__ dst, int* __restrict__ rowptr) {
    int e = blockIdx.x * blockDim.x + threadIdx.x;
    if (e < N_EDGES) atomicAdd(&rowptr[dst[e] + 1], 1);
}

__global__ void scanA(int* __restrict__ rowptr, int* __restrict__ bsum) {
    __shared__ int wsum[16];
    int tid = threadIdx.x, lane = tid & 63, wid = tid >> 6;
    int i0 = blockIdx.x * 2048 + tid * 2;
    int v0 = (i0 <= N_NODES) ? rowptr[i0] : 0;
    int v1 = (i0 + 1 <= N_NODES) ? rowptr[i0 + 1] : 0;
    int v = v0 + v1;
#pragma unroll
    for (int off = 1; off < 64; off <<= 1) {
        int t = __shfl_up(v, off, 64);
        if (lane >= off) v += t;
    }
    if (lane == 63) wsum[wid] = v;
    __syncthreads();
    if (tid == 0) { int a = 0; for (int w = 0; w < 16; w++) { a += wsum[w]; wsum[w] = a; } }
    __syncthreads();
    int incl = v + (wid ? wsum[wid - 1] : 0);
    if (i0 <= N_NODES) rowptr[i0] = incl - v1;
    if (i0 + 1 <= N_NODES) rowptr[i0 + 1] = incl;
    if (tid == 1023) bsum[blockIdx.x] = incl;
}
__global__ void scanB(int* __restrict__ bsum, int nb) {
    int lane = threadIdx.x;
    int v = (lane < nb) ? bsum[lane] : 0;
#pragma unroll
    for (int off = 1; off < 64; off <<= 1) {
        int t = __shfl_up(v, off, 64);
        if (lane >= off) v += t;
    }
    if (lane < nb) bsum[lane] = v;
}
__global__ void scanC(const int* __restrict__ bsum, int* __restrict__ rowptr,
                      int* __restrict__ cursor) {
    int i = blockIdx.x * 1024 + threadIdx.x;
    if (i > N_NODES) return;
    int b = i >> 11;
    int v = rowptr[i] + (b ? bsum[b - 1] : 0);
    rowptr[i] = v;
    if (i < N_NODES) cursor[i] = v;
}

__global__ void scatter_kernel(const int* __restrict__ dst, const int* __restrict__ src,
                               int* __restrict__ cursor, int* __restrict__ perm,
                               int* __restrict__ srcs) {
    int e = blockIdx.x * blockDim.x + threadIdx.x;
    if (e >= N_EDGES) return;
    int p = atomicAdd(&cursor[dst[e]], 1);
    perm[e] = p;
    srcs[p] = src[e];
}

// ---------------- MFMA layer building blocks ----------------
// D = Wfrag(A) x ActFrag(B) -> D[n][m]: m = lane&15, n = nt*16 + (lane>>4)*4 + reg.
// Act B-frag (lane,j) = X[m=lane&15][k = kt*32 + (lane>>4)*8 + j] -> contiguous b128.

template<int KT, int NT, int INSTR>
__device__ __forceinline__ void mfma_layer(const u32* ldsin, int lane,
        const short8* __restrict__ Wf, int basef, const float* __restrict__ bias, f32x4* acc) {
    int q = lane >> 4, mr = lane & 15;
#pragma unroll
    for (int nt = 0; nt < NT; nt++) acc[nt] = *(const f32x4*)(bias + nt * 16 + q * 4);
#pragma unroll
    for (int kt = 0; kt < KT; kt++) {
        short8 act = *(const short8*)(ldsin + mr * INSTR + kt * 16 + q * 4);
#pragma unroll
        for (int nt = 0; nt < NT; nt++)
            acc[nt] = mfma16(Wf[(basef + kt * NT + nt) * 64 + lane], act, acc[nt]);
    }
}

template<int KT, int NT>
__device__ __forceinline__ void mfma_layer_reg(const short8* act, int lane,
        const short8* __restrict__ Wf, int basef, const float* __restrict__ bias, f32x4* acc) {
    int q = lane >> 4;
#pragma unroll
    for (int nt = 0; nt < NT; nt++) acc[nt] = *(const f32x4*)(bias + nt * 16 + q * 4);
#pragma unroll
    for (int kt = 0; kt < KT; kt++)
#pragma unroll
        for (int nt = 0; nt < NT; nt++)
            acc[nt] = mfma16(Wf[(basef + kt * NT + nt) * 64 + lane], act[kt], acc[nt]);
}

template<int NT, int OUTSTR>
__device__ __forceinline__ void tanh_pack_lds(const f32x4* acc, u32* ldsout, int lane,
                                              const float2* __restrict__ tbl) {
    int q = lane >> 4, mr = lane & 15;
#pragma unroll
    for (int nt = 0; nt < NT; nt++) {
        f32x4 a = acc[nt];
        ldsout[mr * OUTSTR + nt * 8 + q * 2 + 0] = pack2(lut_tanh(tbl, a[0]), lut_tanh(tbl, a[1]));
        ldsout[mr * OUTSTR + nt * 8 + q * 2 + 1] = pack2(lut_tanh(tbl, a[2]), lut_tanh(tbl, a[3]));
    }
}

// ---------------- encoders / MLP / head ----------------

__global__ __launch_bounds__(256) void edge_encoder(const void* ef, u32* __restrict__ ebuf,
        const int* __restrict__ perm, const float* __restrict__ W,
        const short8* __restrict__ Wf, const int* flag) {
    __shared__ u32 lds[4 * 1152];
    __shared__ float2 tbl[TANH_TBL_N];
    build_tanh_tbl(tbl);
    int wv = threadIdx.x >> 6, lane = threadIdx.x & 63;
    u32* B0 = lds + wv * 1152;
    u32* B1 = B0 + 576;
    long ebase = (long)blockIdx.x * 64 + wv * 16;
    bool bf = (*flag != 0);
    if (lane < 16) {
        long e = ebase + lane;   // N_EDGES % 64 == 0: always valid
        float i0, i1, i2;
        if (bf) { const u16* p = (const u16*)ef + e * 3; i0 = b2f(p[0]); i1 = b2f(p[1]); i2 = b2f(p[2]); }
        else    { const float* p = (const float*)ef + e * 3; i0 = p[0]; i1 = p[1]; i2 = p[2]; }
        u32* row = B0 + lane * 36;
        row[0] = pack2(i0, i1); row[1] = pack2(i2, 0.f);
#pragma unroll
        for (int d = 2; d < 16; d++) row[d] = 0;
    }
    WAVE_SYNC();
    f32x4 acc[4];
    mfma_layer<1, 4, 36>(B0, lane, Wf, FR_EE1, W + EE_B0, acc);
    tanh_pack_lds<4, 36>(acc, B1, lane, tbl);
    WAVE_SYNC();
    mfma_layer<2, 4, 36>(B1, lane, Wf, FR_EE2, W + EE_B1, acc);
    tanh_pack_lds<4, 36>(acc, B0, lane, tbl);
    WAVE_SYNC();
    mfma_layer<2, 4, 36>(B0, lane, Wf, FR_EE3, W + EE_B2, acc);
    tanh_pack_lds<4, 36>(acc, B1, lane, tbl);
    WAVE_SYNC();
    int ro = lane >> 2, cc = (lane & 3) * 8;
    long e = ebase + ro;
    long prow = perm[e];
    u32x4 v0 = *(const u32x4*)&B1[ro * 36 + cc];
    u32x4 v1 = *(const u32x4*)&B1[ro * 36 + cc + 4];
    *(u32x4*)&ebuf[prow * 32 + cc] = v0;
    *(u32x4*)&ebuf[prow * 32 + cc + 4] = v1;
}

__global__ __launch_bounds__(256) void node_encoder(const void* nf, float* __restrict__ x,
        u16* __restrict__ xbf, const float* __restrict__ W,
        const short8* __restrict__ Wf, const int* flag) {
    __shared__ u32 lds[4 * 1152];
    __shared__ float2 tbl[TANH_TBL_N];
    build_tanh_tbl(tbl);
    int wv = threadIdx.x >> 6, lane = threadIdx.x & 63;
    int q = lane >> 4, mr = lane & 15;
    u32* B0 = lds + wv * 1152;
    u32* B1 = B0 + 576;
    long nbase = (long)blockIdx.x * 64 + wv * 16;
    bool bf = (*flag != 0);
    if (lane < 16) {
        long n = nbase + lane;
        float in[12];
#pragma unroll
        for (int j = 0; j < 12; j++) in[j] = 0.f;
        if (n < N_NODES) {
#pragma unroll
            for (int j = 0; j < 11; j++)
                in[j] = bf ? b2f(((const u16*)nf)[n * 11 + j]) : ((const float*)nf)[n * 11 + j];
        }
        u32* row = B0 + lane * 36;
#pragma unroll
        for (int d = 0; d < 6; d++) row[d] = pack2(in[2 * d], in[2 * d + 1]);
#pragma unroll
        for (int d = 6; d < 16; d++) row[d] = 0;
    }
    WAVE_SYNC();
    f32x4 acc[4];
    mfma_layer<1, 4, 36>(B0, lane, Wf, FR_NE1, W + NE_B0, acc);
    tanh_pack_lds<4, 36>(acc, B1, lane, tbl);
    WAVE_SYNC();
    mfma_layer<2, 4, 36>(B1, lane, Wf, FR_NE2, W + NE_B1, acc);
    tanh_pack_lds<4, 36>(acc, B0, lane, tbl);
    WAVE_SYNC();
    mfma_layer<2, 4, 36>(B0, lane, Wf, FR_NE3, W + NE_B2, acc);
    long n = nbase + mr;
    if (n < N_NODES) {
#pragma unroll
        for (int nt = 0; nt < 4; nt++) {
            f32x4 v;
#pragma unroll
            for (int rr = 0; rr < 4; rr++) v[rr] = lut_tanh(tbl, acc[nt][rr]);
            *(f32x4*)(x + n * 64 + nt * 16 + q * 4) = v;
            u32x2 pb; pb.x = pack2(v[0], v[1]); pb.y = pack2(v[2], v[3]);
            *(u32x2*)&xbf[n * 64 + nt * 16 + q * 4] = pb;
        }
    }
}

// wave per node. Lane holds 2 packed features (u32); halves of the wave process
// edges k (lanes 0-31) and k+1 (lanes 32-63) -> ebuf streams 256 B/instr.
__global__ __launch_bounds__(256) void aggregate_kernel(
        const float* __restrict__ x, const u32* __restrict__ xbf32,
        const u32* __restrict__ ebuf32, const int* __restrict__ srcs,
        const int* __restrict__ rowptr, u32* __restrict__ h64bf32) {
    int gw = (int)((blockIdx.x * 256 + threadIdx.x) >> 6);
    int lane = (int)(threadIdx.x & 63);
    if (gw >= N_NODES) return;
    gw = __builtin_amdgcn_readfirstlane(gw);
    int half = lane >> 5, h = lane & 31;
    int beg = rowptr[gw], end = rowptr[gw + 1];
    int cnt = end - beg;
    float num0 = 0.f, den0 = 0.f, num1 = 0.f, den1 = 0.f;
    for (int base = 0; base < cnt; base += 64) {
        int rem = cnt - base; if (rem > 64) rem = 64;
        int lidx = (lane < rem) ? lane : (rem - 1);
        int sk = srcs[beg + base + lidx];
        const u32* eb = ebuf32 + (long)(beg + base) * 32 + h;
        int iters = (rem + 1) >> 1;
#pragma unroll 2
        for (int t = 0; t < iters; t++) {
            int eo = 2 * t + half;
            int eoc = (eo < rem) ? eo : (rem - 1);
            int s = __shfl(sk, eo, 64);          // lanes >= rem hold clamped valid src
            u32 xv = xbf32[(long)s * 32 + h];
            u32 ev = eb[eoc * 32];
            float m0 = fmaxf(lo2f(xv) + lo2f(ev), 0.f) + 1e-7f;
            float m1 = fmaxf(hi2f(xv) + hi2f(ev), 0.f) + 1e-7f;
            bool act = eo < rem;
            float w0 = act ? __expf(m0) : 0.f;
            float w1 = act ? __expf(m1) : 0.f;
            num0 = fmaf(w0, m0, num0); den0 += w0;
            num1 = fmaf(w1, m1, num1); den1 += w1;
        }
    }
    num0 += __shfl_xor(num0, 32, 64); den0 += __shfl_xor(den0, 32, 64);
    num1 += __shfl_xor(num1, 32, 64); den1 += __shfl_xor(den1, 32, 64);
    if (half == 0) {
        float agg0 = (den0 > 0.f) ? __fdividef(num0, den0) : 0.f;
        float agg1 = (den1 > 0.f) ? __fdividef(num1, den1) : 0.f;
        float2 xr = *(const float2*)(x + (long)gw * 64 + 2 * h);
        h64bf32[(long)gw * 32 + h] = pack2(xr.x + agg0, xr.y + agg1);
    }
}

// fused node MLP: 64->128 (acts direct from h64bf), LN (shfl), ReLU, 128->64
__global__ __launch_bounds__(256) void mlp_fused(const u16* __restrict__ h64bf,
        float* __restrict__ xout, u16* __restrict__ xbf,
        const float* __restrict__ W, const short8* __restrict__ Wf, int r) {
    __shared__ u32 lds[4 * 1088];
    int wv = threadIdx.x >> 6, lane = threadIdx.x & 63;
    int q = lane >> 4, mr = lane & 15;
    u32* bufY = lds + wv * 1088;
    long nbase = (long)blockIdx.x * 64 + wv * 16;
    long row = nbase + mr;
    long rc = (row < N_NODES) ? row : (N_NODES - 1);
    short8 act[2];
#pragma unroll
    for (int kt = 0; kt < 2; kt++)
        act[kt] = *(const short8*)&h64bf[rc * 64 + kt * 32 + q * 8];
    f32x4 acc[8];
    mfma_layer_reg<2, 8>(act, lane, Wf, FR_MP0 + r * 16, W + MP_B0 + r * 128, acc);
    float s = 0.f, sq = 0.f;
#pragma unroll
    for (int nt = 0; nt < 8; nt++)
#pragma unroll
        for (int rr = 0; rr < 4; rr++) { float v = acc[nt][rr]; s += v; sq = fmaf(v, v, sq); }
    s += __shfl_xor(s, 16, 64);  s += __shfl_xor(s, 32, 64);
    sq += __shfl_xor(sq, 16, 64); sq += __shfl_xor(sq, 32, 64);
    float mu = s * (1.f / 128.f);
    float var = sq * (1.f / 128.f) - mu * mu;
    float inv = rsqrtf(var + 1e-5f);
    const float* LW = W + LNW_O + r * 128;
    const float* LB = W + LNB_O + r * 128;
#pragma unroll
    for (int nt = 0; nt < 8; nt++) {
        f32x4 lw = *(const f32x4*)(LW + nt * 16 + q * 4);
        f32x4 lb = *(const f32x4*)(LB + nt * 16 + q * 4);
        float u0 = fmaxf(fmaf((acc[nt][0] - mu) * inv, lw[0], lb[0]), 0.f);
        float u1 = fmaxf(fmaf((acc[nt][1] - mu) * inv, lw[1], lb[1]), 0.f);
        float u2 = fmaxf(fmaf((acc[nt][2] - mu) * inv, lw[2], lb[2]), 0.f);
        float u3 = fmaxf(fmaf((acc[nt][3] - mu) * inv, lw[3], lb[3]), 0.f);
        bufY[mr * 68 + nt * 8 + q * 2 + 0] = pack2(u0, u1);
        bufY[mr * 68 + nt * 8 + q * 2 + 1] = pack2(u2, u3);
    }
    WAVE_SYNC();
    f32x4 acc2[4];
    mfma_layer<4, 4, 68>(bufY, lane, Wf, FR_MP1 + r * 16, W + MP_B1 + r * 64, acc2);
    if (row < N_NODES) {
#pragma unroll
        for (int nt = 0; nt < 4; nt++) {
            f32x4 v = acc2[nt];
            *(f32x4*)(xout + row * 64 + nt * 16 + q * 4) = v;
            u32x2 pb; pb.x = pack2(v[0], v[1]); pb.y = pack2(v[2], v[3]);
            *(u32x2*)&xbf[row * 64 + nt * 16 + q * 4] = pb;
        }
    }
}

__global__ __launch_bounds__(256) void policy_head(const u16* __restrict__ xbf, void* out,
        const float* __restrict__ W, const short8* __restrict__ Wf, const int* flag) {
    __shared__ u32 lds[4 * 576];
    __shared__ float2 tbl[TANH_TBL_N];
    build_tanh_tbl(tbl);
    int wv = threadIdx.x >> 6, lane = threadIdx.x & 63;
    int q = lane >> 4, mr = lane & 15;
    u32* bufY = lds + wv * 576;
    long nbase = (long)blockIdx.x * 64 + wv * 16;
    long row = nbase + mr;
    long rc = (row < N_NODES) ? row : (N_NODES - 1);
    bool bf = (*flag != 0);
    short8 act[2];
#pragma unroll
    for (int kt = 0; kt < 2; kt++)
        act[kt] = *(const short8*)&xbf[rc * 64 + kt * 32 + q * 8];
    f32x4 acc[4];
    mfma_layer_reg<2, 4>(act, lane, Wf, FR_PI0, W + PI_B0, acc);
    tanh_pack_lds<4, 36>(acc, bufY, lane, tbl);
    WAVE_SYNC();
    mfma_layer<2, 4, 36>(bufY, lane, Wf, FR_PI1, W + PI_B1, acc);
    float o = 0.f;
#pragma unroll
    for (int nt = 0; nt < 4; nt++) {
        f32x4 w2 = *(const f32x4*)(W + PI_W2 + nt * 16 + q * 4);
#pragma unroll
        for (int rr = 0; rr < 4; rr++) o = fmaf(lut_tanh(tbl, acc[nt][rr]), w2[rr], o);
    }
    o += __shfl_xor(o, 16, 64);
    o += __shfl_xor(o, 32, 64);
    if (lane < 16 && row < N_NODES) {
        float means = 30.f * (o + W[PI_B2]);
        if (bf) ((u16*)out)[row] = f2b(means);
        else    ((float*)out)[row] = means;
    }
}

// ---------------- launch ----------------
extern "C" void kernel_launch(void* const* d_in, const int* in_sizes, int n_in,
                              void* d_out, int out_size, void* d_ws, size_t ws_size,
                              hipStream_t stream) {
    char* ws = (char*)d_ws;
    float* W      = (float*)(ws + OFF_W);
    int*   flag   = (int*)(ws + OFF_FLAG);
    u16*   Wb     = (u16*)(ws + OFF_WB);
    const short8* Wf = (const short8*)(ws + OFF_WB);
    float* x0     = (float*)(ws + OFF_X0);
    float* x1     = (float*)(ws + OFF_X1);
    u16*   xb0    = (u16*)(ws + OFF_XB0);
    u16*   xb1    = (u16*)(ws + OFF_XB1);
    u16*   h64bf  = (u16*)(ws + OFF_H64B);
    u32*   h64b32 = (u32*)(ws + OFF_H64B);
    u32*   ebuf32 = (u32*)(ws + OFF_E);
    int*   rowptr = (int*)(ws + OFF_ROWPTR);
    int*   cursor = (int*)(ws + OFF_CURSOR);
    int*   perm   = (int*)(ws + OFF_PERM);
    int*   srcs   = (int*)(ws + OFF_SRCS);
    int*   bsum   = (int*)(ws + OFF_BSUM);

    const int* ei   = (const int*)d_in[2];
    const int* srcv = ei;
    const int* dstv = ei + N_EDGES;

    detect_kernel<<<1, 64, 0, stream>>>(d_in[0], flag);
    hipMemsetAsync(rowptr, 0, (N_NODES + 1) * sizeof(int), stream);

    Ptrs24 ps;
    for (int k = 0; k < 24; k++) ps.p[k] = d_in[3 + k];
    convert_weights<<<(W_TOTAL + 255) / 256, 256, 0, stream>>>(ps, W, flag);
    make_frags<<<(FR_TOTAL * 512 + 255) / 256, 256, 0, stream>>>(W, Wb);

    hist_kernel<<<(N_EDGES + 255) / 256, 256, 0, stream>>>(dstv, rowptr);
    scanA<<<25, 1024, 0, stream>>>(rowptr, bsum);
    scanB<<<1, 64, 0, stream>>>(bsum, 25);
    scanC<<<(N_NODES + 1024) / 1024, 1024, 0, stream>>>(bsum, rowptr, cursor);
    scatter_kernel<<<(N_EDGES + 255) / 256, 256, 0, stream>>>(dstv, srcv, cursor, perm, srcs);

    node_encoder<<<(N_NODES + 63) / 64, 256, 0, stream>>>(d_in[0], x0, xb0, W, Wf, flag);
    edge_encoder<<<N_EDGES / 64, 256, 0, stream>>>(d_in[1], ebuf32, perm, W, Wf, flag);

    float* xc = x0; float* xn = x1;
    u16* xbc = xb0; u16* xbn = xb1;
    for (int r = 0; r < 3; r++) {
        aggregate_kernel<<<(N_NODES * 64 + 255) / 256, 256, 0, stream>>>(
            xc, (const u32*)xbc, ebuf32, srcs, rowptr, h64b32);
        mlp_fused<<<(N_NODES + 63) / 64, 256, 0, stream>>>(h64bf, xn, xbn, W, Wf, r);
        float* t = xc; xc = xn; xn = t;
        u16* tb = xbc; xbc = xbn; xbn = tb;
    }
    policy_head<<<(N_NODES + 63) / 64, 256, 0, stream>>>(xbc, d_out, W, Wf, flag);
}

// Round 6
// 461.883 us; speedup vs baseline: 4.4177x; 1.0037x over previous
//
#include <hip/hip_runtime.h>
#include <stdint.h>

#define N_NODES 50000
#define N_EDGES 800000

typedef unsigned short u16;
typedef unsigned int u32;
typedef __attribute__((ext_vector_type(8))) short short8;   // 8 bf16 = A/B frag
typedef __attribute__((ext_vector_type(4))) float f32x4;    // C/D frag
typedef __attribute__((ext_vector_type(4))) u32 u32x4;
typedef __attribute__((ext_vector_type(2))) u32 u32x2;

// wave-private LDS exchange: writes committed (lgkmcnt==0) before reads issue.
#define WAVE_SYNC() asm volatile("s_waitcnt lgkmcnt(0)" ::: "memory")

// ---------------- helpers ----------------
__device__ __forceinline__ float b2f(u16 v) {
    u32 u = ((u32)v) << 16; float f; __builtin_memcpy(&f, &u, 4); return f;
}
__device__ __forceinline__ u16 f2b(float f) {
    u32 u; __builtin_memcpy(&u, &f, 4);
    return (u16)((u + 0x8000u) >> 16);
}
__device__ __forceinline__ float lo2f(u32 p) {
    u32 u = p << 16; float f; __builtin_memcpy(&f, &u, 4); return f;
}
__device__ __forceinline__ float hi2f(u32 p) {
    u32 u = p & 0xffff0000u; float f; __builtin_memcpy(&f, &u, 4); return f;
}
// pack two f32 -> two bf16 (round-half-up) in 3 ops via v_perm_b32
__device__ __forceinline__ u32 pack2(float a, float b) {
    u32 ua, ub; __builtin_memcpy(&ua, &a, 4); __builtin_memcpy(&ub, &b, 4);
    return __builtin_amdgcn_perm(ub + 0x8000u, ua + 0x8000u, 0x07060302u);
}
__device__ __forceinline__ f32x4 mfma16(short8 a, short8 b, f32x4 c) {
    return __builtin_amdgcn_mfma_f32_16x16x32_bf16(a, b, c, 0, 0, 0);
}

// ---- LUT tanh: 192 segments, step 1/32 over [0,6); y = fma(s, a, b~), sign via bfi.
#define TANH_TBL_N 192
__device__ __forceinline__ void build_tanh_tbl(float2* tbl) {
    int i = (int)threadIdx.x;
    if (i < TANH_TBL_N) {
        float x0 = i * 0.03125f, x1 = x0 + 0.03125f;
        float t0 = tanhf(x0), t1 = tanhf(x1);
        float s = (t1 - t0) * 32.f;
        tbl[i] = make_float2(fmaf(-s, x0, t0), s);   // b~ = t0 - s*x0
    }
    __syncthreads();
}
__device__ __forceinline__ float lut_tanh(const float2* __restrict__ tbl, float x) {
    float a = __builtin_fabsf(x);
    a = fminf(a, 5.96875f);
    int i = (int)(a * 32.f);
    float2 bs = tbl[i];
    float y = fmaf(bs.y, a, bs.x);
    return copysignf(y, x);   // v_bfi_b32
}

// ---------------- f32 weight layout (transposed to [in][out]) ----------------
enum : int {
    NE_T0 = 0,     NE_B0 = 704,   NE_T1 = 768,   NE_B1 = 4864,  NE_T2 = 4928,  NE_B2 = 9024,
    EE_T0 = 9088,  EE_B0 = 9280,  EE_T1 = 9344,  EE_B1 = 13440, EE_T2 = 13504, EE_B2 = 17600,
    MP_T0 = 17664, MP_B0 = 42240, LNW_O = 42624, LNB_O = 43008, MP_T1 = 43392, MP_B1 = 67968,
    PI_T0 = 68160, PI_B0 = 72256, PI_T1 = 72320, PI_B1 = 76416, PI_W2 = 76480, PI_B2 = 76608,
    W_TOTAL = 76610
};

// fragment-buffer layer bases (frag id; 512 bf16 per frag)
enum : int {
    FR_EE1 = 0, FR_EE2 = 4, FR_EE3 = 12, FR_NE1 = 20, FR_NE2 = 24, FR_NE3 = 32,
    FR_MP0 = 40, FR_MP1 = 88, FR_PI0 = 136, FR_PI1 = 144, FR_TOTAL = 152
};

// ---------------- workspace layout (bytes) ----------------
#define OFF_W       ((size_t)0)
#define OFF_FLAG    ((size_t)0x60000)
#define OFF_WB      ((size_t)0x61000)
#define OFF_XB0     ((size_t)0x90000)      // 6.4 MB bf16
#define OFF_XB1     ((size_t)0x700000)     // 6.4 MB bf16
#define OFF_H64B    ((size_t)0xE00000)     // 6.4 MB bf16
#define OFF_E       ((size_t)0x1500000)    // ebuf: up to 850k x 64 bf16 = 108.8 MB
#define OFF_ROWPTR  ((size_t)0x8300000)    // prow (padded CSR), N+1 ints
#define OFF_CURSOR  ((size_t)0x8340000)
#define OFF_CNT     ((size_t)0x8380000)    // per-node degree
#define OFF_PERM    ((size_t)0x83C0000)    // 3.2 MB
#define OFF_SRCS    ((size_t)0x8700000)    // 851968 ints (memset -1; pads stay -1)
#define OFF_BSUM    ((size_t)0x8A80000)

struct Ptrs24 { const void* p[24]; };

// ---------------- setup kernels ----------------

__global__ void detect_kernel(const void* nf, int* flag) {
    u32 w = ((const u32*)nf)[threadIdx.x & 63];
    u32 lo = w & 0xffffu;
    int e = (int)((lo >> 7) & 0xff);
    int good = ((e >= 118 && e <= 132) || lo == 0) ? 1 : 0;
    unsigned long long b = __ballot(good != 0);
    if (threadIdx.x == 0) *flag = (__popcll(b) >= 48) ? 1 : 0;
}

__global__ void convert_weights(Ptrs24 ps, float* __restrict__ W, const int* flag) {
    const int segIN[24] = {11,64,64,64,64,64, 3,64,64,64,64,64, 64,384,384,384,128,192, 64,64,64,64,128,2};
    const int segOUT[24]= {64, 1,64, 1,64, 1, 64, 1,64, 1,64, 1, 128, 1,  1,  1, 64,  1, 64, 1,64, 1,  1,1};
    const int segS[24]  = { 1, 1, 1, 1, 1, 1,  1, 1, 1, 1, 1, 1,   3, 1,  1,  1,  3,  1,  1, 1, 1, 1,  1,1};
    const int segTR[24] = { 1, 0, 1, 0, 1, 0,  1, 0, 1, 0, 1, 0,   1, 0,  0,  0,  1,  0,  1, 0, 1, 0,  0,0};
    int t = blockIdx.x * blockDim.x + threadIdx.x;
    if (t >= W_TOTAL) return;
    bool bf = (*flag != 0);
    int seg = 0, off = t;
    for (;;) {
        int cnt = segIN[seg] * segOUT[seg] * segS[seg];
        if (off < cnt) break;
        off -= cnt; seg++;
    }
    int srcIdx;
    if (segTR[seg]) {
        int per = segIN[seg] * segOUT[seg];
        int s = off / per, d = off % per;
        int j = d / segOUT[seg], i = d % segOUT[seg];
        srcIdx = s * per + i * segIN[seg] + j;
    } else {
        srcIdx = off;
    }
    const void* p = ps.p[seg];
    W[t] = bf ? b2f(((const u16*)p)[srcIdx]) : ((const float*)p)[srcIdx];
}

__global__ void make_frags(const float* __restrict__ W, u16* __restrict__ Wb) {
    const int base[15] = {FR_EE1,FR_EE2,FR_EE3,FR_NE1,FR_NE2,FR_NE3,
                          FR_MP0,FR_MP0+16,FR_MP0+32, FR_MP1,FR_MP1+16,FR_MP1+32,
                          FR_PI0,FR_PI1,FR_TOTAL};
    const int woff[14] = {EE_T0,EE_T1,EE_T2, NE_T0,NE_T1,NE_T2,
                          MP_T0,MP_T0+8192,MP_T0+16384, MP_T1,MP_T1+8192,MP_T1+16384,
                          PI_T0,PI_T1};
    const int kreal[14] = {3,64,64, 11,64,64, 64,64,64, 128,128,128, 64,64};
    const int nn[14]    = {64,64,64, 64,64,64, 128,128,128, 64,64,64, 64,64};
    int t = blockIdx.x * blockDim.x + threadIdx.x;
    if (t >= FR_TOTAL * 512) return;
    int f = t >> 9, r = t & 511, lane = r >> 3, j = r & 7;
    int l = 0;
    while (f >= base[l + 1]) l++;
    int lf = f - base[l];
    int NT = nn[l] >> 4;
    int kt = lf / NT, nt = lf % NT;
    int k = kt * 32 + (lane >> 4) * 8 + j;
    int n = nt * 16 + (lane & 15);
    float v = (k < kreal[l]) ? W[woff[l] + k * nn[l] + n] : 0.f;
    u32 u; __builtin_memcpy(&u, &v, 4);
    Wb[t] = (u16)((u + 0x7fffu + ((u >> 16) & 1u)) >> 16);   // RNE for weights
}

// ---------------- graph build (even-padded CSR) ----------------

__global__ void hist_kernel(const int* __restrict__ dst, int* __restrict__ cnts) {
    int e = blockIdx.x * blockDim.x + threadIdx.x;
    if (e < N_EDGES) atomicAdd(&cnts[dst[e]], 1);
}

// scan of padded counts: prow[i] = sum_{j<i} evenpad(cnt_j), inclusive layout over [0..N]
__global__ void scanA(const int* __restrict__ cnts, int* __restrict__ prow,
                      int* __restrict__ bsum) {
    __shared__ int wsum[16];
    int tid = threadIdx.x, lane = tid & 63, wid = tid >> 6;
    int i0 = blockIdx.x * 2048 + tid * 2;
    int v0 = 0, v1 = 0;
    if (i0 >= 1 && i0 <= N_NODES) v0 = (cnts[i0 - 1] + 1) & ~1;
    if (i0 + 1 <= N_NODES && i0 + 1 >= 1) v1 = (cnts[i0] + 1) & ~1;
    int v = v0 + v1;
#pragma unroll
    for (int off = 1; off < 64; off <<= 1) {
        int t = __shfl_up(v, off, 64);
        if (lane >= off) v += t;
    }
    if (lane == 63) wsum[wid] = v;
    __syncthreads();
    if (tid == 0) { int a = 0; for (int w = 0; w < 16; w++) { a += wsum[w]; wsum[w] = a; } }
    __syncthreads();
    int incl = v + (wid ? wsum[wid - 1] : 0);
    if (i0 <= N_NODES) prow[i0] = incl - v1;
    if (i0 + 1 <= N_NODES) prow[i0 + 1] = incl;
    if (tid == 1023) bsum[blockIdx.x] = incl;
}
__global__ void scanB(int* __restrict__ bsum, int nb) {
    int lane = threadIdx.x;
    int v = (lane < nb) ? bsum[lane] : 0;
#pragma unroll
    for (int off = 1; off < 64; off <<= 1) {
        int t = __shfl_up(v, off, 64);
        if (lane >= off) v += t;
    }
    if (lane < nb) bsum[lane] = v;
}
__global__ void scanC(const int* __restrict__ bsum, int* __restrict__ prow,
                      int* __restrict__ cursor) {
    int i = blockIdx.x * 1024 + threadIdx.x;
    if (i > N_NODES) return;
    int b = i >> 11;
    int v = prow[i] + (b ? bsum[b - 1] : 0);
    prow[i] = v;
    if (i < N_NODES) cursor[i] = v;
}

__global__ void scatter_kernel(const int* __restrict__ dst, const int* __restrict__ src,
                               int* __restrict__ cursor, int* __restrict__ perm,
                               int* __restrict__ srcs) {
    int e = blockIdx.x * blockDim.x + threadIdx.x;
    if (e >= N_EDGES) return;
    int p = atomicAdd(&cursor[dst[e]], 1);
    perm[e] = p;
    srcs[p] = src[e];
}

// ---------------- MFMA layer building blocks ----------------
// D = Wfrag(A) x ActFrag(B) -> D[n][m]: m = lane&15, n = nt*16 + (lane>>4)*4 + reg.

template<int KT, int NT, int INSTR>
__device__ __forceinline__ void mfma_layer(const u32* ldsin, int lane,
        const short8* __restrict__ Wf, int basef, const float* __restrict__ bias, f32x4* acc) {
    int q = lane >> 4, mr = lane & 15;
#pragma unroll
    for (int nt = 0; nt < NT; nt++) acc[nt] = *(const f32x4*)(bias + nt * 16 + q * 4);
#pragma unroll
    for (int kt = 0; kt < KT; kt++) {
        short8 act = *(const short8*)(ldsin + mr * INSTR + kt * 16 + q * 4);
#pragma unroll
        for (int nt = 0; nt < NT; nt++)
            acc[nt] = mfma16(Wf[(basef + kt * NT + nt) * 64 + lane], act, acc[nt]);
    }
}

template<int KT, int NT>
__device__ __forceinline__ void mfma_layer_reg(const short8* act, int lane,
        const short8* __restrict__ Wf, int basef, const float* __restrict__ bias, f32x4* acc) {
    int q = lane >> 4;
#pragma unroll
    for (int nt = 0; nt < NT; nt++) acc[nt] = *(const f32x4*)(bias + nt * 16 + q * 4);
#pragma unroll
    for (int kt = 0; kt < KT; kt++)
#pragma unroll
        for (int nt = 0; nt < NT; nt++)
            acc[nt] = mfma16(Wf[(basef + kt * NT + nt) * 64 + lane], act[kt], acc[nt]);
}

template<int NT, int OUTSTR>
__device__ __forceinline__ void tanh_pack_lds(const f32x4* acc, u32* ldsout, int lane,
                                              const float2* __restrict__ tbl) {
    int q = lane >> 4, mr = lane & 15;
#pragma unroll
    for (int nt = 0; nt < NT; nt++) {
        f32x4 a = acc[nt];
        ldsout[mr * OUTSTR + nt * 8 + q * 2 + 0] = pack2(lut_tanh(tbl, a[0]), lut_tanh(tbl, a[1]));
        ldsout[mr * OUTSTR + nt * 8 + q * 2 + 1] = pack2(lut_tanh(tbl, a[2]), lut_tanh(tbl, a[3]));
    }
}

// ---------------- encoders / MLP / head ----------------

__global__ __launch_bounds__(256) void edge_encoder(const void* ef, u32* __restrict__ ebuf,
        const int* __restrict__ perm, const float* __restrict__ W,
        const short8* __restrict__ Wf, const int* flag) {
    __shared__ u32 lds[4 * 1152];
    __shared__ float2 tbl[TANH_TBL_N];
    build_tanh_tbl(tbl);
    int wv = threadIdx.x >> 6, lane = threadIdx.x & 63;
    u32* B0 = lds + wv * 1152;
    u32* B1 = B0 + 576;
    long ebase = (long)blockIdx.x * 64 + wv * 16;
    bool bf = (*flag != 0);
    if (lane < 16) {
        long e = ebase + lane;   // N_EDGES % 64 == 0: always valid
        float i0, i1, i2;
        if (bf) { const u16* p = (const u16*)ef + e * 3; i0 = b2f(p[0]); i1 = b2f(p[1]); i2 = b2f(p[2]); }
        else    { const float* p = (const float*)ef + e * 3; i0 = p[0]; i1 = p[1]; i2 = p[2]; }
        u32* row = B0 + lane * 36;
        row[0] = pack2(i0, i1); row[1] = pack2(i2, 0.f);
#pragma unroll
        for (int d = 2; d < 16; d++) row[d] = 0;
    }
    WAVE_SYNC();
    f32x4 acc[4];
    mfma_layer<1, 4, 36>(B0, lane, Wf, FR_EE1, W + EE_B0, acc);
    tanh_pack_lds<4, 36>(acc, B1, lane, tbl);
    WAVE_SYNC();
    mfma_layer<2, 4, 36>(B1, lane, Wf, FR_EE2, W + EE_B1, acc);
    tanh_pack_lds<4, 36>(acc, B0, lane, tbl);
    WAVE_SYNC();
    mfma_layer<2, 4, 36>(B0, lane, Wf, FR_EE3, W + EE_B2, acc);
    tanh_pack_lds<4, 36>(acc, B1, lane, tbl);
    WAVE_SYNC();
    int ro = lane >> 2, cc = (lane & 3) * 8;
    long e = ebase + ro;
    long prowp = perm[e];
    u32x4 v0 = *(const u32x4*)&B1[ro * 36 + cc];
    u32x4 v1 = *(const u32x4*)&B1[ro * 36 + cc + 4];
    *(u32x4*)&ebuf[prowp * 32 + cc] = v0;
    *(u32x4*)&ebuf[prowp * 32 + cc + 4] = v1;
}

__global__ __launch_bounds__(256) void node_encoder(const void* nf,
        u16* __restrict__ xbf, const float* __restrict__ W,
        const short8* __restrict__ Wf, const int* flag) {
    __shared__ u32 lds[4 * 1152];
    __shared__ float2 tbl[TANH_TBL_N];
    build_tanh_tbl(tbl);
    int wv = threadIdx.x >> 6, lane = threadIdx.x & 63;
    int q = lane >> 4, mr = lane & 15;
    u32* B0 = lds + wv * 1152;
    u32* B1 = B0 + 576;
    long nbase = (long)blockIdx.x * 64 + wv * 16;
    bool bf = (*flag != 0);
    if (lane < 16) {
        long n = nbase + lane;
        float in[12];
#pragma unroll
        for (int j = 0; j < 12; j++) in[j] = 0.f;
        if (n < N_NODES) {
#pragma unroll
            for (int j = 0; j < 11; j++)
                in[j] = bf ? b2f(((const u16*)nf)[n * 11 + j]) : ((const float*)nf)[n * 11 + j];
        }
        u32* row = B0 + lane * 36;
#pragma unroll
        for (int d = 0; d < 6; d++) row[d] = pack2(in[2 * d], in[2 * d + 1]);
#pragma unroll
        for (int d = 6; d < 16; d++) row[d] = 0;
    }
    WAVE_SYNC();
    f32x4 acc[4];
    mfma_layer<1, 4, 36>(B0, lane, Wf, FR_NE1, W + NE_B0, acc);
    tanh_pack_lds<4, 36>(acc, B1, lane, tbl);
    WAVE_SYNC();
    mfma_layer<2, 4, 36>(B1, lane, Wf, FR_NE2, W + NE_B1, acc);
    tanh_pack_lds<4, 36>(acc, B0, lane, tbl);
    WAVE_SYNC();
    mfma_layer<2, 4, 36>(B0, lane, Wf, FR_NE3, W + NE_B2, acc);
    long n = nbase + mr;
    if (n < N_NODES) {
#pragma unroll
        for (int nt = 0; nt < 4; nt++) {
            float v0 = lut_tanh(tbl, acc[nt][0]), v1 = lut_tanh(tbl, acc[nt][1]);
            float v2 = lut_tanh(tbl, acc[nt][2]), v3 = lut_tanh(tbl, acc[nt][3]);
            u32x2 pb; pb.x = pack2(v0, v1); pb.y = pack2(v2, v3);
            *(u32x2*)&xbf[n * 64 + nt * 16 + q * 4] = pb;
        }
    }
}

// 4 consecutive nodes per wave: contiguous padded edge range, one sliding srcs
// window, setup amortized 4x. Pads carry src=-1 -> w=0.
__global__ __launch_bounds__(256) void aggregate_kernel(
        const u32* __restrict__ xbf32, const u32* __restrict__ ebuf32,
        const int* __restrict__ srcs, const int* __restrict__ prow,
        u32* __restrict__ h64bf32) {
    int wid = (int)((blockIdx.x * 256 + threadIdx.x) >> 6);
    int lane = (int)(threadIdx.x & 63);
    int n0 = __builtin_amdgcn_readfirstlane(wid) * 4;
    if (n0 >= N_NODES) return;
    int half = lane >> 5, h = lane & 31;
    int rl = n0 + (lane < 4 ? lane : 4);
    if (rl > N_NODES) rl = N_NODES;
    int rv = prow[rl];
    int win = __shfl(rv, 0, 64);
    int sk = srcs[win + lane];
    for (int j = 0; j < 4; j++) {
        int n = n0 + j;
        if (n >= N_NODES) break;
        int kb = __shfl(rv, j, 64);
        int ke = __shfl(rv, j + 1, 64);
        u32 xr = xbf32[(long)n * 32 + h];
        float num0 = 0.f, den0 = 0.f, num1 = 0.f, den1 = 0.f;
        for (int k = kb; k < ke; k += 2) {
            if (k + 1 >= win + 64) { win = k; sk = srcs[win + lane]; }
            int s = __shfl(sk, k - win + half, 64);
            u32 ev = ebuf32[(long)(k + half) * 32 + h];
            bool valid = s >= 0;
            long sr = valid ? (long)s : 0;
            u32 xv = xbf32[sr * 32 + h];
            float m0 = fmaxf(lo2f(xv) + lo2f(ev), 0.f) + 1e-7f;
            float m1 = fmaxf(hi2f(xv) + hi2f(ev), 0.f) + 1e-7f;
            float w0 = valid ? __expf(m0) : 0.f;
            float w1 = valid ? __expf(m1) : 0.f;
            num0 = fmaf(w0, m0, num0); den0 += w0;
            num1 = fmaf(w1, m1, num1); den1 += w1;
        }
        num0 += __shfl_xor(num0, 32, 64); den0 += __shfl_xor(den0, 32, 64);
        num1 += __shfl_xor(num1, 32, 64); den1 += __shfl_xor(den1, 32, 64);
        if (half == 0) {
            float agg0 = (den0 > 0.f) ? __fdividef(num0, den0) : 0.f;
            float agg1 = (den1 > 0.f) ? __fdividef(num1, den1) : 0.f;
            h64bf32[(long)n * 32 + h] = pack2(lo2f(xr) + agg0, hi2f(xr) + agg1);
        }
    }
}

// fused node MLP: 64->128 (acts direct from h64bf), LN (shfl), ReLU, 128->64
__global__ __launch_bounds__(256) void mlp_fused(const u16* __restrict__ h64bf,
        u16* __restrict__ xbf,
        const float* __restrict__ W, const short8* __restrict__ Wf, int r) {
    __shared__ u32 lds[4 * 1088];
    int wv = threadIdx.x >> 6, lane = threadIdx.x & 63;
    int q = lane >> 4, mr = lane & 15;
    u32* bufY = lds + wv * 1088;
    long nbase = (long)blockIdx.x * 64 + wv * 16;
    long row = nbase + mr;
    long rc = (row < N_NODES) ? row : (N_NODES - 1);
    short8 act[2];
#pragma unroll
    for (int kt = 0; kt < 2; kt++)
        act[kt] = *(const short8*)&h64bf[rc * 64 + kt * 32 + q * 8];
    f32x4 acc[8];
    mfma_layer_reg<2, 8>(act, lane, Wf, FR_MP0 + r * 16, W + MP_B0 + r * 128, acc);
    float s = 0.f, sq = 0.f;
#pragma unroll
    for (int nt = 0; nt < 8; nt++)
#pragma unroll
        for (int rr = 0; rr < 4; rr++) { float v = acc[nt][rr]; s += v; sq = fmaf(v, v, sq); }
    s += __shfl_xor(s, 16, 64);  s += __shfl_xor(s, 32, 64);
    sq += __shfl_xor(sq, 16, 64); sq += __shfl_xor(sq, 32, 64);
    float mu = s * (1.f / 128.f);
    float var = sq * (1.f / 128.f) - mu * mu;
    float inv = rsqrtf(var + 1e-5f);
    const float* LW = W + LNW_O + r * 128;
    const float* LB = W + LNB_O + r * 128;
#pragma unroll
    for (int nt = 0; nt < 8; nt++) {
        f32x4 lw = *(const f32x4*)(LW + nt * 16 + q * 4);
        f32x4 lb = *(const f32x4*)(LB + nt * 16 + q * 4);
        float u0 = fmaxf(fmaf((acc[nt][0] - mu) * inv, lw[0], lb[0]), 0.f);
        float u1 = fmaxf(fmaf((acc[nt][1] - mu) * inv, lw[1], lb[1]), 0.f);
        float u2 = fmaxf(fmaf((acc[nt][2] - mu) * inv, lw[2], lb[2]), 0.f);
        float u3 = fmaxf(fmaf((acc[nt][3] - mu) * inv, lw[3], lb[3]), 0.f);
        bufY[mr * 68 + nt * 8 + q * 2 + 0] = pack2(u0, u1);
        bufY[mr * 68 + nt * 8 + q * 2 + 1] = pack2(u2, u3);
    }
    WAVE_SYNC();
    f32x4 acc2[4];
    mfma_layer<4, 4, 68>(bufY, lane, Wf, FR_MP1 + r * 16, W + MP_B1 + r * 64, acc2);
    if (row < N_NODES) {
#pragma unroll
        for (int nt = 0; nt < 4; nt++) {
            f32x4 v = acc2[nt];
            u32x2 pb; pb.x = pack2(v[0], v[1]); pb.y = pack2(v[2], v[3]);
            *(u32x2*)&xbf[row * 64 + nt * 16 + q * 4] = pb;
        }
    }
}

__global__ __launch_bounds__(256) void policy_head(const u16* __restrict__ xbf, void* out,
        const float* __restrict__ W, const short8* __restrict__ Wf, const int* flag) {
    __shared__ u32 lds[4 * 576];
    __shared__ float2 tbl[TANH_TBL_N];
    build_tanh_tbl(tbl);
    int wv = threadIdx.x >> 6, lane = threadIdx.x & 63;
    int q = lane >> 4, mr = lane & 15;
    u32* bufY = lds + wv * 576;
    long nbase = (long)blockIdx.x * 64 + wv * 16;
    long row = nbase + mr;
    long rc = (row < N_NODES) ? row : (N_NODES - 1);
    bool bf = (*flag != 0);
    short8 act[2];
#pragma unroll
    for (int kt = 0; kt < 2; kt++)
        act[kt] = *(const short8*)&xbf[rc * 64 + kt * 32 + q * 8];
    f32x4 acc[4];
    mfma_layer_reg<2, 4>(act, lane, Wf, FR_PI0, W + PI_B0, acc);
    tanh_pack_lds<4, 36>(acc, bufY, lane, tbl);
    WAVE_SYNC();
    mfma_layer<2, 4, 36>(bufY, lane, Wf, FR_PI1, W + PI_B1, acc);
    float o = 0.f;
#pragma unroll
    for (int nt = 0; nt < 4; nt++) {
        f32x4 w2 = *(const f32x4*)(W + PI_W2 + nt * 16 + q * 4);
#pragma unroll
        for (int rr = 0; rr < 4; rr++) o = fmaf(lut_tanh(tbl, acc[nt][rr]), w2[rr], o);
    }
    o += __shfl_xor(o, 16, 64);
    o += __shfl_xor(o, 32, 64);
    if (lane < 16 && row < N_NODES) {
        float means = 30.f * (o + W[PI_B2]);
        if (bf) ((u16*)out)[row] = f2b(means);
        else    ((float*)out)[row] = means;
    }
}

// ---------------- launch ----------------
extern "C" void kernel_launch(void* const* d_in, const int* in_sizes, int n_in,
                              void* d_out, int out_size, void* d_ws, size_t ws_size,
                              hipStream_t stream) {
    char* ws = (char*)d_ws;
    float* W      = (float*)(ws + OFF_W);
    int*   flag   = (int*)(ws + OFF_FLAG);
    u16*   Wb     = (u16*)(ws + OFF_WB);
    const short8* Wf = (const short8*)(ws + OFF_WB);
    u16*   xb0    = (u16*)(ws + OFF_XB0);
    u16*   xb1    = (u16*)(ws + OFF_XB1);
    u16*   h64bf  = (u16*)(ws + OFF_H64B);
    u32*   h64b32 = (u32*)(ws + OFF_H64B);
    u32*   ebuf32 = (u32*)(ws + OFF_E);
    int*   prow   = (int*)(ws + OFF_ROWPTR);
    int*   cursor = (int*)(ws + OFF_CURSOR);
    int*   cnts   = (int*)(ws + OFF_CNT);
    int*   perm   = (int*)(ws + OFF_PERM);
    int*   srcs   = (int*)(ws + OFF_SRCS);
    int*   bsum   = (int*)(ws + OFF_BSUM);

    const int* ei   = (const int*)d_in[2];
    const int* srcv = ei;
    const int* dstv = ei + N_EDGES;

    detect_kernel<<<1, 64, 0, stream>>>(d_in[0], flag);
    hipMemsetAsync(cnts, 0, N_NODES * sizeof(int), stream);
    hipMemsetAsync(srcs, 0xFF, (size_t)0x340000, stream);   // srcs = -1 (pad marker)

    Ptrs24 ps;
    for (int k = 0; k < 24; k++) ps.p[k] = d_in[3 + k];
    convert_weights<<<(W_TOTAL + 255) / 256, 256, 0, stream>>>(ps, W, flag);
    make_frags<<<(FR_TOTAL * 512 + 255) / 256, 256, 0, stream>>>(W, Wb);

    hist_kernel<<<(N_EDGES + 255) / 256, 256, 0, stream>>>(dstv, cnts);
    scanA<<<25, 1024, 0, stream>>>(cnts, prow, bsum);
    scanB<<<1, 64, 0, stream>>>(bsum, 25);
    scanC<<<(N_NODES + 1024) / 1024, 1024, 0, stream>>>(bsum, prow, cursor);
    scatter_kernel<<<(N_EDGES + 255) / 256, 256, 0, stream>>>(dstv, srcv, cursor, perm, srcs);

    node_encoder<<<(N_NODES + 63) / 64, 256, 0, stream>>>(d_in[0], xb0, W, Wf, flag);
    edge_encoder<<<N_EDGES / 64, 256, 0, stream>>>(d_in[1], ebuf32, perm, W, Wf, flag);

    u16* xbc = xb0; u16* xbn = xb1;
    const int aggBlocks = ((N_NODES + 3) / 4 * 64 + 255) / 256;
    for (int r = 0; r < 3; r++) {
        aggregate_kernel<<<aggBlocks, 256, 0, stream>>>(
            (const u32*)xbc, ebuf32, srcs, prow, h64b32);
        mlp_fused<<<(N_NODES + 63) / 64, 256, 0, stream>>>(h64bf, xbn, W, Wf, r);
        u16* tb = xbc; xbc = xbn; xbn = tb;
    }
    policy_head<<<(N_NODES + 63) / 64, 256, 0, stream>>>(xbc, d_out, W, Wf, flag);
}

// Round 7
// 431.885 us; speedup vs baseline: 4.7245x; 1.0695x over previous
//
#include <hip/hip_runtime.h>
#include <stdint.h>

#define N_NODES 50000
#define N_EDGES 800000

typedef unsigned short u16;
typedef unsigned int u32;
typedef __attribute__((ext_vector_type(8))) short short8;   // 8 bf16 = A/B frag
typedef __attribute__((ext_vector_type(4))) float f32x4;    // C/D frag
typedef __attribute__((ext_vector_type(4))) u32 u32x4;
typedef __attribute__((ext_vector_type(2))) u32 u32x2;

// wave-private LDS exchange: DS ops are in-order per wave; only need lgkmcnt drain.
#define WAVE_SYNC() asm volatile("s_waitcnt lgkmcnt(0)" ::: "memory")

// ---------------- helpers ----------------
__device__ __forceinline__ float b2f(u16 v) {
    u32 u = ((u32)v) << 16; float f; __builtin_memcpy(&f, &u, 4); return f;
}
__device__ __forceinline__ u16 f2b(float f) {
    u32 u; __builtin_memcpy(&u, &f, 4);
    return (u16)((u + 0x8000u) >> 16);
}
__device__ __forceinline__ float lo2f(u32 p) {
    u32 u = p << 16; float f; __builtin_memcpy(&f, &u, 4); return f;
}
__device__ __forceinline__ float hi2f(u32 p) {
    u32 u = p & 0xffff0000u; float f; __builtin_memcpy(&f, &u, 4); return f;
}
// pack two f32 -> two bf16 (round-half-up) in 3 ops via v_perm_b32
__device__ __forceinline__ u32 pack2(float a, float b) {
    u32 ua, ub; __builtin_memcpy(&ua, &a, 4); __builtin_memcpy(&ub, &b, 4);
    return __builtin_amdgcn_perm(ub + 0x8000u, ua + 0x8000u, 0x07060302u);
}
__device__ __forceinline__ f32x4 mfma16(short8 a, short8 b, f32x4 c) {
    return __builtin_amdgcn_mfma_f32_16x16x32_bf16(a, b, c, 0, 0, 0);
}

// ---- LUT tanh: 192 segments, step 1/32 over [0,6); y = fma(s, a, b~), sign via bfi.
#define TANH_TBL_N 192
__device__ __forceinline__ void load_tbl(const float2* __restrict__ g, float2* tbl) {
    int i = (int)threadIdx.x;
    if (i < TANH_TBL_N) tbl[i] = g[i];
    __syncthreads();
}
__device__ __forceinline__ float lut_tanh(const float2* __restrict__ tbl, float x) {
    float a = __builtin_fabsf(x);
    a = fminf(a, 5.96875f);
    int i = (int)(a * 32.f);
    float2 bs = tbl[i];
    float y = fmaf(bs.y, a, bs.x);
    return copysignf(y, x);   // v_bfi_b32
}

// ---------------- f32 weight layout (transposed to [in][out]) ----------------
enum : int {
    NE_T0 = 0,     NE_B0 = 704,   NE_T1 = 768,   NE_B1 = 4864,  NE_T2 = 4928,  NE_B2 = 9024,
    EE_T0 = 9088,  EE_B0 = 9280,  EE_T1 = 9344,  EE_B1 = 13440, EE_T2 = 13504, EE_B2 = 17600,
    MP_T0 = 17664, MP_B0 = 42240, LNW_O = 42624, LNB_O = 43008, MP_T1 = 43392, MP_B1 = 67968,
    PI_T0 = 68160, PI_B0 = 72256, PI_T1 = 72320, PI_B1 = 76416, PI_W2 = 76480, PI_B2 = 76608,
    W_TOTAL = 76610
};

// fragment-buffer layer bases (frag id; 512 bf16 per frag)
enum : int {
    FR_EE1 = 0, FR_EE2 = 4, FR_EE3 = 12, FR_NE1 = 20, FR_NE2 = 24, FR_NE3 = 32,
    FR_MP0 = 40, FR_MP1 = 88, FR_PI0 = 136, FR_PI1 = 144, FR_TOTAL = 152
};

// ---------------- workspace layout (bytes) ----------------
#define OFF_W       ((size_t)0)
#define OFF_FLAG    ((size_t)0x60000)
#define OFF_WB      ((size_t)0x61000)      // 152*512*2 = 155648 B
#define OFF_TBL     ((size_t)0x88000)      // 192 float2 = 1536 B
#define OFF_XB0     ((size_t)0x90000)      // 6.4 MB bf16
#define OFF_XB1     ((size_t)0x700000)     // 6.4 MB bf16
#define OFF_H64B    ((size_t)0xE00000)     // 6.4 MB bf16
#define OFF_E       ((size_t)0x1500000)    // ebuf: up to 850k x 64 bf16
#define OFF_ROWPTR  ((size_t)0x8300000)    // prow (padded CSR), N+1 ints
#define OFF_CURSOR  ((size_t)0x8340000)
#define OFF_CNT     ((size_t)0x8380000)
#define OFF_PERM    ((size_t)0x83C0000)
#define OFF_SRCS    ((size_t)0x8700000)    // 851968 ints (memset -1; pads stay -1)
#define OFF_BSUM    ((size_t)0x8A80000)

struct Ptrs24 { const void* p[24]; };

// ---------------- setup kernels ----------------

__global__ void detect_kernel(const void* nf, int* flag) {
    u32 w = ((const u32*)nf)[threadIdx.x & 63];
    u32 lo = w & 0xffffu;
    int e = (int)((lo >> 7) & 0xff);
    int good = ((e >= 118 && e <= 132) || lo == 0) ? 1 : 0;
    unsigned long long b = __ballot(good != 0);
    if (threadIdx.x == 0) *flag = (__popcll(b) >= 48) ? 1 : 0;
}

__global__ void convert_weights(Ptrs24 ps, float* __restrict__ W, const int* flag) {
    const int segIN[24] = {11,64,64,64,64,64, 3,64,64,64,64,64, 64,384,384,384,128,192, 64,64,64,64,128,2};
    const int segOUT[24]= {64, 1,64, 1,64, 1, 64, 1,64, 1,64, 1, 128, 1,  1,  1, 64,  1, 64, 1,64, 1,  1,1};
    const int segS[24]  = { 1, 1, 1, 1, 1, 1,  1, 1, 1, 1, 1, 1,   3, 1,  1,  1,  3,  1,  1, 1, 1, 1,  1,1};
    const int segTR[24] = { 1, 0, 1, 0, 1, 0,  1, 0, 1, 0, 1, 0,   1, 0,  0,  0,  1,  0,  1, 0, 1, 0,  0,0};
    int t = blockIdx.x * blockDim.x + threadIdx.x;
    if (t >= W_TOTAL) return;
    bool bf = (*flag != 0);
    int seg = 0, off = t;
    for (;;) {
        int cnt = segIN[seg] * segOUT[seg] * segS[seg];
        if (off < cnt) break;
        off -= cnt; seg++;
    }
    int srcIdx;
    if (segTR[seg]) {
        int per = segIN[seg] * segOUT[seg];
        int s = off / per, d = off % per;
        int j = d / segOUT[seg], i = d % segOUT[seg];
        srcIdx = s * per + i * segIN[seg] + j;
    } else {
        srcIdx = off;
    }
    const void* p = ps.p[seg];
    W[t] = bf ? b2f(((const u16*)p)[srcIdx]) : ((const float*)p)[srcIdx];
}

// bake bf16 MFMA A-frags + the global tanh LUT
__global__ void make_frags(const float* __restrict__ W, u16* __restrict__ Wb,
                           float2* __restrict__ gtbl) {
    const int base[15] = {FR_EE1,FR_EE2,FR_EE3,FR_NE1,FR_NE2,FR_NE3,
                          FR_MP0,FR_MP0+16,FR_MP0+32, FR_MP1,FR_MP1+16,FR_MP1+32,
                          FR_PI0,FR_PI1,FR_TOTAL};
    const int woff[14] = {EE_T0,EE_T1,EE_T2, NE_T0,NE_T1,NE_T2,
                          MP_T0,MP_T0+8192,MP_T0+16384, MP_T1,MP_T1+8192,MP_T1+16384,
                          PI_T0,PI_T1};
    const int kreal[14] = {3,64,64, 11,64,64, 64,64,64, 128,128,128, 64,64};
    const int nn[14]    = {64,64,64, 64,64,64, 128,128,128, 64,64,64, 64,64};
    int t = blockIdx.x * blockDim.x + threadIdx.x;
    if (t >= FR_TOTAL * 512) {
        int i = t - FR_TOTAL * 512;
        if (i < TANH_TBL_N) {
            float x0 = i * 0.03125f, x1 = x0 + 0.03125f;
            float t0 = tanhf(x0), t1 = tanhf(x1);
            float s = (t1 - t0) * 32.f;
            gtbl[i] = make_float2(fmaf(-s, x0, t0), s);
        }
        return;
    }
    int f = t >> 9, r = t & 511, lane = r >> 3, j = r & 7;
    int l = 0;
    while (f >= base[l + 1]) l++;
    int lf = f - base[l];
    int NT = nn[l] >> 4;
    int kt = lf / NT, nt = lf % NT;
    int k = kt * 32 + (lane >> 4) * 8 + j;
    int n = nt * 16 + (lane & 15);
    float v = (k < kreal[l]) ? W[woff[l] + k * nn[l] + n] : 0.f;
    u32 u; __builtin_memcpy(&u, &v, 4);
    Wb[t] = (u16)((u + 0x7fffu + ((u >> 16) & 1u)) >> 16);   // RNE for weights
}

// ---------------- graph build (even-padded CSR) ----------------

__global__ void hist_kernel(const int* __restrict__ dst, int* __restrict__ cnts) {
    int e = blockIdx.x * blockDim.x + threadIdx.x;
    if (e < N_EDGES) atomicAdd(&cnts[dst[e]], 1);
}

__global__ void scanA(const int* __restrict__ cnts, int* __restrict__ prow,
                      int* __restrict__ bsum) {
    __shared__ int wsum[16];
    int tid = threadIdx.x, lane = tid & 63, wid = tid >> 6;
    int i0 = blockIdx.x * 2048 + tid * 2;
    int v0 = 0, v1 = 0;
    if (i0 >= 1 && i0 <= N_NODES) v0 = (cnts[i0 - 1] + 1) & ~1;
    if (i0 + 1 <= N_NODES && i0 + 1 >= 1) v1 = (cnts[i0] + 1) & ~1;
    int v = v0 + v1;
#pragma unroll
    for (int off = 1; off < 64; off <<= 1) {
        int t = __shfl_up(v, off, 64);
        if (lane >= off) v += t;
    }
    if (lane == 63) wsum[wid] = v;
    __syncthreads();
    if (tid == 0) { int a = 0; for (int w = 0; w < 16; w++) { a += wsum[w]; wsum[w] = a; } }
    __syncthreads();
    int incl = v + (wid ? wsum[wid - 1] : 0);
    if (i0 <= N_NODES) prow[i0] = incl - v1;
    if (i0 + 1 <= N_NODES) prow[i0 + 1] = incl;
    if (tid == 1023) bsum[blockIdx.x] = incl;   // raw per-block total
}
// fused cross-block prefix + cursor init (bsum holds raw block totals)
__global__ void scanC(const int* __restrict__ bsum, int* __restrict__ prow,
                      int* __restrict__ cursor) {
    int i = blockIdx.x * 1024 + threadIdx.x;
    if (i > N_NODES) return;
    int nb = (int)(blockIdx.x >> 1);
    int add = 0;
    for (int b = 0; b < nb; b++) add += bsum[b];
    int v = prow[i] + add;
    prow[i] = v;
    if (i < N_NODES) cursor[i] = v;
}

__global__ void scatter_kernel(const int* __restrict__ dst, const int* __restrict__ src,
                               int* __restrict__ cursor, int* __restrict__ perm,
                               int* __restrict__ srcs) {
    int e = blockIdx.x * blockDim.x + threadIdx.x;
    if (e >= N_EDGES) return;
    int p = atomicAdd(&cursor[dst[e]], 1);
    perm[e] = p;
    srcs[p] = src[e];
}

// ---------------- MFMA layer building blocks ----------------
// D = Wfrag(A) x ActFrag(B) -> D[n][m]: m = lane&15, n = nt*16 + (lane>>4)*4 + reg.

template<int KT, int NT, int INSTR>
__device__ __forceinline__ void mfma_layer(const u32* ldsin, int lane,
        const short8* __restrict__ Wf, int basef, const float* __restrict__ bias, f32x4* acc) {
    int q = lane >> 4, mr = lane & 15;
#pragma unroll
    for (int nt = 0; nt < NT; nt++) acc[nt] = *(const f32x4*)(bias + nt * 16 + q * 4);
#pragma unroll
    for (int kt = 0; kt < KT; kt++) {
        short8 act = *(const short8*)(ldsin + mr * INSTR + kt * 16 + q * 4);
#pragma unroll
        for (int nt = 0; nt < NT; nt++)
            acc[nt] = mfma16(Wf[(basef + kt * NT + nt) * 64 + lane], act, acc[nt]);
    }
}

template<int KT, int NT>
__device__ __forceinline__ void mfma_layer_reg(const short8* act, int lane,
        const short8* __restrict__ Wf, int basef, const float* __restrict__ bias, f32x4* acc) {
    int q = lane >> 4;
#pragma unroll
    for (int nt = 0; nt < NT; nt++) acc[nt] = *(const f32x4*)(bias + nt * 16 + q * 4);
#pragma unroll
    for (int kt = 0; kt < KT; kt++)
#pragma unroll
        for (int nt = 0; nt < NT; nt++)
            acc[nt] = mfma16(Wf[(basef + kt * NT + nt) * 64 + lane], act[kt], acc[nt]);
}

template<int NT, int OUTSTR>
__device__ __forceinline__ void tanh_pack_lds(const f32x4* acc, u32* ldsout, int lane,
                                              const float2* __restrict__ tbl) {
    int q = lane >> 4, mr = lane & 15;
#pragma unroll
    for (int nt = 0; nt < NT; nt++) {
        f32x4 a = acc[nt];
        ldsout[mr * OUTSTR + nt * 8 + q * 2 + 0] = pack2(lut_tanh(tbl, a[0]), lut_tanh(tbl, a[1]));
        ldsout[mr * OUTSTR + nt * 8 + q * 2 + 1] = pack2(lut_tanh(tbl, a[2]), lut_tanh(tbl, a[3]));
    }
}

// full-wave zero-fill of the 16x16-dword staging region (stride-36 rows)
__device__ __forceinline__ void zero_stage(u32* B0, int lane) {
#pragma unroll
    for (int it = 0; it < 4; it++) {
        int f = lane + 64 * it;
        B0[(f >> 4) * 36 + (f & 15)] = 0;
    }
}

// ---------------- encoders / MLP / head ----------------

__global__ __launch_bounds__(256) void edge_encoder(const void* ef, u32* __restrict__ ebuf,
        const int* __restrict__ perm, const float* __restrict__ W,
        const short8* __restrict__ Wf, const float2* __restrict__ gtbl, const int* flag) {
    __shared__ u32 lds[4 * 1152];
    __shared__ float2 tbl[TANH_TBL_N];
    load_tbl(gtbl, tbl);
    int wv = threadIdx.x >> 6, lane = threadIdx.x & 63;
    u32* B0 = lds + wv * 1152;
    u32* B1 = B0 + 576;
    long ebase = (long)blockIdx.x * 64 + wv * 16;
    bool bf = (*flag != 0);
    zero_stage(B0, lane);
    if (lane < 16) {
        long e = ebase + lane;   // N_EDGES % 64 == 0: always valid
        float i0, i1, i2;
        if (bf) { const u16* p = (const u16*)ef + e * 3; i0 = b2f(p[0]); i1 = b2f(p[1]); i2 = b2f(p[2]); }
        else    { const float* p = (const float*)ef + e * 3; i0 = p[0]; i1 = p[1]; i2 = p[2]; }
        u32* row = B0 + lane * 36;
        row[0] = pack2(i0, i1); row[1] = pack2(i2, 0.f);
    }
    WAVE_SYNC();
    f32x4 acc[4];
    mfma_layer<1, 4, 36>(B0, lane, Wf, FR_EE1, W + EE_B0, acc);
    tanh_pack_lds<4, 36>(acc, B1, lane, tbl);
    WAVE_SYNC();
    mfma_layer<2, 4, 36>(B1, lane, Wf, FR_EE2, W + EE_B1, acc);
    tanh_pack_lds<4, 36>(acc, B0, lane, tbl);
    WAVE_SYNC();
    mfma_layer<2, 4, 36>(B0, lane, Wf, FR_EE3, W + EE_B2, acc);
    tanh_pack_lds<4, 36>(acc, B1, lane, tbl);
    WAVE_SYNC();
    int ro = lane >> 2, cc = (lane & 3) * 8;
    long e = ebase + ro;
    long prowp = perm[e];
    u32x4 v0 = *(const u32x4*)&B1[ro * 36 + cc];
    u32x4 v1 = *(const u32x4*)&B1[ro * 36 + cc + 4];
    *(u32x4*)&ebuf[prowp * 32 + cc] = v0;
    *(u32x4*)&ebuf[prowp * 32 + cc + 4] = v1;
}

__global__ __launch_bounds__(256) void node_encoder(const void* nf,
        u16* __restrict__ xbf, const float* __restrict__ W,
        const short8* __restrict__ Wf, const float2* __restrict__ gtbl, const int* flag) {
    __shared__ u32 lds[4 * 1152];
    __shared__ float2 tbl[TANH_TBL_N];
    load_tbl(gtbl, tbl);
    int wv = threadIdx.x >> 6, lane = threadIdx.x & 63;
    int q = lane >> 4, mr = lane & 15;
    u32* B0 = lds + wv * 1152;
    u32* B1 = B0 + 576;
    long nbase = (long)blockIdx.x * 64 + wv * 16;
    bool bf = (*flag != 0);
    zero_stage(B0, lane);
    if (lane < 16) {
        long n = nbase + lane;
        if (n < N_NODES) {
            float in[11];
#pragma unroll
            for (int j = 0; j < 11; j++)
                in[j] = bf ? b2f(((const u16*)nf)[n * 11 + j]) : ((const float*)nf)[n * 11 + j];
            u32* row = B0 + lane * 36;
#pragma unroll
            for (int d = 0; d < 5; d++) row[d] = pack2(in[2 * d], in[2 * d + 1]);
            row[5] = pack2(in[10], 0.f);
        }
    }
    WAVE_SYNC();
    f32x4 acc[4];
    mfma_layer<1, 4, 36>(B0, lane, Wf, FR_NE1, W + NE_B0, acc);
    tanh_pack_lds<4, 36>(acc, B1, lane, tbl);
    WAVE_SYNC();
    mfma_layer<2, 4, 36>(B1, lane, Wf, FR_NE2, W + NE_B1, acc);
    tanh_pack_lds<4, 36>(acc, B0, lane, tbl);
    WAVE_SYNC();
    mfma_layer<2, 4, 36>(B0, lane, Wf, FR_NE3, W + NE_B2, acc);
    long n = nbase + mr;
    if (n < N_NODES) {
#pragma unroll
        for (int nt = 0; nt < 4; nt++) {
            float v0 = lut_tanh(tbl, acc[nt][0]), v1 = lut_tanh(tbl, acc[nt][1]);
            float v2 = lut_tanh(tbl, acc[nt][2]), v3 = lut_tanh(tbl, acc[nt][3]);
            u32x2 pb; pb.x = pack2(v0, v1); pb.y = pack2(v2, v3);
            *(u32x2*)&xbf[n * 64 + nt * 16 + q * 4] = pb;
        }
    }
}

// 2 nodes per wave; srcs window staged to per-wave LDS (outer loop), inner loops
// branchless so the ds_read -> gather chain can be pipelined. Pads: src=-1 -> w=0.
__global__ __launch_bounds__(256) void aggregate_kernel(
        const u32* __restrict__ xbf32, const u32* __restrict__ ebuf32,
        const int* __restrict__ srcs, const int* __restrict__ prow,
        u32* __restrict__ h64bf32) {
    __shared__ int ldsW[4][64];
    int wv = threadIdx.x >> 6;
    int wid = (int)((blockIdx.x * 256 + threadIdx.x) >> 6);
    int lane = (int)(threadIdx.x & 63);
    int n0 = __builtin_amdgcn_readfirstlane(wid) * 2;
    if (n0 >= N_NODES) return;
    int half = lane >> 5, h = lane & 31;
    int rl = n0 + (lane < 2 ? lane : 2);
    int rv = prow[rl];
    int kb0 = __shfl(rv, 0, 64);
    int kb1 = __shfl(rv, 1, 64);
    int kb2 = __shfl(rv, 2, 64);
    float num[2][2], den[2][2];
#pragma unroll
    for (int j = 0; j < 2; j++) { num[j][0] = num[j][1] = den[j][0] = den[j][1] = 0.f; }
    for (int wb = kb0; wb < kb2; wb += 64) {
        ldsW[wv][lane] = srcs[wb + lane];
        WAVE_SYNC();
        int we = wb + 64;
        int hi0 = kb1 < we ? kb1 : we;
        int lo1 = kb1 > wb ? kb1 : wb;
        int hi1 = kb2 < we ? kb2 : we;
#pragma unroll 2
        for (int k = wb; k < hi0; k += 2) {
            int s = ldsW[wv][k - wb + half];
            u32 ev = ebuf32[(size_t)(k + half) * 32 + h];
            u32 xv = xbf32[(size_t)(s > 0 ? s : 0) * 32 + h];
            float m0 = fmaxf(lo2f(xv) + lo2f(ev), 0.f) + 1e-7f;
            float m1 = fmaxf(hi2f(xv) + hi2f(ev), 0.f) + 1e-7f;
            float w0 = __expf(m0), w1 = __expf(m1);
            if (s < 0) { w0 = 0.f; w1 = 0.f; }
            num[0][0] = fmaf(w0, m0, num[0][0]); den[0][0] += w0;
            num[0][1] = fmaf(w1, m1, num[0][1]); den[0][1] += w1;
        }
#pragma unroll 2
        for (int k = lo1; k < hi1; k += 2) {
            int s = ldsW[wv][k - wb + half];
            u32 ev = ebuf32[(size_t)(k + half) * 32 + h];
            u32 xv = xbf32[(size_t)(s > 0 ? s : 0) * 32 + h];
            float m0 = fmaxf(lo2f(xv) + lo2f(ev), 0.f) + 1e-7f;
            float m1 = fmaxf(hi2f(xv) + hi2f(ev), 0.f) + 1e-7f;
            float w0 = __expf(m0), w1 = __expf(m1);
            if (s < 0) { w0 = 0.f; w1 = 0.f; }
            num[1][0] = fmaf(w0, m0, num[1][0]); den[1][0] += w0;
            num[1][1] = fmaf(w1, m1, num[1][1]); den[1][1] += w1;
        }
        WAVE_SYNC();   // drain reads before next window overwrite (in-order DS, cheap)
    }
#pragma unroll
    for (int j = 0; j < 2; j++) {
        float n0f = num[j][0] + __shfl_xor(num[j][0], 32, 64);
        float d0f = den[j][0] + __shfl_xor(den[j][0], 32, 64);
        float n1f = num[j][1] + __shfl_xor(num[j][1], 32, 64);
        float d1f = den[j][1] + __shfl_xor(den[j][1], 32, 64);
        if (half == 0) {
            float agg0 = (d0f > 0.f) ? __fdividef(n0f, d0f) : 0.f;
            float agg1 = (d1f > 0.f) ? __fdividef(n1f, d1f) : 0.f;
            u32 xr = xbf32[(size_t)(n0 + j) * 32 + h];
            h64bf32[(size_t)(n0 + j) * 32 + h] = pack2(lo2f(xr) + agg0, hi2f(xr) + agg1);
        }
    }
}

// fused node MLP: 64->128 (acts direct from h64bf), LN (shfl), ReLU, 128->64
__global__ __launch_bounds__(256) void mlp_fused(const u16* __restrict__ h64bf,
        u16* __restrict__ xbf,
        const float* __restrict__ W, const short8* __restrict__ Wf, int r) {
    __shared__ u32 lds[4 * 1088];
    int wv = threadIdx.x >> 6, lane = threadIdx.x & 63;
    int q = lane >> 4, mr = lane & 15;
    u32* bufY = lds + wv * 1088;
    long nbase = (long)blockIdx.x * 64 + wv * 16;
    long row = nbase + mr;
    long rc = (row < N_NODES) ? row : (N_NODES - 1);
    short8 act[2];
#pragma unroll
    for (int kt = 0; kt < 2; kt++)
        act[kt] = *(const short8*)&h64bf[rc * 64 + kt * 32 + q * 8];
    f32x4 acc[8];
    mfma_layer_reg<2, 8>(act, lane, Wf, FR_MP0 + r * 16, W + MP_B0 + r * 128, acc);
    float s = 0.f, sq = 0.f;
#pragma unroll
    for (int nt = 0; nt < 8; nt++)
#pragma unroll
        for (int rr = 0; rr < 4; rr++) { float v = acc[nt][rr]; s += v; sq = fmaf(v, v, sq); }
    s += __shfl_xor(s, 16, 64);  s += __shfl_xor(s, 32, 64);
    sq += __shfl_xor(sq, 16, 64); sq += __shfl_xor(sq, 32, 64);
    float mu = s * (1.f / 128.f);
    float var = sq * (1.f / 128.f) - mu * mu;
    float inv = rsqrtf(var + 1e-5f);
    const float* LW = W + LNW_O + r * 128;
    const float* LB = W + LNB_O + r * 128;
#pragma unroll
    for (int nt = 0; nt < 8; nt++) {
        f32x4 lw = *(const f32x4*)(LW + nt * 16 + q * 4);
        f32x4 lb = *(const f32x4*)(LB + nt * 16 + q * 4);
        float u0 = fmaxf(fmaf((acc[nt][0] - mu) * inv, lw[0], lb[0]), 0.f);
        float u1 = fmaxf(fmaf((acc[nt][1] - mu) * inv, lw[1], lb[1]), 0.f);
        float u2 = fmaxf(fmaf((acc[nt][2] - mu) * inv, lw[2], lb[2]), 0.f);
        float u3 = fmaxf(fmaf((acc[nt][3] - mu) * inv, lw[3], lb[3]), 0.f);
        bufY[mr * 68 + nt * 8 + q * 2 + 0] = pack2(u0, u1);
        bufY[mr * 68 + nt * 8 + q * 2 + 1] = pack2(u2, u3);
    }
    WAVE_SYNC();
    f32x4 acc2[4];
    mfma_layer<4, 4, 68>(bufY, lane, Wf, FR_MP1 + r * 16, W + MP_B1 + r * 64, acc2);
    if (row < N_NODES) {
#pragma unroll
        for (int nt = 0; nt < 4; nt++) {
            f32x4 v = acc2[nt];
            u32x2 pb; pb.x = pack2(v[0], v[1]); pb.y = pack2(v[2], v[3]);
            *(u32x2*)&xbf[row * 64 + nt * 16 + q * 4] = pb;
        }
    }
}

__global__ __launch_bounds__(256) void policy_head(const u16* __restrict__ xbf, void* out,
        const float* __restrict__ W, const short8* __restrict__ Wf,
        const float2* __restrict__ gtbl, const int* flag) {
    __shared__ u32 lds[4 * 576];
    __shared__ float2 tbl[TANH_TBL_N];
    load_tbl(gtbl, tbl);
    int wv = threadIdx.x >> 6, lane = threadIdx.x & 63;
    int q = lane >> 4, mr = lane & 15;
    u32* bufY = lds + wv * 576;
    long nbase = (long)blockIdx.x * 64 + wv * 16;
    long row = nbase + mr;
    long rc = (row < N_NODES) ? row : (N_NODES - 1);
    bool bf = (*flag != 0);
    short8 act[2];
#pragma unroll
    for (int kt = 0; kt < 2; kt++)
        act[kt] = *(const short8*)&xbf[rc * 64 + kt * 32 + q * 8];
    f32x4 acc[4];
    mfma_layer_reg<2, 4>(act, lane, Wf, FR_PI0, W + PI_B0, acc);
    tanh_pack_lds<4, 36>(acc, bufY, lane, tbl);
    WAVE_SYNC();
    mfma_layer<2, 4, 36>(bufY, lane, Wf, FR_PI1, W + PI_B1, acc);
    float o = 0.f;
#pragma unroll
    for (int nt = 0; nt < 4; nt++) {
        f32x4 w2 = *(const f32x4*)(W + PI_W2 + nt * 16 + q * 4);
#pragma unroll
        for (int rr = 0; rr < 4; rr++) o = fmaf(lut_tanh(tbl, acc[nt][rr]), w2[rr], o);
    }
    o += __shfl_xor(o, 16, 64);
    o += __shfl_xor(o, 32, 64);
    if (lane < 16 && row < N_NODES) {
        float means = 30.f * (o + W[PI_B2]);
        if (bf) ((u16*)out)[row] = f2b(means);
        else    ((float*)out)[row] = means;
    }
}

// ---------------- launch ----------------
extern "C" void kernel_launch(void* const* d_in, const int* in_sizes, int n_in,
                              void* d_out, int out_size, void* d_ws, size_t ws_size,
                              hipStream_t stream) {
    char* ws = (char*)d_ws;
    float* W      = (float*)(ws + OFF_W);
    int*   flag   = (int*)(ws + OFF_FLAG);
    u16*   Wb     = (u16*)(ws + OFF_WB);
    const short8* Wf = (const short8*)(ws + OFF_WB);
    float2* gtbl  = (float2*)(ws + OFF_TBL);
    u16*   xb0    = (u16*)(ws + OFF_XB0);
    u16*   xb1    = (u16*)(ws + OFF_XB1);
    u16*   h64bf  = (u16*)(ws + OFF_H64B);
    u32*   h64b32 = (u32*)(ws + OFF_H64B);
    u32*   ebuf32 = (u32*)(ws + OFF_E);
    int*   prow   = (int*)(ws + OFF_ROWPTR);
    int*   cursor = (int*)(ws + OFF_CURSOR);
    int*   cnts   = (int*)(ws + OFF_CNT);
    int*   perm   = (int*)(ws + OFF_PERM);
    int*   srcs   = (int*)(ws + OFF_SRCS);
    int*   bsum   = (int*)(ws + OFF_BSUM);

    const int* ei   = (const int*)d_in[2];
    const int* srcv = ei;
    const int* dstv = ei + N_EDGES;

    detect_kernel<<<1, 64, 0, stream>>>(d_in[0], flag);
    hipMemsetAsync(cnts, 0, N_NODES * sizeof(int), stream);
    hipMemsetAsync(srcs, 0xFF, (size_t)0x340000, stream);   // srcs = -1 (pad marker)

    Ptrs24 ps;
    for (int k = 0; k < 24; k++) ps.p[k] = d_in[3 + k];
    convert_weights<<<(W_TOTAL + 255) / 256, 256, 0, stream>>>(ps, W, flag);
    make_frags<<<(FR_TOTAL * 512 + TANH_TBL_N + 255) / 256, 256, 0, stream>>>(W, Wb, gtbl);

    hist_kernel<<<(N_EDGES + 255) / 256, 256, 0, stream>>>(dstv, cnts);
    scanA<<<25, 1024, 0, stream>>>(cnts, prow, bsum);
    scanC<<<(N_NODES + 1024) / 1024, 1024, 0, stream>>>(bsum, prow, cursor);
    scatter_kernel<<<(N_EDGES + 255) / 256, 256, 0, stream>>>(dstv, srcv, cursor, perm, srcs);

    node_encoder<<<(N_NODES + 63) / 64, 256, 0, stream>>>(d_in[0], xb0, W, Wf, gtbl, flag);
    edge_encoder<<<N_EDGES / 64, 256, 0, stream>>>(d_in[1], ebuf32, perm, W, Wf, gtbl, flag);

    u16* xbc = xb0; u16* xbn = xb1;
    const int aggBlocks = (N_NODES / 2 * 64) / 256;   // 2 nodes/wave, 4 waves/block
    for (int r = 0; r < 3; r++) {
        aggregate_kernel<<<aggBlocks, 256, 0, stream>>>(
            (const u32*)xbc, ebuf32, srcs, prow, h64b32);
        mlp_fused<<<(N_NODES + 63) / 64, 256, 0, stream>>>(h64bf, xbn, W, Wf, r);
        u16* tb = xbc; xbc = xbn; xbn = tb;
    }
    policy_head<<<(N_NODES + 63) / 64, 256, 0, stream>>>(xbc, d_out, W, Wf, gtbl, flag);
}

// Round 8
// 420.759 us; speedup vs baseline: 4.8495x; 1.0264x over previous
//
#include <hip/hip_runtime.h>
#include <hip/hip_fp16.h>
#include <stdint.h>

#define N_NODES 50000
#define N_EDGES 800000

typedef unsigned short u16;
typedef unsigned int u32;
typedef __attribute__((ext_vector_type(8))) short short8;   // 8 bf16 = A/B frag
typedef __attribute__((ext_vector_type(4))) float f32x4;    // C/D frag
typedef __attribute__((ext_vector_type(4))) u32 u32x4;
typedef __attribute__((ext_vector_type(2))) u32 u32x2;

// wave-private LDS exchange: DS ops in-order per wave; only lgkmcnt drain needed.
#define WAVE_SYNC() asm volatile("s_waitcnt lgkmcnt(0)" ::: "memory")

// ---------------- helpers ----------------
__device__ __forceinline__ float b2f(u16 v) {
    u32 u = ((u32)v) << 16; float f; __builtin_memcpy(&f, &u, 4); return f;
}
__device__ __forceinline__ u16 f2b(float f) {
    u32 u; __builtin_memcpy(&u, &f, 4);
    return (u16)((u + 0x8000u) >> 16);
}
__device__ __forceinline__ float lo2f(u32 p) {
    u32 u = p << 16; float f; __builtin_memcpy(&f, &u, 4); return f;
}
__device__ __forceinline__ float hi2f(u32 p) {
    u32 u = p & 0xffff0000u; float f; __builtin_memcpy(&f, &u, 4); return f;
}
// pack two f32 -> two bf16 (round-half-up) in 3 ops via v_perm_b32
__device__ __forceinline__ u32 pack2(float a, float b) {
    u32 ua, ub; __builtin_memcpy(&ua, &a, 4); __builtin_memcpy(&ub, &b, 4);
    return __builtin_amdgcn_perm(ub + 0x8000u, ua + 0x8000u, 0x07060302u);
}
__device__ __forceinline__ f32x4 mfma16(short8 a, short8 b, f32x4 c) {
    return __builtin_amdgcn_mfma_f32_16x16x32_bf16(a, b, c, 0, 0, 0);
}

// bf16-vs-f32 input detection, inlined per block (all waves read the same 64
// dwords of node_features -> identical, wave-uniform result).
__device__ __forceinline__ bool detect_bf(const void* nf) {
    u32 w = ((const u32*)nf)[threadIdx.x & 63];
    u32 lo = w & 0xffffu;
    int e = (int)((lo >> 7) & 0xff);
    int good = ((e >= 118 && e <= 132) || lo == 0) ? 1 : 0;
    unsigned long long b = __ballot(good != 0);
    return __popcll(b) >= 48;
}

// ---- LUT tanh: 256 segments (f16 intercept/slope packed in u32), step 1/32
// over [0,8); y = fma(s, a, b), sign via v_bfi. err ~1e-3 (< bf16 storage noise).
#define TANH_TBL_N 256
__device__ __forceinline__ void load_tbl(const u32* __restrict__ g, u32* tbl) {
    int i = (int)threadIdx.x;
    if (i < TANH_TBL_N) tbl[i] = g[i];
    __syncthreads();
}
__device__ __forceinline__ float lut_tanh(const u32* __restrict__ tbl, float x) {
    float a = __builtin_fabsf(x);
    a = fminf(a, 7.96875f);
    int i = (int)(a * 32.f);
    u32 e = tbl[i];
    __half2 h2; __builtin_memcpy(&h2, &e, 4);
    float b = __half2float(__low2half(h2));
    float s = __half2float(__high2half(h2));
    return copysignf(fmaf(s, a, b), x);
}

// ---------------- f32 weight buffer offsets (biases/LN/head only) ----------------
enum : int {
    NE_B0 = 704,   NE_B1 = 4864,  NE_B2 = 9024,
    EE_B0 = 9280,  EE_B1 = 13440, EE_B2 = 17600,
    MP_B0 = 42240, LNW_O = 42624, LNB_O = 43008, MP_B1 = 67968,
    PI_B0 = 72256, PI_B1 = 76416, PI_W2 = 76480, PI_B2 = 76608,
    W_TOTAL = 76610
};

// fragment-buffer layer bases (frag id; 512 bf16 per frag)
enum : int {
    FR_EE1 = 0, FR_EE2 = 4, FR_EE3 = 12, FR_NE1 = 20, FR_NE2 = 24, FR_NE3 = 32,
    FR_MP0 = 40, FR_MP1 = 88, FR_PI0 = 136, FR_PI1 = 144, FR_TOTAL = 152
};

// ---------------- workspace layout (bytes) ----------------
#define OFF_W       ((size_t)0)
#define OFF_WB      ((size_t)0x61000)      // 152*512*2 = 155648 B
#define OFF_TBL     ((size_t)0x88000)      // 256 u32 = 1 KB
#define OFF_XB0     ((size_t)0x90000)      // 6.4 MB bf16
#define OFF_XB1     ((size_t)0x700000)     // 6.4 MB bf16
#define OFF_H64B    ((size_t)0xE00000)     // 6.4 MB bf16
#define OFF_E       ((size_t)0x1500000)    // ebuf: up to 850k x 64 bf16
#define OFF_ROWPTR  ((size_t)0x8300000)    // prow (padded CSR), N+1 ints
#define OFF_CURSOR  ((size_t)0x8340000)
#define OFF_CNT     ((size_t)0x8380000)
#define OFF_PERM    ((size_t)0x83C0000)
#define OFF_SRCS    ((size_t)0x8700000)    // 851968+ ints; pads written by scanC
#define OFF_BSUM    ((size_t)0x8A80000)

struct Ptrs24 { const void* p[24]; };
// index map within Ptrs24 (= d_in[3+i]):
// 0 ne_w0 1 ne_b0 2 ne_w1 3 ne_b1 4 ne_w2 5 ne_b2 6 ee_w0 7 ee_b0 8 ee_w1 9 ee_b1
// 10 ee_w2 11 ee_b2 12 mp_w0 13 mp_b0 14 mp_ln_w 15 mp_ln_b 16 mp_w1 17 mp_b1
// 18 pi_w0 19 pi_b0 20 pi_w1 21 pi_b1 22 pi_w2 23 pi_b2

// ---------------- one-shot prep: frag bake + bias convert + tanh LUT ----------------
__global__ void prep_kernel(const void* nf, Ptrs24 ps, float* __restrict__ W,
                            u16* __restrict__ Wb, u32* __restrict__ gtbl) {
    bool bf = detect_bf(nf);
    int t = blockIdx.x * blockDim.x + threadIdx.x;
    if (t < FR_TOTAL * 512) {
        // bake bf16 MFMA A-frag directly from source weights (w[n][k] row-major)
        const int base[15] = {FR_EE1,FR_EE2,FR_EE3,FR_NE1,FR_NE2,FR_NE3,
                              FR_MP0,FR_MP0+16,FR_MP0+32, FR_MP1,FR_MP1+16,FR_MP1+32,
                              FR_PI0,FR_PI1,FR_TOTAL};
        const int psrc[14]  = {6,8,10, 0,2,4, 12,12,12, 16,16,16, 18,20};
        const int soff[14]  = {0,0,0, 0,0,0, 0,8192,16384, 0,8192,16384, 0,0};
        const int kreal[14] = {3,64,64, 11,64,64, 64,64,64, 128,128,128, 64,64};
        const int nn[14]    = {64,64,64, 64,64,64, 128,128,128, 64,64,64, 64,64};
        int f = t >> 9, r = t & 511, lane = r >> 3, j = r & 7;
        int l = 0;
        while (f >= base[l + 1]) l++;
        int lf = f - base[l];
        int NT = nn[l] >> 4;
        int kt = lf / NT, nt = lf % NT;
        int k = kt * 32 + (lane >> 4) * 8 + j;
        int n = nt * 16 + (lane & 15);
        float v = 0.f;
        if (k < kreal[l]) {
            long idx = (long)soff[l] + (long)n * kreal[l] + k;
            const void* p = ps.p[psrc[l]];
            v = bf ? b2f(((const u16*)p)[idx]) : ((const float*)p)[idx];
        }
        u32 u; __builtin_memcpy(&u, &v, 4);
        Wb[t] = (u16)((u + 0x7fffu + ((u >> 16) & 1u)) >> 16);   // RNE
        return;
    }
    int t2 = t - FR_TOTAL * 512;
    if (t2 < 1986) {
        // convert biases / LN params / head weights to f32 W buffer
        const int cnt[14]  = {64,64,64, 64,64,64, 384,384,384,192, 64,64,128,2};
        const int wdst[14] = {NE_B0,NE_B1,NE_B2, EE_B0,EE_B1,EE_B2,
                              MP_B0,LNW_O,LNB_O,MP_B1, PI_B0,PI_B1,PI_W2,PI_B2};
        const int sp[14]   = {1,3,5, 7,9,11, 13,14,15,17, 19,21,22,23};
        int sgi = 0, off = t2;
        while (off >= cnt[sgi]) { off -= cnt[sgi]; sgi++; }
        const void* p = ps.p[sp[sgi]];
        W[wdst[sgi] + off] = bf ? b2f(((const u16*)p)[off]) : ((const float*)p)[off];
        return;
    }
    int i = t2 - 1986;
    if (i < TANH_TBL_N) {
        float x0 = i * 0.03125f, x1 = x0 + 0.03125f;
        float t0 = tanhf(x0), t1 = tanhf(x1);
        float s = (t1 - t0) * 32.f;
        float b = fmaf(-s, x0, t0);
        __half hs = __float2half(s), hb = __float2half(b);
        u16 us, ub;
        __builtin_memcpy(&us, &hs, 2); __builtin_memcpy(&ub, &hb, 2);
        gtbl[i] = (u32)ub | ((u32)us << 16);
    }
}

// ---------------- graph build (even-padded CSR) ----------------

__global__ void hist_kernel(const int* __restrict__ dst, int* __restrict__ cnts) {
    int e = blockIdx.x * blockDim.x + threadIdx.x;
    if (e < N_EDGES) atomicAdd(&cnts[dst[e]], 1);
}

__global__ void scanA(const int* __restrict__ cnts, int* __restrict__ prow,
                      int* __restrict__ bsum) {
    __shared__ int wsum[16];
    int tid = threadIdx.x, lane = tid & 63, wid = tid >> 6;
    int i0 = blockIdx.x * 2048 + tid * 2;
    int v0 = 0, v1 = 0;
    if (i0 >= 1 && i0 <= N_NODES) v0 = (cnts[i0 - 1] + 1) & ~1;
    if (i0 + 1 <= N_NODES && i0 + 1 >= 1) v1 = (cnts[i0] + 1) & ~1;
    int v = v0 + v1;
#pragma unroll
    for (int off = 1; off < 64; off <<= 1) {
        int t = __shfl_up(v, off, 64);
        if (lane >= off) v += t;
    }
    if (lane == 63) wsum[wid] = v;
    __syncthreads();
    if (tid == 0) { int a = 0; for (int w = 0; w < 16; w++) { a += wsum[w]; wsum[w] = a; } }
    __syncthreads();
    int incl = v + (wid ? wsum[wid - 1] : 0);
    if (i0 <= N_NODES) prow[i0] = incl - v1;
    if (i0 + 1 <= N_NODES) prow[i0 + 1] = incl;
    if (tid == 1023) bsum[blockIdx.x] = incl;   // raw per-block total
}
// cross-block prefix + cursor init + pad-slot marking (replaces srcs memset)
__global__ void scanC(const int* __restrict__ bsum, const int* __restrict__ cnts,
                      int* __restrict__ prow, int* __restrict__ cursor,
                      int* __restrict__ srcs) {
    int i = blockIdx.x * 1024 + threadIdx.x;
    if (i > N_NODES) return;
    int nb = (int)(blockIdx.x >> 1);
    int add = 0;
    for (int b = 0; b < nb; b++) add += bsum[b];
    int v = prow[i] + add;
    prow[i] = v;
    if (i < N_NODES) {
        cursor[i] = v;
        int c = cnts[i];
        if (c & 1) srcs[v + c] = -1;   // pad marker for odd-degree nodes
    }
}

__global__ void scatter_kernel(const int* __restrict__ dst, const int* __restrict__ src,
                               int* __restrict__ cursor, int* __restrict__ perm,
                               int* __restrict__ srcs) {
    int e = blockIdx.x * blockDim.x + threadIdx.x;
    if (e >= N_EDGES) return;
    int p = atomicAdd(&cursor[dst[e]], 1);
    perm[e] = p;
    srcs[p] = src[e];
}

// ---------------- MFMA layer building blocks ----------------
// D = Wfrag(A) x ActFrag(B) -> D[n][m]: m = lane&15, n = nt*16 + (lane>>4)*4 + reg.

template<int KT, int NT, int INSTR>
__device__ __forceinline__ void mfma_layer(const u32* ldsin, int lane,
        const short8* __restrict__ Wf, int basef, const float* __restrict__ bias, f32x4* acc) {
    int q = lane >> 4, mr = lane & 15;
#pragma unroll
    for (int nt = 0; nt < NT; nt++) acc[nt] = *(const f32x4*)(bias + nt * 16 + q * 4);
#pragma unroll
    for (int kt = 0; kt < KT; kt++) {
        short8 act = *(const short8*)(ldsin + mr * INSTR + kt * 16 + q * 4);
#pragma unroll
        for (int nt = 0; nt < NT; nt++)
            acc[nt] = mfma16(Wf[(basef + kt * NT + nt) * 64 + lane], act, acc[nt]);
    }
}

template<int KT, int NT>
__device__ __forceinline__ void mfma_layer_reg(const short8* act, int lane,
        const short8* __restrict__ Wf, int basef, const float* __restrict__ bias, f32x4* acc) {
    int q = lane >> 4;
#pragma unroll
    for (int nt = 0; nt < NT; nt++) acc[nt] = *(const f32x4*)(bias + nt * 16 + q * 4);
#pragma unroll
    for (int kt = 0; kt < KT; kt++)
#pragma unroll
        for (int nt = 0; nt < NT; nt++)
            acc[nt] = mfma16(Wf[(basef + kt * NT + nt) * 64 + lane], act[kt], acc[nt]);
}

template<int NT, int OUTSTR>
__device__ __forceinline__ void tanh_pack_lds(const f32x4* acc, u32* ldsout, int lane,
                                              const u32* __restrict__ tbl) {
    int q = lane >> 4, mr = lane & 15;
#pragma unroll
    for (int nt = 0; nt < NT; nt++) {
        f32x4 a = acc[nt];
        ldsout[mr * OUTSTR + nt * 8 + q * 2 + 0] = pack2(lut_tanh(tbl, a[0]), lut_tanh(tbl, a[1]));
        ldsout[mr * OUTSTR + nt * 8 + q * 2 + 1] = pack2(lut_tanh(tbl, a[2]), lut_tanh(tbl, a[3]));
    }
}

// full-wave zero-fill of the 16x16-dword staging region (stride-36 rows)
__device__ __forceinline__ void zero_stage(u32* B0, int lane) {
#pragma unroll
    for (int it = 0; it < 4; it++) {
        int f = lane + 64 * it;
        B0[(f >> 4) * 36 + (f & 15)] = 0;
    }
}

// ---------------- encoders / MLP / head ----------------

__global__ __launch_bounds__(256) void edge_encoder(const void* nf, const void* ef,
        u32* __restrict__ ebuf, const int* __restrict__ perm, const float* __restrict__ W,
        const short8* __restrict__ Wf, const u32* __restrict__ gtbl) {
    __shared__ u32 lds[4 * 1152];
    __shared__ u32 tbl[TANH_TBL_N];
    bool bf = detect_bf(nf);
    load_tbl(gtbl, tbl);
    int wv = threadIdx.x >> 6, lane = threadIdx.x & 63;
    u32* B0 = lds + wv * 1152;
    u32* B1 = B0 + 576;
    long ebase = (long)blockIdx.x * 64 + wv * 16;
    zero_stage(B0, lane);
    if (lane < 16) {
        long e = ebase + lane;   // N_EDGES % 64 == 0: always valid
        float i0, i1, i2;
        if (bf) { const u16* p = (const u16*)ef + e * 3; i0 = b2f(p[0]); i1 = b2f(p[1]); i2 = b2f(p[2]); }
        else    { const float* p = (const float*)ef + e * 3; i0 = p[0]; i1 = p[1]; i2 = p[2]; }
        u32* row = B0 + lane * 36;
        row[0] = pack2(i0, i1); row[1] = pack2(i2, 0.f);
    }
    WAVE_SYNC();
    f32x4 acc[4];
    mfma_layer<1, 4, 36>(B0, lane, Wf, FR_EE1, W + EE_B0, acc);
    tanh_pack_lds<4, 36>(acc, B1, lane, tbl);
    WAVE_SYNC();
    mfma_layer<2, 4, 36>(B1, lane, Wf, FR_EE2, W + EE_B1, acc);
    tanh_pack_lds<4, 36>(acc, B0, lane, tbl);
    WAVE_SYNC();
    mfma_layer<2, 4, 36>(B0, lane, Wf, FR_EE3, W + EE_B2, acc);
    tanh_pack_lds<4, 36>(acc, B1, lane, tbl);
    WAVE_SYNC();
    int ro = lane >> 2, cc = (lane & 3) * 8;
    long e = ebase + ro;
    long prowp = perm[e];
    u32x4 v0 = *(const u32x4*)&B1[ro * 36 + cc];
    u32x4 v1 = *(const u32x4*)&B1[ro * 36 + cc + 4];
    *(u32x4*)&ebuf[prowp * 32 + cc] = v0;
    *(u32x4*)&ebuf[prowp * 32 + cc + 4] = v1;
}

__global__ __launch_bounds__(256) void node_encoder(const void* nf,
        u16* __restrict__ xbf, const float* __restrict__ W,
        const short8* __restrict__ Wf, const u32* __restrict__ gtbl) {
    __shared__ u32 lds[4 * 1152];
    __shared__ u32 tbl[TANH_TBL_N];
    bool bf = detect_bf(nf);
    load_tbl(gtbl, tbl);
    int wv = threadIdx.x >> 6, lane = threadIdx.x & 63;
    int q = lane >> 4, mr = lane & 15;
    u32* B0 = lds + wv * 1152;
    u32* B1 = B0 + 576;
    long nbase = (long)blockIdx.x * 64 + wv * 16;
    zero_stage(B0, lane);
    if (lane < 16) {
        long n = nbase + lane;
        if (n < N_NODES) {
            float in[11];
#pragma unroll
            for (int j = 0; j < 11; j++)
                in[j] = bf ? b2f(((const u16*)nf)[n * 11 + j]) : ((const float*)nf)[n * 11 + j];
            u32* row = B0 + lane * 36;
#pragma unroll
            for (int d = 0; d < 5; d++) row[d] = pack2(in[2 * d], in[2 * d + 1]);
            row[5] = pack2(in[10], 0.f);
        }
    }
    WAVE_SYNC();
    f32x4 acc[4];
    mfma_layer<1, 4, 36>(B0, lane, Wf, FR_NE1, W + NE_B0, acc);
    tanh_pack_lds<4, 36>(acc, B1, lane, tbl);
    WAVE_SYNC();
    mfma_layer<2, 4, 36>(B1, lane, Wf, FR_NE2, W + NE_B1, acc);
    tanh_pack_lds<4, 36>(acc, B0, lane, tbl);
    WAVE_SYNC();
    mfma_layer<2, 4, 36>(B0, lane, Wf, FR_NE3, W + NE_B2, acc);
    long n = nbase + mr;
    if (n < N_NODES) {
#pragma unroll
        for (int nt = 0; nt < 4; nt++) {
            float v0 = lut_tanh(tbl, acc[nt][0]), v1 = lut_tanh(tbl, acc[nt][1]);
            float v2 = lut_tanh(tbl, acc[nt][2]), v3 = lut_tanh(tbl, acc[nt][3]);
            u32x2 pb; pb.x = pack2(v0, v1); pb.y = pack2(v2, v3);
            *(u32x2*)&xbf[n * 64 + nt * 16 + q * 4] = pb;
        }
    }
}

// 2 nodes per wave; srcs window staged to per-wave LDS; inner loops branchless.
// Pads: src=-1 -> w=0. Templated on round for profiler visibility.
template<int R>
__global__ __launch_bounds__(256) void aggregate_kernel(
        const u32* __restrict__ xbf32, const u32* __restrict__ ebuf32,
        const int* __restrict__ srcs, const int* __restrict__ prow,
        u32* __restrict__ h64bf32) {
    __shared__ int ldsW[4][64];
    int wv = threadIdx.x >> 6;
    int wid = (int)((blockIdx.x * 256 + threadIdx.x) >> 6);
    int lane = (int)(threadIdx.x & 63);
    int n0 = __builtin_amdgcn_readfirstlane(wid) * 2;
    if (n0 >= N_NODES) return;
    int half = lane >> 5, h = lane & 31;
    int rl = n0 + (lane < 2 ? lane : 2);
    int rv = prow[rl];
    int kb0 = __shfl(rv, 0, 64);
    int kb1 = __shfl(rv, 1, 64);
    int kb2 = __shfl(rv, 2, 64);
    float num[2][2], den[2][2];
#pragma unroll
    for (int j = 0; j < 2; j++) { num[j][0] = num[j][1] = den[j][0] = den[j][1] = 0.f; }
    for (int wb = kb0; wb < kb2; wb += 64) {
        ldsW[wv][lane] = srcs[wb + lane];
        WAVE_SYNC();
        int we = wb + 64;
        int hi0 = kb1 < we ? kb1 : we;
        int lo1 = kb1 > wb ? kb1 : wb;
        int hi1 = kb2 < we ? kb2 : we;
#pragma unroll 4
        for (int k = wb; k < hi0; k += 2) {
            int s = ldsW[wv][k - wb + half];
            u32 ev = ebuf32[(size_t)(k + half) * 32 + h];
            u32 xv = xbf32[(size_t)(s > 0 ? s : 0) * 32 + h];
            float m0 = fmaxf(lo2f(xv) + lo2f(ev), 0.f) + 1e-7f;
            float m1 = fmaxf(hi2f(xv) + hi2f(ev), 0.f) + 1e-7f;
            float w0 = __expf(m0), w1 = __expf(m1);
            if (s < 0) { w0 = 0.f; w1 = 0.f; }
            num[0][0] = fmaf(w0, m0, num[0][0]); den[0][0] += w0;
            num[0][1] = fmaf(w1, m1, num[0][1]); den[0][1] += w1;
        }
#pragma unroll 4
        for (int k = lo1; k < hi1; k += 2) {
            int s = ldsW[wv][k - wb + half];
            u32 ev = ebuf32[(size_t)(k + half) * 32 + h];
            u32 xv = xbf32[(size_t)(s > 0 ? s : 0) * 32 + h];
            float m0 = fmaxf(lo2f(xv) + lo2f(ev), 0.f) + 1e-7f;
            float m1 = fmaxf(hi2f(xv) + hi2f(ev), 0.f) + 1e-7f;
            float w0 = __expf(m0), w1 = __expf(m1);
            if (s < 0) { w0 = 0.f; w1 = 0.f; }
            num[1][0] = fmaf(w0, m0, num[1][0]); den[1][0] += w0;
            num[1][1] = fmaf(w1, m1, num[1][1]); den[1][1] += w1;
        }
        WAVE_SYNC();   // drain reads before next window overwrite
    }
#pragma unroll
    for (int j = 0; j < 2; j++) {
        float n0f = num[j][0] + __shfl_xor(num[j][0], 32, 64);
        float d0f = den[j][0] + __shfl_xor(den[j][0], 32, 64);
        float n1f = num[j][1] + __shfl_xor(num[j][1], 32, 64);
        float d1f = den[j][1] + __shfl_xor(den[j][1], 32, 64);
        if (half == 0) {
            float agg0 = (d0f > 0.f) ? __fdividef(n0f, d0f) : 0.f;
            float agg1 = (d1f > 0.f) ? __fdividef(n1f, d1f) : 0.f;
            u32 xr = xbf32[(size_t)(n0 + j) * 32 + h];
            h64bf32[(size_t)(n0 + j) * 32 + h] = pack2(lo2f(xr) + agg0, hi2f(xr) + agg1);
        }
    }
}

// fused node MLP: 64->128 (acts direct from h64bf), LN (shfl), ReLU, 128->64
__global__ __launch_bounds__(256) void mlp_fused(const u16* __restrict__ h64bf,
        u16* __restrict__ xbf,
        const float* __restrict__ W, const short8* __restrict__ Wf, int r) {
    __shared__ u32 lds[4 * 1088];
    int wv = threadIdx.x >> 6, lane = threadIdx.x & 63;
    int q = lane >> 4, mr = lane & 15;
    u32* bufY = lds + wv * 1088;
    long nbase = (long)blockIdx.x * 64 + wv * 16;
    long row = nbase + mr;
    long rc = (row < N_NODES) ? row : (N_NODES - 1);
    short8 act[2];
#pragma unroll
    for (int kt = 0; kt < 2; kt++)
        act[kt] = *(const short8*)&h64bf[rc * 64 + kt * 32 + q * 8];
    f32x4 acc[8];
    mfma_layer_reg<2, 8>(act, lane, Wf, FR_MP0 + r * 16, W + MP_B0 + r * 128, acc);
    float s = 0.f, sq = 0.f;
#pragma unroll
    for (int nt = 0; nt < 8; nt++)
#pragma unroll
        for (int rr = 0; rr < 4; rr++) { float v = acc[nt][rr]; s += v; sq = fmaf(v, v, sq); }
    s += __shfl_xor(s, 16, 64);  s += __shfl_xor(s, 32, 64);
    sq += __shfl_xor(sq, 16, 64); sq += __shfl_xor(sq, 32, 64);
    float mu = s * (1.f / 128.f);
    float var = sq * (1.f / 128.f) - mu * mu;
    float inv = rsqrtf(var + 1e-5f);
    const float* LW = W + LNW_O + r * 128;
    const float* LB = W + LNB_O + r * 128;
#pragma unroll
    for (int nt = 0; nt < 8; nt++) {
        f32x4 lw = *(const f32x4*)(LW + nt * 16 + q * 4);
        f32x4 lb = *(const f32x4*)(LB + nt * 16 + q * 4);
        float u0 = fmaxf(fmaf((acc[nt][0] - mu) * inv, lw[0], lb[0]), 0.f);
        float u1 = fmaxf(fmaf((acc[nt][1] - mu) * inv, lw[1], lb[1]), 0.f);
        float u2 = fmaxf(fmaf((acc[nt][2] - mu) * inv, lw[2], lb[2]), 0.f);
        float u3 = fmaxf(fmaf((acc[nt][3] - mu) * inv, lw[3], lb[3]), 0.f);
        bufY[mr * 68 + nt * 8 + q * 2 + 0] = pack2(u0, u1);
        bufY[mr * 68 + nt * 8 + q * 2 + 1] = pack2(u2, u3);
    }
    WAVE_SYNC();
    f32x4 acc2[4];
    mfma_layer<4, 4, 68>(bufY, lane, Wf, FR_MP1 + r * 16, W + MP_B1 + r * 64, acc2);
    if (row < N_NODES) {
#pragma unroll
        for (int nt = 0; nt < 4; nt++) {
            f32x4 v = acc2[nt];
            u32x2 pb; pb.x = pack2(v[0], v[1]); pb.y = pack2(v[2], v[3]);
            *(u32x2*)&xbf[row * 64 + nt * 16 + q * 4] = pb;
        }
    }
}

__global__ __launch_bounds__(256) void policy_head(const void* nf,
        const u16* __restrict__ xbf, void* out, const float* __restrict__ W,
        const short8* __restrict__ Wf, const u32* __restrict__ gtbl) {
    __shared__ u32 lds[4 * 576];
    __shared__ u32 tbl[TANH_TBL_N];
    bool bf = detect_bf(nf);
    load_tbl(gtbl, tbl);
    int wv = threadIdx.x >> 6, lane = threadIdx.x & 63;
    int q = lane >> 4, mr = lane & 15;
    u32* bufY = lds + wv * 576;
    long nbase = (long)blockIdx.x * 64 + wv * 16;
    long row = nbase + mr;
    long rc = (row < N_NODES) ? row : (N_NODES - 1);
    short8 act[2];
#pragma unroll
    for (int kt = 0; kt < 2; kt++)
        act[kt] = *(const short8*)&xbf[rc * 64 + kt * 32 + q * 8];
    f32x4 acc[4];
    mfma_layer_reg<2, 4>(act, lane, Wf, FR_PI0, W + PI_B0, acc);
    tanh_pack_lds<4, 36>(acc, bufY, lane, tbl);
    WAVE_SYNC();
    mfma_layer<2, 4, 36>(bufY, lane, Wf, FR_PI1, W + PI_B1, acc);
    float o = 0.f;
#pragma unroll
    for (int nt = 0; nt < 4; nt++) {
        f32x4 w2 = *(const f32x4*)(W + PI_W2 + nt * 16 + q * 4);
#pragma unroll
        for (int rr = 0; rr < 4; rr++) o = fmaf(lut_tanh(tbl, acc[nt][rr]), w2[rr], o);
    }
    o += __shfl_xor(o, 16, 64);
    o += __shfl_xor(o, 32, 64);
    if (lane < 16 && row < N_NODES) {
        float means = 30.f * (o + W[PI_B2]);
        if (bf) ((u16*)out)[row] = f2b(means);
        else    ((float*)out)[row] = means;
    }
}

// ---------------- launch ----------------
extern "C" void kernel_launch(void* const* d_in, const int* in_sizes, int n_in,
                              void* d_out, int out_size, void* d_ws, size_t ws_size,
                              hipStream_t stream) {
    char* ws = (char*)d_ws;
    float* W      = (float*)(ws + OFF_W);
    u16*   Wb     = (u16*)(ws + OFF_WB);
    const short8* Wf = (const short8*)(ws + OFF_WB);
    u32*   gtbl   = (u32*)(ws + OFF_TBL);
    u16*   xb0    = (u16*)(ws + OFF_XB0);
    u16*   xb1    = (u16*)(ws + OFF_XB1);
    u16*   h64bf  = (u16*)(ws + OFF_H64B);
    u32*   h64b32 = (u32*)(ws + OFF_H64B);
    u32*   ebuf32 = (u32*)(ws + OFF_E);
    int*   prow   = (int*)(ws + OFF_ROWPTR);
    int*   cursor = (int*)(ws + OFF_CURSOR);
    int*   cnts   = (int*)(ws + OFF_CNT);
    int*   perm   = (int*)(ws + OFF_PERM);
    int*   srcs   = (int*)(ws + OFF_SRCS);
    int*   bsum   = (int*)(ws + OFF_BSUM);

    const void* nf  = d_in[0];
    const int* ei   = (const int*)d_in[2];
    const int* srcv = ei;
    const int* dstv = ei + N_EDGES;

    hipMemsetAsync(cnts, 0, N_NODES * sizeof(int), stream);

    Ptrs24 ps;
    for (int k = 0; k < 24; k++) ps.p[k] = d_in[3 + k];
    prep_kernel<<<(FR_TOTAL * 512 + 1986 + TANH_TBL_N + 255) / 256, 256, 0, stream>>>(
        nf, ps, W, Wb, gtbl);

    hist_kernel<<<(N_EDGES + 255) / 256, 256, 0, stream>>>(dstv, cnts);
    scanA<<<25, 1024, 0, stream>>>(cnts, prow, bsum);
    scanC<<<(N_NODES + 1024) / 1024, 1024, 0, stream>>>(bsum, cnts, prow, cursor, srcs);
    scatter_kernel<<<(N_EDGES + 255) / 256, 256, 0, stream>>>(dstv, srcv, cursor, perm, srcs);

    node_encoder<<<(N_NODES + 63) / 64, 256, 0, stream>>>(nf, xb0, W, Wf, gtbl);
    edge_encoder<<<N_EDGES / 64, 256, 0, stream>>>(nf, d_in[1], ebuf32, perm, W, Wf, gtbl);

    u16* xbc = xb0; u16* xbn = xb1;
    const int aggBlocks = (N_NODES / 2 * 64) / 256;   // 2 nodes/wave, 4 waves/block
    aggregate_kernel<0><<<aggBlocks, 256, 0, stream>>>((const u32*)xbc, ebuf32, srcs, prow, h64b32);
    mlp_fused<<<(N_NODES + 63) / 64, 256, 0, stream>>>(h64bf, xbn, W, Wf, 0);
    { u16* tb = xbc; xbc = xbn; xbn = tb; }
    aggregate_kernel<1><<<aggBlocks, 256, 0, stream>>>((const u32*)xbc, ebuf32, srcs, prow, h64b32);
    mlp_fused<<<(N_NODES + 63) / 64, 256, 0, stream>>>(h64bf, xbn, W, Wf, 1);
    { u16* tb = xbc; xbc = xbn; xbn = tb; }
    aggregate_kernel<2><<<aggBlocks, 256, 0, stream>>>((const u32*)xbc, ebuf32, srcs, prow, h64b32);
    mlp_fused<<<(N_NODES + 63) / 64, 256, 0, stream>>>(h64bf, xbn, W, Wf, 2);
    { u16* tb = xbc; xbc = xbn; xbn = tb; }

    policy_head<<<(N_NODES + 63) / 64, 256, 0, stream>>>(nf, xbc, d_out, W, Wf, gtbl);
}